// Round 1
// baseline (7823.446 us; speedup 1.0000x reference)
//
#include <hip/hip_runtime.h>
#include <math.h>

// GAT pipeline: two 512->256 GATConvs (spatial + gene graphs) on x, ELU, 0.5/0.5 fuse,
// then 256->64 GATConv on spatial graph. fp32 throughout (round-1 correctness anchor).
//
// Workspace layout (floats):
//   B1 [N*256]  h_sp, later agg_gene
//   B2 [N*256]  h_gs, later h_fu (N*64)
//   B3 [N*256]  agg_spatial, later h_fused
//   asrc[N], adst[N], denom[N], ex[E+N]
// Total = 3*N*256 + 3N + (E+N) floats ~= 312 MB for N=1e5, E=8e5.

#define NEG_SLOPE 0.2f

__device__ __forceinline__ void atomAddF(float* p, float v) { unsafeAtomicAdd(p, v); }

// ---------------- fp32 tiled GEMM: C[M,Nc] = A[M,K] @ B[K,Nc], row-major ----------------
__global__ __launch_bounds__(256) void sgemm64(const float* __restrict__ A,
                                               const float* __restrict__ B,
                                               float* __restrict__ C,
                                               int M, int Nc, int K) {
  __shared__ float sA[16][68];  // [k][m], row stride 68 floats = 272B (16B aligned)
  __shared__ float sB[16][68];  // [k][n]
  const int bm = blockIdx.x * 64;
  const int bn = blockIdx.y * 64;
  const int t = threadIdx.x;
  const int tx = t & 15, ty = t >> 4;
  const int lr = t >> 2, lc4 = (t & 3) << 2;   // A tile: row 0..63, col {0,4,8,12}
  const int bkr = t >> 4, bc4 = (t & 15) << 2; // B tile: k 0..15, col {0..60}
  float acc[4][4] = {{0.f}};
  for (int k0 = 0; k0 < K; k0 += 16) {
    float4 av = make_float4(0.f, 0.f, 0.f, 0.f);
    const int ar = bm + lr;
    if (ar < M) av = *(const float4*)(A + (size_t)ar * K + k0 + lc4);
    sA[lc4 + 0][lr] = av.x;
    sA[lc4 + 1][lr] = av.y;
    sA[lc4 + 2][lr] = av.z;
    sA[lc4 + 3][lr] = av.w;
    const float4 bv = *(const float4*)(B + (size_t)(k0 + bkr) * Nc + bn + bc4);
    *(float4*)&sB[bkr][bc4] = bv;
    __syncthreads();
#pragma unroll
    for (int kk = 0; kk < 16; ++kk) {
      const float4 a = *(const float4*)&sA[kk][ty << 2];
      const float4 b = *(const float4*)&sB[kk][tx << 2];
      acc[0][0] += a.x * b.x; acc[0][1] += a.x * b.y; acc[0][2] += a.x * b.z; acc[0][3] += a.x * b.w;
      acc[1][0] += a.y * b.x; acc[1][1] += a.y * b.y; acc[1][2] += a.y * b.z; acc[1][3] += a.y * b.w;
      acc[2][0] += a.z * b.x; acc[2][1] += a.z * b.y; acc[2][2] += a.z * b.z; acc[2][3] += a.z * b.w;
      acc[3][0] += a.w * b.x; acc[3][1] += a.w * b.y; acc[3][2] += a.w * b.z; acc[3][3] += a.w * b.w;
    }
    __syncthreads();
  }
#pragma unroll
  for (int i = 0; i < 4; ++i) {
    const int r = bm + (ty << 2) + i;
    if (r < M) {
      float4 o = make_float4(acc[i][0], acc[i][1], acc[i][2], acc[i][3]);
      *(float4*)(C + (size_t)r * Nc + bn + (tx << 2)) = o;
    }
  }
}

// ---------------- alpha dots: asrc[r] = h[r,:] . a_src, adst likewise (H=256) ----------
__global__ __launch_bounds__(256) void alpha256(const float* __restrict__ h,
                                                const float* __restrict__ a_src,
                                                const float* __restrict__ a_dst,
                                                float* __restrict__ asrc,
                                                float* __restrict__ adst, int N) {
  const int wave = (int)((blockIdx.x * (size_t)blockDim.x + threadIdx.x) >> 6);
  const int lane = threadIdx.x & 63;
  if (wave >= N) return;
  const float4 hv = ((const float4*)(h + (size_t)wave * 256))[lane];
  const float4 s4 = ((const float4*)a_src)[lane];
  const float4 d4 = ((const float4*)a_dst)[lane];
  float ps = hv.x * s4.x + hv.y * s4.y + hv.z * s4.z + hv.w * s4.w;
  float pd = hv.x * d4.x + hv.y * d4.y + hv.z * d4.z + hv.w * d4.w;
#pragma unroll
  for (int off = 32; off; off >>= 1) {
    ps += __shfl_down(ps, off);
    pd += __shfl_down(pd, off);
  }
  if (lane == 0) { asrc[wave] = ps; adst[wave] = pd; }
}

// H=64 variant
__global__ __launch_bounds__(256) void alpha64(const float* __restrict__ h,
                                               const float* __restrict__ a_src,
                                               const float* __restrict__ a_dst,
                                               float* __restrict__ asrc,
                                               float* __restrict__ adst, int N) {
  const int wave = (int)((blockIdx.x * (size_t)blockDim.x + threadIdx.x) >> 6);
  const int lane = threadIdx.x & 63;
  if (wave >= N) return;
  const float hv = h[(size_t)wave * 64 + lane];
  float ps = hv * a_src[lane];
  float pd = hv * a_dst[lane];
#pragma unroll
  for (int off = 32; off; off >>= 1) {
    ps += __shfl_down(ps, off);
    pd += __shfl_down(pd, off);
  }
  if (lane == 0) { asrc[wave] = ps; adst[wave] = pd; }
}

// ---------------- edge pass: w = exp(leaky_relu(asrc[s]+adst[d])), denom[d] += w -------
// No segment-max pass: e is bounded (|e| <~ 10) so exp() cannot overflow in fp32 and the
// softmax ratio is mathematically identical to the max-subtracted reference.
__global__ __launch_bounds__(256) void edge_pass(const int* __restrict__ ei,
                                                 const float* __restrict__ asrc,
                                                 const float* __restrict__ adst,
                                                 float* __restrict__ ex,
                                                 float* __restrict__ denom,
                                                 int E, int Mtot) {
  const int m = (int)(blockIdx.x * (size_t)blockDim.x + threadIdx.x);
  if (m >= Mtot) return;
  int s, d;
  if (m < E) { s = ei[m]; d = ei[E + m]; } else { s = d = m - E; }
  float e = asrc[s] + adst[d];
  e = e > 0.f ? e : NEG_SLOPE * e;
  const float w = expf(e);
  ex[m] = w;
  atomAddF(&denom[d], w);
}

// ---------------- aggregation (H=256): out[d,:] += (ex[m]/denom[d]) * h[s,:] -----------
// one wave per message; lane handles 4 contiguous floats
__global__ __launch_bounds__(256) void agg256(const int* __restrict__ ei,
                                              const float* __restrict__ ex,
                                              const float* __restrict__ denom,
                                              const float* __restrict__ h,
                                              float* __restrict__ out,
                                              int E, int Mtot) {
  const size_t g = blockIdx.x * (size_t)blockDim.x + threadIdx.x;
  const int m = (int)(g >> 6), lane = (int)(g & 63);
  if (m >= Mtot) return;
  int s, d;
  if (m < E) { s = ei[m]; d = ei[E + m]; } else { s = d = m - E; }
  const float coef = ex[m] / denom[d];
  const float4 hv = ((const float4*)(h + (size_t)s * 256))[lane];
  float* o = out + (size_t)d * 256 + (lane << 2);
  atomAddF(o + 0, coef * hv.x);
  atomAddF(o + 1, coef * hv.y);
  atomAddF(o + 2, coef * hv.z);
  atomAddF(o + 3, coef * hv.w);
}

// H=64 variant: 16 lanes per message, float4 each
__global__ __launch_bounds__(256) void agg64(const int* __restrict__ ei,
                                             const float* __restrict__ ex,
                                             const float* __restrict__ denom,
                                             const float* __restrict__ h,
                                             float* __restrict__ out,
                                             int E, int Mtot) {
  const size_t g = blockIdx.x * (size_t)blockDim.x + threadIdx.x;
  const int m = (int)(g >> 4), l = (int)(g & 15);
  if (m >= Mtot) return;
  int s, d;
  if (m < E) { s = ei[m]; d = ei[E + m]; } else { s = d = m - E; }
  const float coef = ex[m] / denom[d];
  const float4 hv = ((const float4*)(h + (size_t)s * 64))[l];
  float* o = out + (size_t)d * 64 + (l << 2);
  atomAddF(o + 0, coef * hv.x);
  atomAddF(o + 1, coef * hv.y);
  atomAddF(o + 2, coef * hv.z);
  atomAddF(o + 3, coef * hv.w);
}

// ---------------- fuse: B3 = 0.5*elu(agg_gs + b_gs) + 0.5*elu(agg_sp + b_sp) ----------
__global__ __launch_bounds__(256) void fuse_elu(const float* __restrict__ agg_gs,
                                                float* __restrict__ agg_sp_io,
                                                const float* __restrict__ b_gs,
                                                const float* __restrict__ b_sp,
                                                size_t n4) {
  const size_t i = blockIdx.x * (size_t)blockDim.x + threadIdx.x;
  if (i >= n4) return;
  const float4 g = ((const float4*)agg_gs)[i];
  const float4 s = ((const float4*)agg_sp_io)[i];
  const int c0 = (int)((i << 2) & 255);
  float r[4];
  const float gv[4] = {g.x, g.y, g.z, g.w};
  const float sv[4] = {s.x, s.y, s.z, s.w};
#pragma unroll
  for (int j = 0; j < 4; ++j) {
    float a = gv[j] + b_gs[c0 + j];
    float b = sv[j] + b_sp[c0 + j];
    a = a > 0.f ? a : (expf(a) - 1.f);
    b = b > 0.f ? b : (expf(b) - 1.f);
    r[j] = 0.5f * a + 0.5f * b;
  }
  ((float4*)agg_sp_io)[i] = make_float4(r[0], r[1], r[2], r[3]);
}

// ---------------- init d_out with bias (aggregation accumulates on top) ---------------
__global__ __launch_bounds__(256) void init_bias64(float* __restrict__ out,
                                                   const float* __restrict__ b,
                                                   size_t total) {
  const size_t i = blockIdx.x * (size_t)blockDim.x + threadIdx.x;
  if (i < total) out[i] = b[i & 63];
}

extern "C" void kernel_launch(void* const* d_in, const int* in_sizes, int n_in,
                              void* d_out, int out_size, void* d_ws, size_t ws_size,
                              hipStream_t stream) {
  const float* x        = (const float*)d_in[0];
  const int*   ei_sp    = (const int*)d_in[1];
  const int*   ei_gs    = (const int*)d_in[2];
  const float* W_sp     = (const float*)d_in[3];
  const float* a_src_sp = (const float*)d_in[4];
  const float* a_dst_sp = (const float*)d_in[5];
  const float* b_sp     = (const float*)d_in[6];
  const float* W_gs     = (const float*)d_in[7];
  const float* a_src_gs = (const float*)d_in[8];
  const float* a_dst_gs = (const float*)d_in[9];
  const float* b_gs     = (const float*)d_in[10];
  const float* W_fu     = (const float*)d_in[11];
  const float* a_src_fu = (const float*)d_in[12];
  const float* a_dst_fu = (const float*)d_in[13];
  const float* b_fu     = (const float*)d_in[14];
  float* out = (float*)d_out;

  const int N = in_sizes[0] / 512;
  const int E = in_sizes[1] / 2;
  const int Mtot = E + N;

  float* B1    = (float*)d_ws;              // N*256
  float* B2    = B1 + (size_t)N * 256;      // N*256
  float* B3    = B2 + (size_t)N * 256;      // N*256
  float* asrc  = B3 + (size_t)N * 256;      // N
  float* adst  = asrc + N;                  // N
  float* denom = adst + N;                  // N
  float* ex    = denom + N;                 // E+N

  const int BLK = 256;
  const dim3 gemmGrid((N + 63) / 64, 256 / 64);
  const dim3 gemmGridFu((N + 63) / 64, 64 / 64);
  const int alphaGrid = (N + 3) / 4;
  const int edgeGrid = (Mtot + BLK - 1) / BLK;
  const int agg256Grid = (int)(((size_t)Mtot * 64 + BLK - 1) / BLK);
  const int agg64Grid = (int)(((size_t)Mtot * 16 + BLK - 1) / BLK);
  const size_t n4 = (size_t)N * 64;  // N*256/4 float4s
  const int fuseGrid = (int)((n4 + BLK - 1) / BLK);
  const size_t outTotal = (size_t)N * 64;
  const int initGrid = (int)((outTotal + BLK - 1) / BLK);

  // ---- layer 1 (spatial): h_sp = x@W_sp -> B1
  sgemm64<<<gemmGrid, BLK, 0, stream>>>(x, W_sp, B1, N, 256, 512);
  // ---- layer 1 (gene): h_gs = x@W_gs -> B2
  sgemm64<<<gemmGrid, BLK, 0, stream>>>(x, W_gs, B2, N, 256, 512);

  // spatial attention + aggregate into B3
  alpha256<<<alphaGrid, BLK, 0, stream>>>(B1, a_src_sp, a_dst_sp, asrc, adst, N);
  hipMemsetAsync(denom, 0, (size_t)N * 4, stream);
  edge_pass<<<edgeGrid, BLK, 0, stream>>>(ei_sp, asrc, adst, ex, denom, E, Mtot);
  hipMemsetAsync(B3, 0, (size_t)N * 256 * 4, stream);
  agg256<<<agg256Grid, BLK, 0, stream>>>(ei_sp, ex, denom, B1, B3, E, Mtot);

  // gene attention + aggregate into B1 (h_sp no longer needed)
  alpha256<<<alphaGrid, BLK, 0, stream>>>(B2, a_src_gs, a_dst_gs, asrc, adst, N);
  hipMemsetAsync(denom, 0, (size_t)N * 4, stream);
  edge_pass<<<edgeGrid, BLK, 0, stream>>>(ei_gs, asrc, adst, ex, denom, E, Mtot);
  hipMemsetAsync(B1, 0, (size_t)N * 256 * 4, stream);
  agg256<<<agg256Grid, BLK, 0, stream>>>(ei_gs, ex, denom, B2, B1, E, Mtot);

  // fuse: B3 = 0.5*elu(B1 + b_gs) + 0.5*elu(B3 + b_sp)  (= h_fused)
  fuse_elu<<<fuseGrid, BLK, 0, stream>>>(B1, B3, b_gs, b_sp, n4);

  // ---- layer 2 (fusion GAT on spatial graph): h_fu = h_fused@W_fu -> B2 (free)
  sgemm64<<<gemmGridFu, BLK, 0, stream>>>(B3, W_fu, B2, N, 64, 256);
  alpha64<<<alphaGrid, BLK, 0, stream>>>(B2, a_src_fu, a_dst_fu, asrc, adst, N);
  hipMemsetAsync(denom, 0, (size_t)N * 4, stream);
  edge_pass<<<edgeGrid, BLK, 0, stream>>>(ei_sp, asrc, adst, ex, denom, E, Mtot);
  init_bias64<<<initGrid, BLK, 0, stream>>>(out, b_fu, outTotal);
  agg64<<<agg64Grid, BLK, 0, stream>>>(ei_sp, ex, denom, B2, out, E, Mtot);
}

// Round 2
// 1504.075 us; speedup vs baseline: 5.2015x; 5.2015x over previous
//
#include <hip/hip_runtime.h>
#include <math.h>

// GAT pipeline, round 2: CSR-based gather aggregation (no fp32 atomics).
// Per GATConv: h = x@W (fp32 tiled GEMM); per-node alpha dots; then ONE fused
// kernel per conv: wave-per-dst-node walks CSR in-edges, computes softmax
// weights on the fly (no max-subtraction needed: |e| is bounded so exp() is
// safe in fp32 and the ratio is mathematically identical), accumulates w*h[src]
// in registers, writes the row once with the epilogue fused
// (ELU+bias / blend / final bias).
//
// Workspace (floats unless noted):
//   B1 [N*256]  h_sp, later h_fu (N*64)
//   B2 [N*256]  h_gs
//   B3 [N*256]  agg_spatial_elu -> h_fused (in-place blend)
//   asrc[N], adst[N]
//   int rs_sp[N+1], rs_gs[N+1], csr_sp[E], csr_gs[E], deg/cursor[N], parts[512]

#define NEG_SLOPE 0.2f

// ---------------- CSR build ----------------
__global__ __launch_bounds__(256) void hist_dst(const int* __restrict__ dst,
                                                int* __restrict__ deg, int E) {
  const int m = blockIdx.x * 256 + threadIdx.x;
  if (m < E) atomicAdd(&deg[dst[m]], 1);
}

__global__ __launch_bounds__(256) void scan1(const int* __restrict__ deg,
                                             int* __restrict__ rs,
                                             int* __restrict__ parts, int N) {
  __shared__ int sm[256];
  const int i = blockIdx.x * 256 + threadIdx.x;
  const int v = (i < N) ? deg[i] : 0;
  sm[threadIdx.x] = v;
  __syncthreads();
  for (int off = 1; off < 256; off <<= 1) {
    const int x = (threadIdx.x >= off) ? sm[threadIdx.x - off] : 0;
    __syncthreads();
    sm[threadIdx.x] += x;
    __syncthreads();
  }
  if (i < N) rs[i] = sm[threadIdx.x] - v;  // exclusive within block
  if (threadIdx.x == 255) parts[blockIdx.x] = sm[255];
}

__global__ __launch_bounds__(512) void scan2(int* __restrict__ parts, int nb) {
  __shared__ int sm[512];
  const int t = threadIdx.x;
  const int v = (t < nb) ? parts[t] : 0;
  sm[t] = v;
  __syncthreads();
  for (int off = 1; off < 512; off <<= 1) {
    const int x = (t >= off) ? sm[t - off] : 0;
    __syncthreads();
    sm[t] += x;
    __syncthreads();
  }
  if (t < nb) parts[t] = sm[t] - v;  // exclusive
}

__global__ __launch_bounds__(256) void scan3(int* __restrict__ rs,
                                             const int* __restrict__ parts,
                                             int N, int E) {
  const int i = blockIdx.x * 256 + threadIdx.x;
  if (i < N) rs[i] += parts[blockIdx.x];
  if (i == 0) rs[N] = E;
}

__global__ __launch_bounds__(256) void scatter_src(const int* __restrict__ ei,
                                                   const int* __restrict__ rs,
                                                   int* __restrict__ cursor,
                                                   int* __restrict__ csr, int E) {
  const int m = blockIdx.x * 256 + threadIdx.x;
  if (m >= E) return;
  const int s = ei[m], d = ei[E + m];
  const int slot = rs[d] + atomicAdd(&cursor[d], 1);
  csr[slot] = s;
}

// ---------------- fp32 tiled GEMM: C[M,Nc] = A[M,K] @ B[K,Nc], row-major --------------
__global__ __launch_bounds__(256) void sgemm64(const float* __restrict__ A,
                                               const float* __restrict__ B,
                                               float* __restrict__ C,
                                               int M, int Nc, int K) {
  __shared__ float sA[16][68];
  __shared__ float sB[16][68];
  const int bm = blockIdx.x * 64;
  const int bn = blockIdx.y * 64;
  const int t = threadIdx.x;
  const int tx = t & 15, ty = t >> 4;
  const int lr = t >> 2, lc4 = (t & 3) << 2;
  const int bkr = t >> 4, bc4 = (t & 15) << 2;
  float acc[4][4] = {{0.f}};
  for (int k0 = 0; k0 < K; k0 += 16) {
    float4 av = make_float4(0.f, 0.f, 0.f, 0.f);
    const int ar = bm + lr;
    if (ar < M) av = *(const float4*)(A + (size_t)ar * K + k0 + lc4);
    sA[lc4 + 0][lr] = av.x;
    sA[lc4 + 1][lr] = av.y;
    sA[lc4 + 2][lr] = av.z;
    sA[lc4 + 3][lr] = av.w;
    const float4 bv = *(const float4*)(B + (size_t)(k0 + bkr) * Nc + bn + bc4);
    *(float4*)&sB[bkr][bc4] = bv;
    __syncthreads();
#pragma unroll
    for (int kk = 0; kk < 16; ++kk) {
      const float4 a = *(const float4*)&sA[kk][ty << 2];
      const float4 b = *(const float4*)&sB[kk][tx << 2];
      acc[0][0] += a.x * b.x; acc[0][1] += a.x * b.y; acc[0][2] += a.x * b.z; acc[0][3] += a.x * b.w;
      acc[1][0] += a.y * b.x; acc[1][1] += a.y * b.y; acc[1][2] += a.y * b.z; acc[1][3] += a.y * b.w;
      acc[2][0] += a.z * b.x; acc[2][1] += a.z * b.y; acc[2][2] += a.z * b.z; acc[2][3] += a.z * b.w;
      acc[3][0] += a.w * b.x; acc[3][1] += a.w * b.y; acc[3][2] += a.w * b.z; acc[3][3] += a.w * b.w;
    }
    __syncthreads();
  }
#pragma unroll
  for (int i = 0; i < 4; ++i) {
    const int r = bm + (ty << 2) + i;
    if (r < M) {
      float4 o = make_float4(acc[i][0], acc[i][1], acc[i][2], acc[i][3]);
      *(float4*)(C + (size_t)r * Nc + bn + (tx << 2)) = o;
    }
  }
}

// ---------------- alpha dots ----------------
__global__ __launch_bounds__(256) void alpha256(const float* __restrict__ h,
                                                const float* __restrict__ a_src,
                                                const float* __restrict__ a_dst,
                                                float* __restrict__ asrc,
                                                float* __restrict__ adst, int N) {
  const int wave = (int)((blockIdx.x * (size_t)blockDim.x + threadIdx.x) >> 6);
  const int lane = threadIdx.x & 63;
  if (wave >= N) return;
  const float4 hv = ((const float4*)(h + (size_t)wave * 256))[lane];
  const float4 s4 = ((const float4*)a_src)[lane];
  const float4 d4 = ((const float4*)a_dst)[lane];
  float ps = hv.x * s4.x + hv.y * s4.y + hv.z * s4.z + hv.w * s4.w;
  float pd = hv.x * d4.x + hv.y * d4.y + hv.z * d4.z + hv.w * d4.w;
#pragma unroll
  for (int off = 32; off; off >>= 1) {
    ps += __shfl_down(ps, off);
    pd += __shfl_down(pd, off);
  }
  if (lane == 0) { asrc[wave] = ps; adst[wave] = pd; }
}

__global__ __launch_bounds__(256) void alpha64(const float* __restrict__ h,
                                               const float* __restrict__ a_src,
                                               const float* __restrict__ a_dst,
                                               float* __restrict__ asrc,
                                               float* __restrict__ adst, int N) {
  const int wave = (int)((blockIdx.x * (size_t)blockDim.x + threadIdx.x) >> 6);
  const int lane = threadIdx.x & 63;
  if (wave >= N) return;
  const float hv = h[(size_t)wave * 64 + lane];
  float ps = hv * a_src[lane];
  float pd = hv * a_dst[lane];
#pragma unroll
  for (int off = 32; off; off >>= 1) {
    ps += __shfl_down(ps, off);
    pd += __shfl_down(pd, off);
  }
  if (lane == 0) { asrc[wave] = ps; adst[wave] = pd; }
}

// ---------------- fused CSR aggregation, H=256 ----------------
// EPI 1: out = elu(agg + bias)                     (spatial layer-1)
// EPI 2: out = 0.5*elu(agg + bias) + 0.5*other     (gene layer-1 + blend, in-place ok)
template <int EPI>
__global__ __launch_bounds__(256) void agg_csr256(const int* __restrict__ rs,
                                                  const int* __restrict__ csr,
                                                  const float* __restrict__ asrc,
                                                  const float* __restrict__ adst,
                                                  const float* __restrict__ h,
                                                  const float* __restrict__ bias,
                                                  const float* __restrict__ other,
                                                  float* __restrict__ outb, int N) {
  const int d = (int)((blockIdx.x * (size_t)blockDim.x + threadIdx.x) >> 6);
  const int lane = threadIdx.x & 63;
  if (d >= N) return;
  const float ad = adst[d];
  const float4* __restrict__ h4 = (const float4*)h;

  // self-loop
  float e = asrc[d] + ad;
  e = e > 0.f ? e : NEG_SLOPE * e;
  float w = expf(e);
  float den = w;
  float4 hv = h4[(size_t)d * 64 + lane];
  float4 acc = make_float4(w * hv.x, w * hv.y, w * hv.z, w * hv.w);

  const int mend = rs[d + 1];
  for (int m = rs[d]; m < mend; ++m) {
    const int s = csr[m];
    float e2 = asrc[s] + ad;
    e2 = e2 > 0.f ? e2 : NEG_SLOPE * e2;
    const float w2 = expf(e2);
    den += w2;
    const float4 hv2 = h4[(size_t)s * 64 + lane];
    acc.x += w2 * hv2.x;
    acc.y += w2 * hv2.y;
    acc.z += w2 * hv2.z;
    acc.w += w2 * hv2.w;
  }
  const float inv = 1.f / den;
  const float4 b4 = ((const float4*)bias)[lane];
  float v[4] = {acc.x * inv + b4.x, acc.y * inv + b4.y,
                acc.z * inv + b4.z, acc.w * inv + b4.w};
#pragma unroll
  for (int j = 0; j < 4; ++j) v[j] = v[j] > 0.f ? v[j] : (expf(v[j]) - 1.f);
  float4 r;
  if (EPI == 2) {
    const float4 ov = ((const float4*)other)[(size_t)d * 64 + lane];
    r = make_float4(0.5f * v[0] + 0.5f * ov.x, 0.5f * v[1] + 0.5f * ov.y,
                    0.5f * v[2] + 0.5f * ov.z, 0.5f * v[3] + 0.5f * ov.w);
  } else {
    r = make_float4(v[0], v[1], v[2], v[3]);
  }
  ((float4*)outb)[(size_t)d * 64 + lane] = r;
}

// ---------------- fused CSR aggregation, H=64, epilogue = +bias -> d_out --------------
__global__ __launch_bounds__(256) void agg_csr64(const int* __restrict__ rs,
                                                 const int* __restrict__ csr,
                                                 const float* __restrict__ asrc,
                                                 const float* __restrict__ adst,
                                                 const float* __restrict__ h,
                                                 const float* __restrict__ bias,
                                                 float* __restrict__ outb, int N) {
  const int d = (int)((blockIdx.x * (size_t)blockDim.x + threadIdx.x) >> 6);
  const int lane = threadIdx.x & 63;
  if (d >= N) return;
  const float ad = adst[d];

  float e = asrc[d] + ad;
  e = e > 0.f ? e : NEG_SLOPE * e;
  float w = expf(e);
  float den = w;
  float acc = w * h[(size_t)d * 64 + lane];

  const int mend = rs[d + 1];
  for (int m = rs[d]; m < mend; ++m) {
    const int s = csr[m];
    float e2 = asrc[s] + ad;
    e2 = e2 > 0.f ? e2 : NEG_SLOPE * e2;
    const float w2 = expf(e2);
    den += w2;
    acc += w2 * h[(size_t)s * 64 + lane];
  }
  outb[(size_t)d * 64 + lane] = acc / den + bias[lane];
}

extern "C" void kernel_launch(void* const* d_in, const int* in_sizes, int n_in,
                              void* d_out, int out_size, void* d_ws, size_t ws_size,
                              hipStream_t stream) {
  const float* x        = (const float*)d_in[0];
  const int*   ei_sp    = (const int*)d_in[1];
  const int*   ei_gs    = (const int*)d_in[2];
  const float* W_sp     = (const float*)d_in[3];
  const float* a_src_sp = (const float*)d_in[4];
  const float* a_dst_sp = (const float*)d_in[5];
  const float* b_sp     = (const float*)d_in[6];
  const float* W_gs     = (const float*)d_in[7];
  const float* a_src_gs = (const float*)d_in[8];
  const float* a_dst_gs = (const float*)d_in[9];
  const float* b_gs     = (const float*)d_in[10];
  const float* W_fu     = (const float*)d_in[11];
  const float* a_src_fu = (const float*)d_in[12];
  const float* a_dst_fu = (const float*)d_in[13];
  const float* b_fu     = (const float*)d_in[14];
  float* out = (float*)d_out;

  const int N = in_sizes[0] / 512;
  const int E = in_sizes[1] / 2;
  const int nb = (N + 255) / 256;

  float* B1   = (float*)d_ws;               // N*256
  float* B2   = B1 + (size_t)N * 256;       // N*256
  float* B3   = B2 + (size_t)N * 256;       // N*256
  float* asrc = B3 + (size_t)N * 256;       // N
  float* adst = asrc + N;                   // N
  int* rs_sp  = (int*)(adst + N);           // N+1
  int* rs_gs  = rs_sp + (N + 1);            // N+1
  int* csr_sp = rs_gs + (N + 1);            // E
  int* csr_gs = csr_sp + E;                 // E
  int* deg    = csr_gs + E;                 // N (also scatter cursor)
  int* parts  = deg + N;                    // 512

  const int BLK = 256;
  const int eGrid = (E + BLK - 1) / BLK;
  const int nodeWaveGrid = (N + 3) / 4;  // N waves, 4 waves/block
  const dim3 gemmGrid((N + 63) / 64, 256 / 64);
  const dim3 gemmGridFu((N + 63) / 64, 1);

  // ---- build CSR (spatial) ----
  hipMemsetAsync(deg, 0, (size_t)N * 4, stream);
  hist_dst<<<eGrid, BLK, 0, stream>>>(ei_sp + E, deg, E);
  scan1<<<nb, BLK, 0, stream>>>(deg, rs_sp, parts, N);
  scan2<<<1, 512, 0, stream>>>(parts, nb);
  scan3<<<nb, BLK, 0, stream>>>(rs_sp, parts, N, E);
  hipMemsetAsync(deg, 0, (size_t)N * 4, stream);
  scatter_src<<<eGrid, BLK, 0, stream>>>(ei_sp, rs_sp, deg, csr_sp, E);

  // ---- build CSR (gene) ----
  hipMemsetAsync(deg, 0, (size_t)N * 4, stream);
  hist_dst<<<eGrid, BLK, 0, stream>>>(ei_gs + E, deg, E);
  scan1<<<nb, BLK, 0, stream>>>(deg, rs_gs, parts, N);
  scan2<<<1, 512, 0, stream>>>(parts, nb);
  scan3<<<nb, BLK, 0, stream>>>(rs_gs, parts, N, E);
  hipMemsetAsync(deg, 0, (size_t)N * 4, stream);
  scatter_src<<<eGrid, BLK, 0, stream>>>(ei_gs, rs_gs, deg, csr_gs, E);

  // ---- layer 1 GEMMs ----
  sgemm64<<<gemmGrid, BLK, 0, stream>>>(x, W_sp, B1, N, 256, 512);
  sgemm64<<<gemmGrid, BLK, 0, stream>>>(x, W_gs, B2, N, 256, 512);

  // ---- spatial conv -> B3 = elu(agg + b_sp) ----
  alpha256<<<nodeWaveGrid, BLK, 0, stream>>>(B1, a_src_sp, a_dst_sp, asrc, adst, N);
  agg_csr256<1><<<nodeWaveGrid, BLK, 0, stream>>>(rs_sp, csr_sp, asrc, adst, B1, b_sp,
                                                  nullptr, B3, N);

  // ---- gene conv + blend (in-place on B3): B3 = 0.5*elu(agg_gs+b_gs) + 0.5*B3 ----
  alpha256<<<nodeWaveGrid, BLK, 0, stream>>>(B2, a_src_gs, a_dst_gs, asrc, adst, N);
  agg_csr256<2><<<nodeWaveGrid, BLK, 0, stream>>>(rs_gs, csr_gs, asrc, adst, B2, b_gs,
                                                  B3, B3, N);

  // ---- fusion conv (spatial graph, 256->64) ----
  sgemm64<<<gemmGridFu, BLK, 0, stream>>>(B3, W_fu, B1, N, 64, 256);
  alpha64<<<nodeWaveGrid, BLK, 0, stream>>>(B1, a_src_fu, a_dst_fu, asrc, adst, N);
  agg_csr64<<<nodeWaveGrid, BLK, 0, stream>>>(rs_sp, csr_sp, asrc, adst, B1, b_fu, out, N);
}

// Round 3
// 835.837 us; speedup vs baseline: 9.3600x; 1.7995x over previous
//
#include <hip/hip_runtime.h>
#include <math.h>

// Round 3: bf16 MFMA GEMMs (m97-style 128-tile, global_load_lds staging) replace
// fp32 sgemm. Weights device-transposed to bf16 [Nc][K] so the GEMM is NT with
// both fragments contiguous in LDS. Gene-layer aggregation writes h_fused
// directly as bf16 for the fusion GEMM. CSR aggregation unchanged from round 2.

#define NEG_SLOPE 0.2f

typedef __attribute__((ext_vector_type(8))) short bf16x8;
typedef __attribute__((ext_vector_type(4))) float f32x4;

__device__ __forceinline__ unsigned short f2bf(float f) {
  unsigned int u = __float_as_uint(f);
  u = (u + 0x7FFFu + ((u >> 16) & 1u)) >> 16;  // RNE
  return (unsigned short)u;
}

#define GLOAD16(g, l)                                                   \
  __builtin_amdgcn_global_load_lds(                                     \
      (const __attribute__((address_space(1))) void*)(g),               \
      (__attribute__((address_space(3))) void*)(l), 16, 0, 0)

// ---------------- conversions ----------------
__global__ __launch_bounds__(256) void conv_bf16(const float4* __restrict__ in,
                                                 ushort4* __restrict__ out,
                                                 size_t n4) {
  const size_t stride = (size_t)gridDim.x * blockDim.x;
  for (size_t i = blockIdx.x * (size_t)blockDim.x + threadIdx.x; i < n4; i += stride) {
    const float4 v = in[i];
    ushort4 o;
    o.x = f2bf(v.x); o.y = f2bf(v.y); o.z = f2bf(v.z); o.w = f2bf(v.w);
    out[i] = o;
  }
}

// W[K][Nc] fp32 -> Wt[Nc][K] bf16
__global__ __launch_bounds__(256) void wt_bf16(const float* __restrict__ W,
                                               unsigned short* __restrict__ Wt,
                                               int K, int Nc) {
  const int i = blockIdx.x * 256 + threadIdx.x;
  if (i < K * Nc) {
    const int k = i / Nc, n = i % Nc;
    Wt[n * K + k] = f2bf(W[i]);
  }
}

// ---------------- CSR build ----------------
__global__ __launch_bounds__(256) void hist_dst(const int* __restrict__ dst,
                                                int* __restrict__ deg, int E) {
  const int m = blockIdx.x * 256 + threadIdx.x;
  if (m < E) atomicAdd(&deg[dst[m]], 1);
}

__global__ __launch_bounds__(256) void scan1(const int* __restrict__ deg,
                                             int* __restrict__ rs,
                                             int* __restrict__ parts, int N) {
  __shared__ int sm[256];
  const int i = blockIdx.x * 256 + threadIdx.x;
  const int v = (i < N) ? deg[i] : 0;
  sm[threadIdx.x] = v;
  __syncthreads();
  for (int off = 1; off < 256; off <<= 1) {
    const int x = (threadIdx.x >= off) ? sm[threadIdx.x - off] : 0;
    __syncthreads();
    sm[threadIdx.x] += x;
    __syncthreads();
  }
  if (i < N) rs[i] = sm[threadIdx.x] - v;
  if (threadIdx.x == 255) parts[blockIdx.x] = sm[255];
}

__global__ __launch_bounds__(512) void scan2(int* __restrict__ parts, int nb) {
  __shared__ int sm[512];
  const int t = threadIdx.x;
  const int v = (t < nb) ? parts[t] : 0;
  sm[t] = v;
  __syncthreads();
  for (int off = 1; off < 512; off <<= 1) {
    const int x = (t >= off) ? sm[t - off] : 0;
    __syncthreads();
    sm[t] += x;
    __syncthreads();
  }
  if (t < nb) parts[t] = sm[t] - v;
}

__global__ __launch_bounds__(256) void scan3(int* __restrict__ rs,
                                             const int* __restrict__ parts,
                                             int N, int E) {
  const int i = blockIdx.x * 256 + threadIdx.x;
  if (i < N) rs[i] += parts[blockIdx.x];
  if (i == 0) rs[N] = E;
}

__global__ __launch_bounds__(256) void scatter_src(const int* __restrict__ ei,
                                                   const int* __restrict__ rs,
                                                   int* __restrict__ cursor,
                                                   int* __restrict__ csr, int E) {
  const int m = blockIdx.x * 256 + threadIdx.x;
  if (m >= E) return;
  const int s = ei[m], d = ei[E + m];
  const int slot = rs[d] + atomicAdd(&cursor[d], 1);
  csr[slot] = s;
}

// ---------------- bf16 MFMA GEMM (NT): C[M][Nc] = A[M][K] * Bt[Nc][K]^T -------------
// BM=128, BK=64, 256 threads (4 waves). BN=128: 2x2 waves of 64x64. BN=64: 4x1 of 32x64.
template <int BN>
__global__ __launch_bounds__(256) void gemm_bf16_nt(const unsigned short* __restrict__ A,
                                                    const unsigned short* __restrict__ Bt,
                                                    float* __restrict__ C,
                                                    int M, int Nc, int K) {
  constexpr int BM = 128, BK = 64;
  constexpr int NW = BN / 64;         // waves along N
  constexpr int MW = 4 / NW;          // waves along M
  constexpr int MF = (BM / MW) / 16;  // M frags per wave
  constexpr int NF = 4;               // 64/16
  constexpr int ACW = (BM * BK * 2 / 1024) / 4;  // A 1KB-chunks per wave
  constexpr int BCW = (BN * BK * 2 / 1024) / 4;  // B chunks per wave
  __shared__ unsigned short sA[BM * BK];
  __shared__ unsigned short sB[BN * BK];
  const int tid = threadIdx.x;
  const int w = tid >> 6, l = tid & 63;
  const int wr = w / NW, wc = w % NW;
  const int bm = blockIdx.x * BM;
  const int bn = blockIdx.y * BN;
  const int crow = l >> 3;            // 0..7 row within 1KB chunk
  const int cbyte = (l & 7) * 16;     // byte offset within 128B row-slice

  f32x4 acc[MF][NF] = {};
  for (int k0 = 0; k0 < K; k0 += BK) {
    __syncthreads();
#pragma unroll
    for (int c = 0; c < ACW; ++c) {
      const int ch = w * ACW + c;
      int row = bm + ch * 8 + crow;
      row = row < M ? row : M - 1;  // clamp: avoids OOB reads, rows discarded on store
      const char* g = (const char*)A + (size_t)row * K * 2 + (size_t)k0 * 2 + cbyte;
      GLOAD16(g, ((char*)sA) + ch * 1024);
    }
#pragma unroll
    for (int c = 0; c < BCW; ++c) {
      const int ch = w * BCW + c;
      const int row = bn + ch * 8 + crow;  // Bt rows always in range
      const char* g = (const char*)Bt + (size_t)row * K * 2 + (size_t)k0 * 2 + cbyte;
      GLOAD16(g, ((char*)sB) + ch * 1024);
    }
    __syncthreads();
#pragma unroll
    for (int ks = 0; ks < 2; ++ks) {
      bf16x8 af[MF], bfr[NF];
#pragma unroll
      for (int m = 0; m < MF; ++m) {
        const int r = wr * (BM / MW) + m * 16 + (l & 15);
        af[m] = *(const bf16x8*)&sA[r * BK + ks * 32 + (l >> 4) * 8];
      }
#pragma unroll
      for (int n = 0; n < NF; ++n) {
        const int r = wc * 64 + n * 16 + (l & 15);
        bfr[n] = *(const bf16x8*)&sB[r * BK + ks * 32 + (l >> 4) * 8];
      }
#pragma unroll
      for (int m = 0; m < MF; ++m)
#pragma unroll
        for (int n = 0; n < NF; ++n)
          acc[m][n] = __builtin_amdgcn_mfma_f32_16x16x32_bf16(af[m], bfr[n], acc[m][n], 0, 0, 0);
    }
  }
#pragma unroll
  for (int m = 0; m < MF; ++m) {
#pragma unroll
    for (int r = 0; r < 4; ++r) {
      const int row = bm + wr * (BM / MW) + m * 16 + (l >> 4) * 4 + r;
      if (row < M) {
#pragma unroll
        for (int n = 0; n < NF; ++n)
          C[(size_t)row * Nc + bn + wc * 64 + n * 16 + (l & 15)] = acc[m][n][r];
      }
    }
  }
}

// ---------------- alpha dots ----------------
__global__ __launch_bounds__(256) void alpha256(const float* __restrict__ h,
                                                const float* __restrict__ a_src,
                                                const float* __restrict__ a_dst,
                                                float* __restrict__ asrc,
                                                float* __restrict__ adst, int N) {
  const int wave = (int)((blockIdx.x * (size_t)blockDim.x + threadIdx.x) >> 6);
  const int lane = threadIdx.x & 63;
  if (wave >= N) return;
  const float4 hv = ((const float4*)(h + (size_t)wave * 256))[lane];
  const float4 s4 = ((const float4*)a_src)[lane];
  const float4 d4 = ((const float4*)a_dst)[lane];
  float ps = hv.x * s4.x + hv.y * s4.y + hv.z * s4.z + hv.w * s4.w;
  float pd = hv.x * d4.x + hv.y * d4.y + hv.z * d4.z + hv.w * d4.w;
#pragma unroll
  for (int off = 32; off; off >>= 1) {
    ps += __shfl_down(ps, off);
    pd += __shfl_down(pd, off);
  }
  if (lane == 0) { asrc[wave] = ps; adst[wave] = pd; }
}

__global__ __launch_bounds__(256) void alpha64(const float* __restrict__ h,
                                               const float* __restrict__ a_src,
                                               const float* __restrict__ a_dst,
                                               float* __restrict__ asrc,
                                               float* __restrict__ adst, int N) {
  const int wave = (int)((blockIdx.x * (size_t)blockDim.x + threadIdx.x) >> 6);
  const int lane = threadIdx.x & 63;
  if (wave >= N) return;
  const float hv = h[(size_t)wave * 64 + lane];
  float ps = hv * a_src[lane];
  float pd = hv * a_dst[lane];
#pragma unroll
  for (int off = 32; off; off >>= 1) {
    ps += __shfl_down(ps, off);
    pd += __shfl_down(pd, off);
  }
  if (lane == 0) { asrc[wave] = ps; adst[wave] = pd; }
}

// ---------------- fused CSR aggregation, H=256 ----------------
// EPI 1: outf = elu(agg + bias)                         (fp32)
// EPI 2: out16 = bf16(0.5*elu(agg + bias) + 0.5*other)  (h_fused for fusion GEMM)
template <int EPI>
__global__ __launch_bounds__(256) void agg_csr256(const int* __restrict__ rs,
                                                  const int* __restrict__ csr,
                                                  const float* __restrict__ asrc,
                                                  const float* __restrict__ adst,
                                                  const float* __restrict__ h,
                                                  const float* __restrict__ bias,
                                                  const float* __restrict__ other,
                                                  float* __restrict__ outf,
                                                  ushort4* __restrict__ out16, int N) {
  const int d = (int)((blockIdx.x * (size_t)blockDim.x + threadIdx.x) >> 6);
  const int lane = threadIdx.x & 63;
  if (d >= N) return;
  const float ad = adst[d];
  const float4* __restrict__ h4 = (const float4*)h;

  float e = asrc[d] + ad;
  e = e > 0.f ? e : NEG_SLOPE * e;
  float wgt = expf(e);
  float den = wgt;
  float4 hv = h4[(size_t)d * 64 + lane];
  float4 acc = make_float4(wgt * hv.x, wgt * hv.y, wgt * hv.z, wgt * hv.w);

  const int mend = rs[d + 1];
  for (int m = rs[d]; m < mend; ++m) {
    const int s = csr[m];
    float e2 = asrc[s] + ad;
    e2 = e2 > 0.f ? e2 : NEG_SLOPE * e2;
    const float w2 = expf(e2);
    den += w2;
    const float4 hv2 = h4[(size_t)s * 64 + lane];
    acc.x += w2 * hv2.x;
    acc.y += w2 * hv2.y;
    acc.z += w2 * hv2.z;
    acc.w += w2 * hv2.w;
  }
  const float inv = 1.f / den;
  const float4 b4 = ((const float4*)bias)[lane];
  float v[4] = {acc.x * inv + b4.x, acc.y * inv + b4.y,
                acc.z * inv + b4.z, acc.w * inv + b4.w};
#pragma unroll
  for (int j = 0; j < 4; ++j) v[j] = v[j] > 0.f ? v[j] : (expf(v[j]) - 1.f);
  if (EPI == 2) {
    const float4 ov = ((const float4*)other)[(size_t)d * 64 + lane];
    const float ovv[4] = {ov.x, ov.y, ov.z, ov.w};
    ushort4 pk;
    unsigned short* ps = (unsigned short*)&pk;
#pragma unroll
    for (int j = 0; j < 4; ++j) ps[j] = f2bf(0.5f * v[j] + 0.5f * ovv[j]);
    out16[(size_t)d * 64 + lane] = pk;
  } else {
    ((float4*)outf)[(size_t)d * 64 + lane] = make_float4(v[0], v[1], v[2], v[3]);
  }
}

// ---------------- fused CSR aggregation, H=64 -> d_out ----------------
__global__ __launch_bounds__(256) void agg_csr64(const int* __restrict__ rs,
                                                 const int* __restrict__ csr,
                                                 const float* __restrict__ asrc,
                                                 const float* __restrict__ adst,
                                                 const float* __restrict__ h,
                                                 const float* __restrict__ bias,
                                                 float* __restrict__ outb, int N) {
  const int d = (int)((blockIdx.x * (size_t)blockDim.x + threadIdx.x) >> 6);
  const int lane = threadIdx.x & 63;
  if (d >= N) return;
  const float ad = adst[d];

  float e = asrc[d] + ad;
  e = e > 0.f ? e : NEG_SLOPE * e;
  float wgt = expf(e);
  float den = wgt;
  float acc = wgt * h[(size_t)d * 64 + lane];

  const int mend = rs[d + 1];
  for (int m = rs[d]; m < mend; ++m) {
    const int s = csr[m];
    float e2 = asrc[s] + ad;
    e2 = e2 > 0.f ? e2 : NEG_SLOPE * e2;
    const float w2 = expf(e2);
    den += w2;
    acc += w2 * h[(size_t)s * 64 + lane];
  }
  outb[(size_t)d * 64 + lane] = acc / den + bias[lane];
}

extern "C" void kernel_launch(void* const* d_in, const int* in_sizes, int n_in,
                              void* d_out, int out_size, void* d_ws, size_t ws_size,
                              hipStream_t stream) {
  const float* x        = (const float*)d_in[0];
  const int*   ei_sp    = (const int*)d_in[1];
  const int*   ei_gs    = (const int*)d_in[2];
  const float* W_sp     = (const float*)d_in[3];
  const float* a_src_sp = (const float*)d_in[4];
  const float* a_dst_sp = (const float*)d_in[5];
  const float* b_sp     = (const float*)d_in[6];
  const float* W_gs     = (const float*)d_in[7];
  const float* a_src_gs = (const float*)d_in[8];
  const float* a_dst_gs = (const float*)d_in[9];
  const float* b_gs     = (const float*)d_in[10];
  const float* W_fu     = (const float*)d_in[11];
  const float* a_src_fu = (const float*)d_in[12];
  const float* a_dst_fu = (const float*)d_in[13];
  const float* b_fu     = (const float*)d_in[14];
  float* out = (float*)d_out;

  const int N = in_sizes[0] / 512;
  const int E = in_sizes[1] / 2;
  const int nb = (N + 255) / 256;

  // workspace layout (weights first: keeps 16B alignment for gload_lds sources)
  unsigned short* wt_sp = (unsigned short*)d_ws;    // 256*512
  unsigned short* wt_gs = wt_sp + 256 * 512;        // 256*512
  unsigned short* wt_fu = wt_gs + 256 * 512;        // 64*256
  float* R    = (float*)(wt_fu + 64 * 256);         // N*256 floats: x_bf16 -> B3 fp32
  float* B1f  = R + (size_t)N * 256;                // h_sp fp32 -> h_fused bf16
  float* B2f  = B1f + (size_t)N * 256;              // h_gs fp32 -> h_fu fp32 (N*64)
  float* asrc = B2f + (size_t)N * 256;
  float* adst = asrc + N;
  int* rs_sp  = (int*)(adst + N);
  int* rs_gs  = rs_sp + (N + 1);
  int* csr_sp = rs_gs + (N + 1);
  int* csr_gs = csr_sp + E;
  int* deg    = csr_gs + E;
  int* parts  = deg + N;

  unsigned short* xb  = (unsigned short*)R;    // [N][512] bf16
  float*          B3  = R;                     // [N][256] fp32 (after xb dead)
  unsigned short* hfb = (unsigned short*)B1f;  // [N][256] bf16 h_fused
  float*          hfu = B2f;                   // [N][64] fp32

  const int BLK = 256;
  const int eGrid = (E + BLK - 1) / BLK;
  const int nodeWaveGrid = (N + 3) / 4;
  const dim3 g1((N + 127) / 128, 2);   // layer-1 GEMMs: Nc=256
  const dim3 g2((N + 127) / 128, 1);   // fusion GEMM: Nc=64

  // ---- CSR builds ----
  hipMemsetAsync(deg, 0, (size_t)N * 4, stream);
  hist_dst<<<eGrid, BLK, 0, stream>>>(ei_sp + E, deg, E);
  scan1<<<nb, BLK, 0, stream>>>(deg, rs_sp, parts, N);
  scan2<<<1, 512, 0, stream>>>(parts, nb);
  scan3<<<nb, BLK, 0, stream>>>(rs_sp, parts, N, E);
  hipMemsetAsync(deg, 0, (size_t)N * 4, stream);
  scatter_src<<<eGrid, BLK, 0, stream>>>(ei_sp, rs_sp, deg, csr_sp, E);

  hipMemsetAsync(deg, 0, (size_t)N * 4, stream);
  hist_dst<<<eGrid, BLK, 0, stream>>>(ei_gs + E, deg, E);
  scan1<<<nb, BLK, 0, stream>>>(deg, rs_gs, parts, N);
  scan2<<<1, 512, 0, stream>>>(parts, nb);
  scan3<<<nb, BLK, 0, stream>>>(rs_gs, parts, N, E);
  hipMemsetAsync(deg, 0, (size_t)N * 4, stream);
  scatter_src<<<eGrid, BLK, 0, stream>>>(ei_gs, rs_gs, deg, csr_gs, E);

  // ---- conversions ----
  conv_bf16<<<2048, BLK, 0, stream>>>((const float4*)x, (ushort4*)xb, (size_t)N * 128);
  wt_bf16<<<(512 * 256 + 255) / 256, BLK, 0, stream>>>(W_sp, wt_sp, 512, 256);
  wt_bf16<<<(512 * 256 + 255) / 256, BLK, 0, stream>>>(W_gs, wt_gs, 512, 256);
  wt_bf16<<<(256 * 64 + 255) / 256, BLK, 0, stream>>>(W_fu, wt_fu, 256, 64);

  // ---- layer-1 GEMMs (bf16 MFMA) ----
  gemm_bf16_nt<128><<<g1, BLK, 0, stream>>>(xb, wt_sp, B1f, N, 256, 512);
  gemm_bf16_nt<128><<<g1, BLK, 0, stream>>>(xb, wt_gs, B2f, N, 256, 512);

  // ---- spatial conv -> B3 (R region; xb dead after GEMMs) ----
  alpha256<<<nodeWaveGrid, BLK, 0, stream>>>(B1f, a_src_sp, a_dst_sp, asrc, adst, N);
  agg_csr256<1><<<nodeWaveGrid, BLK, 0, stream>>>(rs_sp, csr_sp, asrc, adst, B1f, b_sp,
                                                  nullptr, B3, nullptr, N);

  // ---- gene conv + blend -> h_fused bf16 (B1f region; h_sp dead) ----
  alpha256<<<nodeWaveGrid, BLK, 0, stream>>>(B2f, a_src_gs, a_dst_gs, asrc, adst, N);
  agg_csr256<2><<<nodeWaveGrid, BLK, 0, stream>>>(rs_gs, csr_gs, asrc, adst, B2f, b_gs,
                                                  B3, nullptr, (ushort4*)hfb, N);

  // ---- fusion conv ----
  gemm_bf16_nt<64><<<g2, BLK, 0, stream>>>(hfb, wt_fu, hfu, N, 64, 256);
  alpha64<<<nodeWaveGrid, BLK, 0, stream>>>(hfu, a_src_fu, a_dst_fu, asrc, adst, N);
  agg_csr64<<<nodeWaveGrid, BLK, 0, stream>>>(rs_sp, csr_sp, asrc, adst, hfu, b_fu, out, N);
}

// Round 4
// 710.631 us; speedup vs baseline: 11.0092x; 1.1762x over previous
//
#include <hip/hip_runtime.h>
#include <math.h>

// Round 4: all intermediate h matrices stored as bf16 (GEMM writes bf16, alpha +
// CSR-gather aggregation read bf16, accumulate fp32). Halves the dominant gather
// traffic in agg_csr256. CSR build fused into dual-graph kernels (6 launches).

#define NEG_SLOPE 0.2f

typedef __attribute__((ext_vector_type(8))) short bf16x8;
typedef __attribute__((ext_vector_type(4))) float f32x4;

__device__ __forceinline__ unsigned short f2bf(float f) {
  unsigned int u = __float_as_uint(f);
  u = (u + 0x7FFFu + ((u >> 16) & 1u)) >> 16;  // RNE
  return (unsigned short)u;
}
__device__ __forceinline__ float bf2f(unsigned short u) {
  return __uint_as_float((unsigned int)u << 16);
}

#define GLOAD16(g, l)                                                   \
  __builtin_amdgcn_global_load_lds(                                     \
      (const __attribute__((address_space(1))) void*)(g),               \
      (__attribute__((address_space(3))) void*)(l), 16, 0, 0)

// ---------------- conversions ----------------
__global__ __launch_bounds__(256) void conv_bf16(const float4* __restrict__ in,
                                                 ushort4* __restrict__ out,
                                                 size_t n4) {
  const size_t stride = (size_t)gridDim.x * blockDim.x;
  for (size_t i = blockIdx.x * (size_t)blockDim.x + threadIdx.x; i < n4; i += stride) {
    const float4 v = in[i];
    ushort4 o;
    o.x = f2bf(v.x); o.y = f2bf(v.y); o.z = f2bf(v.z); o.w = f2bf(v.w);
    out[i] = o;
  }
}

// W[K][Nc] fp32 -> Wt[Nc][K] bf16
__global__ __launch_bounds__(256) void wt_bf16(const float* __restrict__ W,
                                               unsigned short* __restrict__ Wt,
                                               int K, int Nc) {
  const int i = blockIdx.x * 256 + threadIdx.x;
  if (i < K * Nc) {
    const int k = i / Nc, n = i % Nc;
    Wt[n * K + k] = f2bf(W[i]);
  }
}

// ---------------- CSR build (both graphs per launch) ----------------
__global__ __launch_bounds__(256) void hist2(const int* __restrict__ dst_sp,
                                             const int* __restrict__ dst_gs,
                                             int* __restrict__ deg_sp,
                                             int* __restrict__ deg_gs, int E) {
  const int m = blockIdx.x * 256 + threadIdx.x;
  if (m < E) {
    atomicAdd(&deg_sp[dst_sp[m]], 1);
    atomicAdd(&deg_gs[dst_gs[m]], 1);
  }
}

__global__ __launch_bounds__(256) void scan1_2(const int* __restrict__ deg_sp,
                                               const int* __restrict__ deg_gs,
                                               int* __restrict__ rs_sp,
                                               int* __restrict__ rs_gs,
                                               int* __restrict__ parts2, int N) {
  __shared__ int sm[256];
  const int* deg = blockIdx.y ? deg_gs : deg_sp;
  int* rs = blockIdx.y ? rs_gs : rs_sp;
  int* parts = parts2 + blockIdx.y * 512;
  const int i = blockIdx.x * 256 + threadIdx.x;
  const int v = (i < N) ? deg[i] : 0;
  sm[threadIdx.x] = v;
  __syncthreads();
  for (int off = 1; off < 256; off <<= 1) {
    const int x = (threadIdx.x >= off) ? sm[threadIdx.x - off] : 0;
    __syncthreads();
    sm[threadIdx.x] += x;
    __syncthreads();
  }
  if (i < N) rs[i] = sm[threadIdx.x] - v;
  if (threadIdx.x == 255) parts[blockIdx.x] = sm[255];
}

__global__ __launch_bounds__(512) void scan2_2(int* __restrict__ parts2, int nb) {
  __shared__ int sm[512];
  int* parts = parts2 + blockIdx.x * 512;
  const int t = threadIdx.x;
  const int v = (t < nb) ? parts[t] : 0;
  sm[t] = v;
  __syncthreads();
  for (int off = 1; off < 512; off <<= 1) {
    const int x = (t >= off) ? sm[t - off] : 0;
    __syncthreads();
    sm[t] += x;
    __syncthreads();
  }
  if (t < nb) parts[t] = sm[t] - v;
}

__global__ __launch_bounds__(256) void scan3_2(int* __restrict__ rs_sp,
                                               int* __restrict__ rs_gs,
                                               const int* __restrict__ parts2,
                                               int N, int E) {
  int* rs = blockIdx.y ? rs_gs : rs_sp;
  const int* parts = parts2 + blockIdx.y * 512;
  const int i = blockIdx.x * 256 + threadIdx.x;
  if (i < N) rs[i] += parts[blockIdx.x];
  if (i == 0) rs[N] = E;
}

__global__ __launch_bounds__(256) void scatter2(const int* __restrict__ ei_sp,
                                                const int* __restrict__ ei_gs,
                                                const int* __restrict__ rs_sp,
                                                const int* __restrict__ rs_gs,
                                                int* __restrict__ cur_sp,
                                                int* __restrict__ cur_gs,
                                                int* __restrict__ csr_sp,
                                                int* __restrict__ csr_gs, int E) {
  const int m = blockIdx.x * 256 + threadIdx.x;
  if (m >= E) return;
  {
    const int s = ei_sp[m], d = ei_sp[E + m];
    csr_sp[rs_sp[d] + atomicAdd(&cur_sp[d], 1)] = s;
  }
  {
    const int s = ei_gs[m], d = ei_gs[E + m];
    csr_gs[rs_gs[d] + atomicAdd(&cur_gs[d], 1)] = s;
  }
}

// ---------------- bf16 MFMA GEMM (NT), bf16 output ----------------
// C[M][Nc] = A[M][K] * Bt[Nc][K]^T ; BM=128, BK=64, 256 threads (4 waves)
template <int BN>
__global__ __launch_bounds__(256) void gemm_bf16_nt(const unsigned short* __restrict__ A,
                                                    const unsigned short* __restrict__ Bt,
                                                    unsigned short* __restrict__ C,
                                                    int M, int Nc, int K) {
  constexpr int BM = 128, BK = 64;
  constexpr int NW = BN / 64;
  constexpr int MW = 4 / NW;
  constexpr int MF = (BM / MW) / 16;
  constexpr int NF = 4;
  constexpr int ACW = (BM * BK * 2 / 1024) / 4;
  constexpr int BCW = (BN * BK * 2 / 1024) / 4;
  __shared__ unsigned short sA[BM * BK];
  __shared__ unsigned short sB[BN * BK];
  const int tid = threadIdx.x;
  const int w = tid >> 6, l = tid & 63;
  const int wr = w / NW, wc = w % NW;
  const int bm = blockIdx.x * BM;
  const int bn = blockIdx.y * BN;
  const int crow = l >> 3;
  const int cbyte = (l & 7) * 16;

  f32x4 acc[MF][NF] = {};
  for (int k0 = 0; k0 < K; k0 += BK) {
    __syncthreads();
#pragma unroll
    for (int c = 0; c < ACW; ++c) {
      const int ch = w * ACW + c;
      int row = bm + ch * 8 + crow;
      row = row < M ? row : M - 1;
      const char* g = (const char*)A + (size_t)row * K * 2 + (size_t)k0 * 2 + cbyte;
      GLOAD16(g, ((char*)sA) + ch * 1024);
    }
#pragma unroll
    for (int c = 0; c < BCW; ++c) {
      const int ch = w * BCW + c;
      const int row = bn + ch * 8 + crow;
      const char* g = (const char*)Bt + (size_t)row * K * 2 + (size_t)k0 * 2 + cbyte;
      GLOAD16(g, ((char*)sB) + ch * 1024);
    }
    __syncthreads();
#pragma unroll
    for (int ks = 0; ks < 2; ++ks) {
      bf16x8 af[MF], bfr[NF];
#pragma unroll
      for (int m = 0; m < MF; ++m) {
        const int r = wr * (BM / MW) + m * 16 + (l & 15);
        af[m] = *(const bf16x8*)&sA[r * BK + ks * 32 + (l >> 4) * 8];
      }
#pragma unroll
      for (int n = 0; n < NF; ++n) {
        const int r = wc * 64 + n * 16 + (l & 15);
        bfr[n] = *(const bf16x8*)&sB[r * BK + ks * 32 + (l >> 4) * 8];
      }
#pragma unroll
      for (int m = 0; m < MF; ++m)
#pragma unroll
        for (int n = 0; n < NF; ++n)
          acc[m][n] = __builtin_amdgcn_mfma_f32_16x16x32_bf16(af[m], bfr[n], acc[m][n], 0, 0, 0);
    }
  }
#pragma unroll
  for (int m = 0; m < MF; ++m) {
#pragma unroll
    for (int r = 0; r < 4; ++r) {
      const int row = bm + wr * (BM / MW) + m * 16 + (l >> 4) * 4 + r;
      if (row < M) {
#pragma unroll
        for (int n = 0; n < NF; ++n)
          C[(size_t)row * Nc + bn + wc * 64 + n * 16 + (l & 15)] = f2bf(acc[m][n][r]);
      }
    }
  }
}

// ---------------- alpha dots (bf16 h) ----------------
__global__ __launch_bounds__(256) void alpha256(const ushort4* __restrict__ h,
                                                const float* __restrict__ a_src,
                                                const float* __restrict__ a_dst,
                                                float* __restrict__ asrc,
                                                float* __restrict__ adst, int N) {
  const int wave = (int)((blockIdx.x * (size_t)blockDim.x + threadIdx.x) >> 6);
  const int lane = threadIdx.x & 63;
  if (wave >= N) return;
  const ushort4 hv = h[(size_t)wave * 64 + lane];
  const float4 s4 = ((const float4*)a_src)[lane];
  const float4 d4 = ((const float4*)a_dst)[lane];
  const float h0 = bf2f(hv.x), h1 = bf2f(hv.y), h2 = bf2f(hv.z), h3 = bf2f(hv.w);
  float ps = h0 * s4.x + h1 * s4.y + h2 * s4.z + h3 * s4.w;
  float pd = h0 * d4.x + h1 * d4.y + h2 * d4.z + h3 * d4.w;
#pragma unroll
  for (int off = 32; off; off >>= 1) {
    ps += __shfl_down(ps, off);
    pd += __shfl_down(pd, off);
  }
  if (lane == 0) { asrc[wave] = ps; adst[wave] = pd; }
}

__global__ __launch_bounds__(256) void alpha64(const unsigned short* __restrict__ h,
                                               const float* __restrict__ a_src,
                                               const float* __restrict__ a_dst,
                                               float* __restrict__ asrc,
                                               float* __restrict__ adst, int N) {
  const int wave = (int)((blockIdx.x * (size_t)blockDim.x + threadIdx.x) >> 6);
  const int lane = threadIdx.x & 63;
  if (wave >= N) return;
  const float hv = bf2f(h[(size_t)wave * 64 + lane]);
  float ps = hv * a_src[lane];
  float pd = hv * a_dst[lane];
#pragma unroll
  for (int off = 32; off; off >>= 1) {
    ps += __shfl_down(ps, off);
    pd += __shfl_down(pd, off);
  }
  if (lane == 0) { asrc[wave] = ps; adst[wave] = pd; }
}

// ---------------- fused CSR aggregation, H=256, bf16 h ----------------
// EPI 1: out16 = bf16(elu(agg + bias))
// EPI 2: out16 = bf16(0.5*elu(agg + bias) + 0.5*other16)
template <int EPI>
__global__ __launch_bounds__(256) void agg_csr256(const int* __restrict__ rs,
                                                  const int* __restrict__ csr,
                                                  const float* __restrict__ asrc,
                                                  const float* __restrict__ adst,
                                                  const ushort4* __restrict__ h4,
                                                  const float* __restrict__ bias,
                                                  const ushort4* __restrict__ other16,
                                                  ushort4* __restrict__ out16, int N) {
  const int d = (int)((blockIdx.x * (size_t)blockDim.x + threadIdx.x) >> 6);
  const int lane = threadIdx.x & 63;
  if (d >= N) return;
  const float ad = adst[d];

  float e = asrc[d] + ad;
  e = e > 0.f ? e : NEG_SLOPE * e;
  float wgt = expf(e);
  float den = wgt;
  const ushort4 hv = h4[(size_t)d * 64 + lane];
  float4 acc = make_float4(wgt * bf2f(hv.x), wgt * bf2f(hv.y),
                           wgt * bf2f(hv.z), wgt * bf2f(hv.w));

  const int mend = rs[d + 1];
  for (int m = rs[d]; m < mend; ++m) {
    const int s = csr[m];
    float e2 = asrc[s] + ad;
    e2 = e2 > 0.f ? e2 : NEG_SLOPE * e2;
    const float w2 = expf(e2);
    den += w2;
    const ushort4 hv2 = h4[(size_t)s * 64 + lane];
    acc.x += w2 * bf2f(hv2.x);
    acc.y += w2 * bf2f(hv2.y);
    acc.z += w2 * bf2f(hv2.z);
    acc.w += w2 * bf2f(hv2.w);
  }
  const float inv = 1.f / den;
  const float4 b4 = ((const float4*)bias)[lane];
  float v[4] = {acc.x * inv + b4.x, acc.y * inv + b4.y,
                acc.z * inv + b4.z, acc.w * inv + b4.w};
#pragma unroll
  for (int j = 0; j < 4; ++j) v[j] = v[j] > 0.f ? v[j] : (expf(v[j]) - 1.f);
  ushort4 pk;
  if (EPI == 2) {
    const ushort4 ov = other16[(size_t)d * 64 + lane];
    pk.x = f2bf(0.5f * v[0] + 0.5f * bf2f(ov.x));
    pk.y = f2bf(0.5f * v[1] + 0.5f * bf2f(ov.y));
    pk.z = f2bf(0.5f * v[2] + 0.5f * bf2f(ov.z));
    pk.w = f2bf(0.5f * v[3] + 0.5f * bf2f(ov.w));
  } else {
    pk.x = f2bf(v[0]); pk.y = f2bf(v[1]); pk.z = f2bf(v[2]); pk.w = f2bf(v[3]);
  }
  out16[(size_t)d * 64 + lane] = pk;
}

// ---------------- fused CSR aggregation, H=64, bf16 h -> fp32 d_out ----------------
__global__ __launch_bounds__(256) void agg_csr64(const int* __restrict__ rs,
                                                 const int* __restrict__ csr,
                                                 const float* __restrict__ asrc,
                                                 const float* __restrict__ adst,
                                                 const unsigned short* __restrict__ h,
                                                 const float* __restrict__ bias,
                                                 float* __restrict__ outb, int N) {
  const int d = (int)((blockIdx.x * (size_t)blockDim.x + threadIdx.x) >> 6);
  const int lane = threadIdx.x & 63;
  if (d >= N) return;
  const float ad = adst[d];

  float e = asrc[d] + ad;
  e = e > 0.f ? e : NEG_SLOPE * e;
  float wgt = expf(e);
  float den = wgt;
  float acc = wgt * bf2f(h[(size_t)d * 64 + lane]);

  const int mend = rs[d + 1];
  for (int m = rs[d]; m < mend; ++m) {
    const int s = csr[m];
    float e2 = asrc[s] + ad;
    e2 = e2 > 0.f ? e2 : NEG_SLOPE * e2;
    const float w2 = expf(e2);
    den += w2;
    acc += w2 * bf2f(h[(size_t)s * 64 + lane]);
  }
  outb[(size_t)d * 64 + lane] = acc / den + bias[lane];
}

extern "C" void kernel_launch(void* const* d_in, const int* in_sizes, int n_in,
                              void* d_out, int out_size, void* d_ws, size_t ws_size,
                              hipStream_t stream) {
  const float* x        = (const float*)d_in[0];
  const int*   ei_sp    = (const int*)d_in[1];
  const int*   ei_gs    = (const int*)d_in[2];
  const float* W_sp     = (const float*)d_in[3];
  const float* a_src_sp = (const float*)d_in[4];
  const float* a_dst_sp = (const float*)d_in[5];
  const float* b_sp     = (const float*)d_in[6];
  const float* W_gs     = (const float*)d_in[7];
  const float* a_src_gs = (const float*)d_in[8];
  const float* a_dst_gs = (const float*)d_in[9];
  const float* b_gs     = (const float*)d_in[10];
  const float* W_fu     = (const float*)d_in[11];
  const float* a_src_fu = (const float*)d_in[12];
  const float* a_dst_fu = (const float*)d_in[13];
  const float* b_fu     = (const float*)d_in[14];
  float* out = (float*)d_out;

  const int N = in_sizes[0] / 512;
  const int E = in_sizes[1] / 2;
  const int nb = (N + 255) / 256;

  // ---- workspace layout ----
  unsigned short* wt_sp = (unsigned short*)d_ws;     // 256*512
  unsigned short* wt_gs = wt_sp + 256 * 512;         // 256*512
  unsigned short* wt_fu = wt_gs + 256 * 512;         // 64*256
  unsigned short* xb    = wt_fu + 64 * 256;          // N*512 bf16 (later B3 + h_fused)
  unsigned short* hb_sp = xb + (size_t)N * 512;      // N*256 bf16 (later h_fu N*64)
  unsigned short* hb_gs = hb_sp + (size_t)N * 256;   // N*256 bf16
  float* asrc = (float*)(hb_gs + (size_t)N * 256);   // N
  float* adst = asrc + N;                            // N
  int* rs_sp  = (int*)(adst + N);                    // N+1
  int* rs_gs  = rs_sp + (N + 1);                     // N+1
  int* csr_sp = rs_gs + (N + 1);                     // E
  int* csr_gs = csr_sp + E;                          // E
  int* deg_sp = csr_gs + E;                          // N (cursor on reuse)
  int* deg_gs = deg_sp + N;                          // N (adjacent: single memset)
  int* parts2 = deg_gs + N;                          // 2*512

  unsigned short* B3  = xb;                          // [N][256] bf16 (xb dead)
  unsigned short* hfb = xb + (size_t)N * 256;        // [N][256] bf16 h_fused
  unsigned short* hfu = hb_sp;                       // [N][64] bf16 (hb_sp dead)

  const int BLK = 256;
  const int eGrid = (E + BLK - 1) / BLK;
  const int nodeWaveGrid = (N + 3) / 4;
  const dim3 g1((N + 127) / 128, 2);
  const dim3 g2((N + 127) / 128, 1);

  // ---- CSR builds (both graphs) ----
  hipMemsetAsync(deg_sp, 0, (size_t)2 * N * 4, stream);
  hist2<<<eGrid, BLK, 0, stream>>>(ei_sp + E, ei_gs + E, deg_sp, deg_gs, E);
  scan1_2<<<dim3(nb, 2), BLK, 0, stream>>>(deg_sp, deg_gs, rs_sp, rs_gs, parts2, N);
  scan2_2<<<2, 512, 0, stream>>>(parts2, nb);
  scan3_2<<<dim3(nb, 2), BLK, 0, stream>>>(rs_sp, rs_gs, parts2, N, E);
  hipMemsetAsync(deg_sp, 0, (size_t)2 * N * 4, stream);
  scatter2<<<eGrid, BLK, 0, stream>>>(ei_sp, ei_gs, rs_sp, rs_gs, deg_sp, deg_gs,
                                      csr_sp, csr_gs, E);

  // ---- conversions ----
  conv_bf16<<<2048, BLK, 0, stream>>>((const float4*)x, (ushort4*)xb, (size_t)N * 128);
  wt_bf16<<<(512 * 256 + 255) / 256, BLK, 0, stream>>>(W_sp, wt_sp, 512, 256);
  wt_bf16<<<(512 * 256 + 255) / 256, BLK, 0, stream>>>(W_gs, wt_gs, 512, 256);
  wt_bf16<<<(256 * 64 + 255) / 256, BLK, 0, stream>>>(W_fu, wt_fu, 256, 64);

  // ---- layer-1 GEMMs (bf16 in/out) ----
  gemm_bf16_nt<128><<<g1, BLK, 0, stream>>>(xb, wt_sp, hb_sp, N, 256, 512);
  gemm_bf16_nt<128><<<g1, BLK, 0, stream>>>(xb, wt_gs, hb_gs, N, 256, 512);

  // ---- spatial conv -> B3 = bf16(elu(agg+b_sp)) (xb region; xb dead) ----
  alpha256<<<nodeWaveGrid, BLK, 0, stream>>>((const ushort4*)hb_sp, a_src_sp, a_dst_sp,
                                             asrc, adst, N);
  agg_csr256<1><<<nodeWaveGrid, BLK, 0, stream>>>(rs_sp, csr_sp, asrc, adst,
                                                  (const ushort4*)hb_sp, b_sp,
                                                  nullptr, (ushort4*)B3, N);

  // ---- gene conv + blend -> h_fused bf16 ----
  alpha256<<<nodeWaveGrid, BLK, 0, stream>>>((const ushort4*)hb_gs, a_src_gs, a_dst_gs,
                                             asrc, adst, N);
  agg_csr256<2><<<nodeWaveGrid, BLK, 0, stream>>>(rs_gs, csr_gs, asrc, adst,
                                                  (const ushort4*)hb_gs, b_gs,
                                                  (const ushort4*)B3, (ushort4*)hfb, N);

  // ---- fusion conv (256->64, spatial graph) ----
  gemm_bf16_nt<64><<<g2, BLK, 0, stream>>>(hfb, wt_fu, hfu, N, 64, 256);
  alpha64<<<nodeWaveGrid, BLK, 0, stream>>>(hfu, a_src_fu, a_dst_fu, asrc, adst, N);
  agg_csr64<<<nodeWaveGrid, BLK, 0, stream>>>(rs_sp, csr_sp, asrc, adst, hfu, b_fu,
                                              out, N);
}

// Round 5
// 591.878 us; speedup vs baseline: 13.2180x; 1.2006x over previous
//
#include <hip/hip_runtime.h>
#include <math.h>

// Round 5: agg kernels restructured — lane-parallel softmax weights (one exp per
// edge, not 64), readlane-broadcast gather loop unrolled x4 for MLP. Everything
// else unchanged from round 4 (bf16 h everywhere, fused CSR build, MFMA GEMMs).

#define NEG_SLOPE 0.2f

typedef __attribute__((ext_vector_type(8))) short bf16x8;
typedef __attribute__((ext_vector_type(4))) float f32x4;

__device__ __forceinline__ unsigned short f2bf(float f) {
  unsigned int u = __float_as_uint(f);
  u = (u + 0x7FFFu + ((u >> 16) & 1u)) >> 16;  // RNE
  return (unsigned short)u;
}
__device__ __forceinline__ float bf2f(unsigned short u) {
  return __uint_as_float((unsigned int)u << 16);
}
__device__ __forceinline__ int rl_i(int v, int l) {
  return __builtin_amdgcn_readlane(v, l);
}
__device__ __forceinline__ float rl_f(float v, int l) {
  return __uint_as_float(__builtin_amdgcn_readlane(__float_as_uint(v), l));
}

#define GLOAD16(g, l)                                                   \
  __builtin_amdgcn_global_load_lds(                                     \
      (const __attribute__((address_space(1))) void*)(g),               \
      (__attribute__((address_space(3))) void*)(l), 16, 0, 0)

// ---------------- conversions ----------------
__global__ __launch_bounds__(256) void conv_bf16(const float4* __restrict__ in,
                                                 ushort4* __restrict__ out,
                                                 size_t n4) {
  const size_t stride = (size_t)gridDim.x * blockDim.x;
  for (size_t i = blockIdx.x * (size_t)blockDim.x + threadIdx.x; i < n4; i += stride) {
    const float4 v = in[i];
    ushort4 o;
    o.x = f2bf(v.x); o.y = f2bf(v.y); o.z = f2bf(v.z); o.w = f2bf(v.w);
    out[i] = o;
  }
}

// W[K][Nc] fp32 -> Wt[Nc][K] bf16
__global__ __launch_bounds__(256) void wt_bf16(const float* __restrict__ W,
                                               unsigned short* __restrict__ Wt,
                                               int K, int Nc) {
  const int i = blockIdx.x * 256 + threadIdx.x;
  if (i < K * Nc) {
    const int k = i / Nc, n = i % Nc;
    Wt[n * K + k] = f2bf(W[i]);
  }
}

// ---------------- CSR build (both graphs per launch) ----------------
__global__ __launch_bounds__(256) void hist2(const int* __restrict__ dst_sp,
                                             const int* __restrict__ dst_gs,
                                             int* __restrict__ deg_sp,
                                             int* __restrict__ deg_gs, int E) {
  const int m = blockIdx.x * 256 + threadIdx.x;
  if (m < E) {
    atomicAdd(&deg_sp[dst_sp[m]], 1);
    atomicAdd(&deg_gs[dst_gs[m]], 1);
  }
}

__global__ __launch_bounds__(256) void scan1_2(const int* __restrict__ deg_sp,
                                               const int* __restrict__ deg_gs,
                                               int* __restrict__ rs_sp,
                                               int* __restrict__ rs_gs,
                                               int* __restrict__ parts2, int N) {
  __shared__ int sm[256];
  const int* deg = blockIdx.y ? deg_gs : deg_sp;
  int* rs = blockIdx.y ? rs_gs : rs_sp;
  int* parts = parts2 + blockIdx.y * 512;
  const int i = blockIdx.x * 256 + threadIdx.x;
  const int v = (i < N) ? deg[i] : 0;
  sm[threadIdx.x] = v;
  __syncthreads();
  for (int off = 1; off < 256; off <<= 1) {
    const int x = (threadIdx.x >= off) ? sm[threadIdx.x - off] : 0;
    __syncthreads();
    sm[threadIdx.x] += x;
    __syncthreads();
  }
  if (i < N) rs[i] = sm[threadIdx.x] - v;
  if (threadIdx.x == 255) parts[blockIdx.x] = sm[255];
}

__global__ __launch_bounds__(512) void scan2_2(int* __restrict__ parts2, int nb) {
  __shared__ int sm[512];
  int* parts = parts2 + blockIdx.x * 512;
  const int t = threadIdx.x;
  const int v = (t < nb) ? parts[t] : 0;
  sm[t] = v;
  __syncthreads();
  for (int off = 1; off < 512; off <<= 1) {
    const int x = (t >= off) ? sm[t - off] : 0;
    __syncthreads();
    sm[t] += x;
    __syncthreads();
  }
  if (t < nb) parts[t] = sm[t] - v;
}

__global__ __launch_bounds__(256) void scan3_2(int* __restrict__ rs_sp,
                                               int* __restrict__ rs_gs,
                                               const int* __restrict__ parts2,
                                               int N, int E) {
  int* rs = blockIdx.y ? rs_gs : rs_sp;
  const int* parts = parts2 + blockIdx.y * 512;
  const int i = blockIdx.x * 256 + threadIdx.x;
  if (i < N) rs[i] += parts[blockIdx.x];
  if (i == 0) rs[N] = E;
}

__global__ __launch_bounds__(256) void scatter2(const int* __restrict__ ei_sp,
                                                const int* __restrict__ ei_gs,
                                                const int* __restrict__ rs_sp,
                                                const int* __restrict__ rs_gs,
                                                int* __restrict__ cur_sp,
                                                int* __restrict__ cur_gs,
                                                int* __restrict__ csr_sp,
                                                int* __restrict__ csr_gs, int E) {
  const int m = blockIdx.x * 256 + threadIdx.x;
  if (m >= E) return;
  {
    const int s = ei_sp[m], d = ei_sp[E + m];
    csr_sp[rs_sp[d] + atomicAdd(&cur_sp[d], 1)] = s;
  }
  {
    const int s = ei_gs[m], d = ei_gs[E + m];
    csr_gs[rs_gs[d] + atomicAdd(&cur_gs[d], 1)] = s;
  }
}

// ---------------- bf16 MFMA GEMM (NT), bf16 output ----------------
template <int BN>
__global__ __launch_bounds__(256) void gemm_bf16_nt(const unsigned short* __restrict__ A,
                                                    const unsigned short* __restrict__ Bt,
                                                    unsigned short* __restrict__ C,
                                                    int M, int Nc, int K) {
  constexpr int BM = 128, BK = 64;
  constexpr int NW = BN / 64;
  constexpr int MW = 4 / NW;
  constexpr int MF = (BM / MW) / 16;
  constexpr int NF = 4;
  constexpr int ACW = (BM * BK * 2 / 1024) / 4;
  constexpr int BCW = (BN * BK * 2 / 1024) / 4;
  __shared__ unsigned short sA[BM * BK];
  __shared__ unsigned short sB[BN * BK];
  const int tid = threadIdx.x;
  const int w = tid >> 6, l = tid & 63;
  const int wr = w / NW, wc = w % NW;
  const int bm = blockIdx.x * BM;
  const int bn = blockIdx.y * BN;
  const int crow = l >> 3;
  const int cbyte = (l & 7) * 16;

  f32x4 acc[MF][NF] = {};
  for (int k0 = 0; k0 < K; k0 += BK) {
    __syncthreads();
#pragma unroll
    for (int c = 0; c < ACW; ++c) {
      const int ch = w * ACW + c;
      int row = bm + ch * 8 + crow;
      row = row < M ? row : M - 1;
      const char* g = (const char*)A + (size_t)row * K * 2 + (size_t)k0 * 2 + cbyte;
      GLOAD16(g, ((char*)sA) + ch * 1024);
    }
#pragma unroll
    for (int c = 0; c < BCW; ++c) {
      const int ch = w * BCW + c;
      const int row = bn + ch * 8 + crow;
      const char* g = (const char*)Bt + (size_t)row * K * 2 + (size_t)k0 * 2 + cbyte;
      GLOAD16(g, ((char*)sB) + ch * 1024);
    }
    __syncthreads();
#pragma unroll
    for (int ks = 0; ks < 2; ++ks) {
      bf16x8 af[MF], bfr[NF];
#pragma unroll
      for (int m = 0; m < MF; ++m) {
        const int r = wr * (BM / MW) + m * 16 + (l & 15);
        af[m] = *(const bf16x8*)&sA[r * BK + ks * 32 + (l >> 4) * 8];
      }
#pragma unroll
      for (int n = 0; n < NF; ++n) {
        const int r = wc * 64 + n * 16 + (l & 15);
        bfr[n] = *(const bf16x8*)&sB[r * BK + ks * 32 + (l >> 4) * 8];
      }
#pragma unroll
      for (int m = 0; m < MF; ++m)
#pragma unroll
        for (int n = 0; n < NF; ++n)
          acc[m][n] = __builtin_amdgcn_mfma_f32_16x16x32_bf16(af[m], bfr[n], acc[m][n], 0, 0, 0);
    }
  }
#pragma unroll
  for (int m = 0; m < MF; ++m) {
#pragma unroll
    for (int r = 0; r < 4; ++r) {
      const int row = bm + wr * (BM / MW) + m * 16 + (l >> 4) * 4 + r;
      if (row < M) {
#pragma unroll
        for (int n = 0; n < NF; ++n)
          C[(size_t)row * Nc + bn + wc * 64 + n * 16 + (l & 15)] = f2bf(acc[m][n][r]);
      }
    }
  }
}

// ---------------- alpha dots (bf16 h) ----------------
__global__ __launch_bounds__(256) void alpha256(const ushort4* __restrict__ h,
                                                const float* __restrict__ a_src,
                                                const float* __restrict__ a_dst,
                                                float* __restrict__ asrc,
                                                float* __restrict__ adst, int N) {
  const int wave = (int)((blockIdx.x * (size_t)blockDim.x + threadIdx.x) >> 6);
  const int lane = threadIdx.x & 63;
  if (wave >= N) return;
  const ushort4 hv = h[(size_t)wave * 64 + lane];
  const float4 s4 = ((const float4*)a_src)[lane];
  const float4 d4 = ((const float4*)a_dst)[lane];
  const float h0 = bf2f(hv.x), h1 = bf2f(hv.y), h2 = bf2f(hv.z), h3 = bf2f(hv.w);
  float ps = h0 * s4.x + h1 * s4.y + h2 * s4.z + h3 * s4.w;
  float pd = h0 * d4.x + h1 * d4.y + h2 * d4.z + h3 * d4.w;
#pragma unroll
  for (int off = 32; off; off >>= 1) {
    ps += __shfl_down(ps, off);
    pd += __shfl_down(pd, off);
  }
  if (lane == 0) { asrc[wave] = ps; adst[wave] = pd; }
}

__global__ __launch_bounds__(256) void alpha64(const unsigned short* __restrict__ h,
                                               const float* __restrict__ a_src,
                                               const float* __restrict__ a_dst,
                                               float* __restrict__ asrc,
                                               float* __restrict__ adst, int N) {
  const int wave = (int)((blockIdx.x * (size_t)blockDim.x + threadIdx.x) >> 6);
  const int lane = threadIdx.x & 63;
  if (wave >= N) return;
  const float hv = bf2f(h[(size_t)wave * 64 + lane]);
  float ps = hv * a_src[lane];
  float pd = hv * a_dst[lane];
#pragma unroll
  for (int off = 32; off; off >>= 1) {
    ps += __shfl_down(ps, off);
    pd += __shfl_down(pd, off);
  }
  if (lane == 0) { asrc[wave] = ps; adst[wave] = pd; }
}

// ---------------- fused CSR aggregation, H=256, bf16 h ----------------
// Lane-parallel weights: lane i computes w for edge base+i (one exp/edge);
// gather loop broadcasts s,w via readlane (SGPR), unrolled x4 for MLP.
// EPI 1: out16 = bf16(elu(agg + bias))
// EPI 2: out16 = bf16(0.5*elu(agg + bias) + 0.5*other16)
template <int EPI>
__global__ __launch_bounds__(256) void agg_csr256(const int* __restrict__ rs,
                                                  const int* __restrict__ csr,
                                                  const float* __restrict__ asrc,
                                                  const float* __restrict__ adst,
                                                  const ushort4* __restrict__ h4,
                                                  const float* __restrict__ bias,
                                                  const ushort4* __restrict__ other16,
                                                  ushort4* __restrict__ out16, int N) {
  const int d = (int)((blockIdx.x * (size_t)blockDim.x + threadIdx.x) >> 6);
  const int lane = threadIdx.x & 63;
  if (d >= N) return;
  const float ad = adst[d];

  // self-loop
  float e = asrc[d] + ad;
  e = e > 0.f ? e : NEG_SLOPE * e;
  const float wself = expf(e);
  float denl = (lane == 0) ? wself : 0.f;  // per-lane partial denominator
  const ushort4 hv = h4[(size_t)d * 64 + lane];
  float ax = wself * bf2f(hv.x), ay = wself * bf2f(hv.y),
        az = wself * bf2f(hv.z), aw = wself * bf2f(hv.w);

  const int base = rs[d], mend = rs[d + 1];
  for (int c = base; c < mend; c += 64) {
    const int m = c + lane;
    int s = 0;
    float w = 0.f;
    if (m < mend) {
      s = csr[m];
      float e2 = asrc[s] + ad;
      e2 = e2 > 0.f ? e2 : NEG_SLOPE * e2;
      w = expf(e2);
    }
    denl += w;
    const int cnt = min(64, mend - c);
    int j = 0;
    for (; j + 3 < cnt; j += 4) {
      const int s0 = rl_i(s, j), s1 = rl_i(s, j + 1), s2 = rl_i(s, j + 2), s3 = rl_i(s, j + 3);
      const float w0 = rl_f(w, j), w1 = rl_f(w, j + 1), w2 = rl_f(w, j + 2), w3 = rl_f(w, j + 3);
      const ushort4 a0 = h4[(size_t)s0 * 64 + lane];
      const ushort4 a1 = h4[(size_t)s1 * 64 + lane];
      const ushort4 a2 = h4[(size_t)s2 * 64 + lane];
      const ushort4 a3 = h4[(size_t)s3 * 64 + lane];
      ax += w0 * bf2f(a0.x) + w1 * bf2f(a1.x) + w2 * bf2f(a2.x) + w3 * bf2f(a3.x);
      ay += w0 * bf2f(a0.y) + w1 * bf2f(a1.y) + w2 * bf2f(a2.y) + w3 * bf2f(a3.y);
      az += w0 * bf2f(a0.z) + w1 * bf2f(a1.z) + w2 * bf2f(a2.z) + w3 * bf2f(a3.z);
      aw += w0 * bf2f(a0.w) + w1 * bf2f(a1.w) + w2 * bf2f(a2.w) + w3 * bf2f(a3.w);
    }
    for (; j < cnt; ++j) {
      const int sj = rl_i(s, j);
      const float wj = rl_f(w, j);
      const ushort4 aj = h4[(size_t)sj * 64 + lane];
      ax += wj * bf2f(aj.x);
      ay += wj * bf2f(aj.y);
      az += wj * bf2f(aj.z);
      aw += wj * bf2f(aj.w);
    }
  }
  // wave-reduce denominator (all lanes get total)
#pragma unroll
  for (int off = 32; off; off >>= 1) denl += __shfl_xor(denl, off);
  const float inv = 1.f / denl;

  const float4 b4 = ((const float4*)bias)[lane];
  float v[4] = {ax * inv + b4.x, ay * inv + b4.y, az * inv + b4.z, aw * inv + b4.w};
#pragma unroll
  for (int j = 0; j < 4; ++j) v[j] = v[j] > 0.f ? v[j] : (expf(v[j]) - 1.f);
  ushort4 pk;
  if (EPI == 2) {
    const ushort4 ov = other16[(size_t)d * 64 + lane];
    pk.x = f2bf(0.5f * v[0] + 0.5f * bf2f(ov.x));
    pk.y = f2bf(0.5f * v[1] + 0.5f * bf2f(ov.y));
    pk.z = f2bf(0.5f * v[2] + 0.5f * bf2f(ov.z));
    pk.w = f2bf(0.5f * v[3] + 0.5f * bf2f(ov.w));
  } else {
    pk.x = f2bf(v[0]); pk.y = f2bf(v[1]); pk.z = f2bf(v[2]); pk.w = f2bf(v[3]);
  }
  out16[(size_t)d * 64 + lane] = pk;
}

// ---------------- fused CSR aggregation, H=64, bf16 h -> fp32 d_out ----------------
__global__ __launch_bounds__(256) void agg_csr64(const int* __restrict__ rs,
                                                 const int* __restrict__ csr,
                                                 const float* __restrict__ asrc,
                                                 const float* __restrict__ adst,
                                                 const unsigned short* __restrict__ h,
                                                 const float* __restrict__ bias,
                                                 float* __restrict__ outb, int N) {
  const int d = (int)((blockIdx.x * (size_t)blockDim.x + threadIdx.x) >> 6);
  const int lane = threadIdx.x & 63;
  if (d >= N) return;
  const float ad = adst[d];

  float e = asrc[d] + ad;
  e = e > 0.f ? e : NEG_SLOPE * e;
  const float wself = expf(e);
  float denl = (lane == 0) ? wself : 0.f;
  float acc = wself * bf2f(h[(size_t)d * 64 + lane]);

  const int base = rs[d], mend = rs[d + 1];
  for (int c = base; c < mend; c += 64) {
    const int m = c + lane;
    int s = 0;
    float w = 0.f;
    if (m < mend) {
      s = csr[m];
      float e2 = asrc[s] + ad;
      e2 = e2 > 0.f ? e2 : NEG_SLOPE * e2;
      w = expf(e2);
    }
    denl += w;
    const int cnt = min(64, mend - c);
    int j = 0;
    for (; j + 3 < cnt; j += 4) {
      const int s0 = rl_i(s, j), s1 = rl_i(s, j + 1), s2 = rl_i(s, j + 2), s3 = rl_i(s, j + 3);
      const float w0 = rl_f(w, j), w1 = rl_f(w, j + 1), w2 = rl_f(w, j + 2), w3 = rl_f(w, j + 3);
      const float a0 = bf2f(h[(size_t)s0 * 64 + lane]);
      const float a1 = bf2f(h[(size_t)s1 * 64 + lane]);
      const float a2 = bf2f(h[(size_t)s2 * 64 + lane]);
      const float a3 = bf2f(h[(size_t)s3 * 64 + lane]);
      acc += w0 * a0 + w1 * a1 + w2 * a2 + w3 * a3;
    }
    for (; j < cnt; ++j) {
      const int sj = rl_i(s, j);
      const float wj = rl_f(w, j);
      acc += wj * bf2f(h[(size_t)sj * 64 + lane]);
    }
  }
#pragma unroll
  for (int off = 32; off; off >>= 1) denl += __shfl_xor(denl, off);
  outb[(size_t)d * 64 + lane] = acc / denl + bias[lane];
}

extern "C" void kernel_launch(void* const* d_in, const int* in_sizes, int n_in,
                              void* d_out, int out_size, void* d_ws, size_t ws_size,
                              hipStream_t stream) {
  const float* x        = (const float*)d_in[0];
  const int*   ei_sp    = (const int*)d_in[1];
  const int*   ei_gs    = (const int*)d_in[2];
  const float* W_sp     = (const float*)d_in[3];
  const float* a_src_sp = (const float*)d_in[4];
  const float* a_dst_sp = (const float*)d_in[5];
  const float* b_sp     = (const float*)d_in[6];
  const float* W_gs     = (const float*)d_in[7];
  const float* a_src_gs = (const float*)d_in[8];
  const float* a_dst_gs = (const float*)d_in[9];
  const float* b_gs     = (const float*)d_in[10];
  const float* W_fu     = (const float*)d_in[11];
  const float* a_src_fu = (const float*)d_in[12];
  const float* a_dst_fu = (const float*)d_in[13];
  const float* b_fu     = (const float*)d_in[14];
  float* out = (float*)d_out;

  const int N = in_sizes[0] / 512;
  const int E = in_sizes[1] / 2;
  const int nb = (N + 255) / 256;

  // ---- workspace layout ----
  unsigned short* wt_sp = (unsigned short*)d_ws;     // 256*512
  unsigned short* wt_gs = wt_sp + 256 * 512;         // 256*512
  unsigned short* wt_fu = wt_gs + 256 * 512;         // 64*256
  unsigned short* xb    = wt_fu + 64 * 256;          // N*512 bf16 (later B3 + h_fused)
  unsigned short* hb_sp = xb + (size_t)N * 512;      // N*256 bf16 (later h_fu N*64)
  unsigned short* hb_gs = hb_sp + (size_t)N * 256;   // N*256 bf16
  float* asrc = (float*)(hb_gs + (size_t)N * 256);   // N
  float* adst = asrc + N;                            // N
  int* rs_sp  = (int*)(adst + N);                    // N+1
  int* rs_gs  = rs_sp + (N + 1);                     // N+1
  int* csr_sp = rs_gs + (N + 1);                     // E
  int* csr_gs = csr_sp + E;                          // E
  int* deg_sp = csr_gs + E;                          // N (cursor on reuse)
  int* deg_gs = deg_sp + N;                          // N
  int* parts2 = deg_gs + N;                          // 2*512

  unsigned short* B3  = xb;                          // [N][256] bf16 (xb dead)
  unsigned short* hfb = xb + (size_t)N * 256;        // [N][256] bf16 h_fused
  unsigned short* hfu = hb_sp;                       // [N][64] bf16 (hb_sp dead)

  const int BLK = 256;
  const int eGrid = (E + BLK - 1) / BLK;
  const int nodeWaveGrid = (N + 3) / 4;
  const dim3 g1((N + 127) / 128, 2);
  const dim3 g2((N + 127) / 128, 1);

  // ---- CSR builds (both graphs) ----
  hipMemsetAsync(deg_sp, 0, (size_t)2 * N * 4, stream);
  hist2<<<eGrid, BLK, 0, stream>>>(ei_sp + E, ei_gs + E, deg_sp, deg_gs, E);
  scan1_2<<<dim3(nb, 2), BLK, 0, stream>>>(deg_sp, deg_gs, rs_sp, rs_gs, parts2, N);
  scan2_2<<<2, 512, 0, stream>>>(parts2, nb);
  scan3_2<<<dim3(nb, 2), BLK, 0, stream>>>(rs_sp, rs_gs, parts2, N, E);
  hipMemsetAsync(deg_sp, 0, (size_t)2 * N * 4, stream);
  scatter2<<<eGrid, BLK, 0, stream>>>(ei_sp, ei_gs, rs_sp, rs_gs, deg_sp, deg_gs,
                                      csr_sp, csr_gs, E);

  // ---- conversions ----
  conv_bf16<<<2048, BLK, 0, stream>>>((const float4*)x, (ushort4*)xb, (size_t)N * 128);
  wt_bf16<<<(512 * 256 + 255) / 256, BLK, 0, stream>>>(W_sp, wt_sp, 512, 256);
  wt_bf16<<<(512 * 256 + 255) / 256, BLK, 0, stream>>>(W_gs, wt_gs, 512, 256);
  wt_bf16<<<(256 * 64 + 255) / 256, BLK, 0, stream>>>(W_fu, wt_fu, 256, 64);

  // ---- layer-1 GEMMs (bf16 in/out) ----
  gemm_bf16_nt<128><<<g1, BLK, 0, stream>>>(xb, wt_sp, hb_sp, N, 256, 512);
  gemm_bf16_nt<128><<<g1, BLK, 0, stream>>>(xb, wt_gs, hb_gs, N, 256, 512);

  // ---- spatial conv -> B3 = bf16(elu(agg+b_sp)) ----
  alpha256<<<nodeWaveGrid, BLK, 0, stream>>>((const ushort4*)hb_sp, a_src_sp, a_dst_sp,
                                             asrc, adst, N);
  agg_csr256<1><<<nodeWaveGrid, BLK, 0, stream>>>(rs_sp, csr_sp, asrc, adst,
                                                  (const ushort4*)hb_sp, b_sp,
                                                  nullptr, (ushort4*)B3, N);

  // ---- gene conv + blend -> h_fused bf16 ----
  alpha256<<<nodeWaveGrid, BLK, 0, stream>>>((const ushort4*)hb_gs, a_src_gs, a_dst_gs,
                                             asrc, adst, N);
  agg_csr256<2><<<nodeWaveGrid, BLK, 0, stream>>>(rs_gs, csr_gs, asrc, adst,
                                                  (const ushort4*)hb_gs, b_gs,
                                                  (const ushort4*)B3, (ushort4*)hfb, N);

  // ---- fusion conv (256->64, spatial graph) ----
  gemm_bf16_nt<64><<<g2, BLK, 0, stream>>>(hfb, wt_fu, hfu, N, 64, 256);
  alpha64<<<nodeWaveGrid, BLK, 0, stream>>>(hfu, a_src_fu, a_dst_fu, asrc, adst, N);
  agg_csr64<<<nodeWaveGrid, BLK, 0, stream>>>(rs_sp, csr_sp, asrc, adst, hfu, b_fu,
                                              out, N);
}

// Round 6
// 563.245 us; speedup vs baseline: 13.8899x; 1.0508x over previous
//
#include <hip/hip_runtime.h>
#include <math.h>

// Round 6: single fused layer-1 kernel (gemm2_fused) reads x fp32 ONCE, converts
// to bf16 in-register into LDS, computes h_sp and h_gs tiles with MFMA (waves
// 0-3 / 4-7). Deletes conv_bf16 and the double A-read of the old GEMM pair.
// Dual alpha pass, single wt-conversion launch. Agg kernels unchanged (round 5).

#define NEG_SLOPE 0.2f

typedef __attribute__((ext_vector_type(8))) short bf16x8;
typedef __attribute__((ext_vector_type(4))) float f32x4;

__device__ __forceinline__ unsigned short f2bf(float f) {
  unsigned int u = __float_as_uint(f);
  u = (u + 0x7FFFu + ((u >> 16) & 1u)) >> 16;  // RNE
  return (unsigned short)u;
}
__device__ __forceinline__ float bf2f(unsigned short u) {
  return __uint_as_float((unsigned int)u << 16);
}
__device__ __forceinline__ int rl_i(int v, int l) {
  return __builtin_amdgcn_readlane(v, l);
}
__device__ __forceinline__ float rl_f(float v, int l) {
  return __uint_as_float(__builtin_amdgcn_readlane(__float_as_uint(v), l));
}

#define GLOAD16(g, l)                                                   \
  __builtin_amdgcn_global_load_lds(                                     \
      (const __attribute__((address_space(1))) void*)(g),               \
      (__attribute__((address_space(3))) void*)(l), 16, 0, 0)

// ---------------- weight conversions (all three in one launch) ----------------
// W[K][Nc] fp32 -> Wt[Nc][K] bf16
__global__ __launch_bounds__(256) void wt_bf16_all(const float* __restrict__ W_sp,
                                                   const float* __restrict__ W_gs,
                                                   const float* __restrict__ W_fu,
                                                   unsigned short* __restrict__ wt_sp,
                                                   unsigned short* __restrict__ wt_gs,
                                                   unsigned short* __restrict__ wt_fu) {
  const int i = blockIdx.x * 256 + threadIdx.x;
  if (i < 131072) {                       // 512x256 spatial
    const int k = i >> 8, n = i & 255;
    wt_sp[n * 512 + k] = f2bf(W_sp[i]);
  } else if (i < 262144) {                // 512x256 gene
    const int j = i - 131072;
    const int k = j >> 8, n = j & 255;
    wt_gs[n * 512 + k] = f2bf(W_gs[j]);
  } else if (i < 278528) {                // 256x64 fusion
    const int j = i - 262144;
    const int k = j >> 6, n = j & 63;
    wt_fu[n * 256 + k] = f2bf(W_fu[j]);
  }
}

// ---------------- CSR build (both graphs per launch) ----------------
__global__ __launch_bounds__(256) void hist2(const int* __restrict__ dst_sp,
                                             const int* __restrict__ dst_gs,
                                             int* __restrict__ deg_sp,
                                             int* __restrict__ deg_gs, int E) {
  const int m = blockIdx.x * 256 + threadIdx.x;
  if (m < E) {
    atomicAdd(&deg_sp[dst_sp[m]], 1);
    atomicAdd(&deg_gs[dst_gs[m]], 1);
  }
}

__global__ __launch_bounds__(256) void scan1_2(const int* __restrict__ deg_sp,
                                               const int* __restrict__ deg_gs,
                                               int* __restrict__ rs_sp,
                                               int* __restrict__ rs_gs,
                                               int* __restrict__ parts2, int N) {
  __shared__ int sm[256];
  const int* deg = blockIdx.y ? deg_gs : deg_sp;
  int* rs = blockIdx.y ? rs_gs : rs_sp;
  int* parts = parts2 + blockIdx.y * 512;
  const int i = blockIdx.x * 256 + threadIdx.x;
  const int v = (i < N) ? deg[i] : 0;
  sm[threadIdx.x] = v;
  __syncthreads();
  for (int off = 1; off < 256; off <<= 1) {
    const int x = (threadIdx.x >= off) ? sm[threadIdx.x - off] : 0;
    __syncthreads();
    sm[threadIdx.x] += x;
    __syncthreads();
  }
  if (i < N) rs[i] = sm[threadIdx.x] - v;
  if (threadIdx.x == 255) parts[blockIdx.x] = sm[255];
}

__global__ __launch_bounds__(512) void scan2_2(int* __restrict__ parts2, int nb) {
  __shared__ int sm[512];
  int* parts = parts2 + blockIdx.x * 512;
  const int t = threadIdx.x;
  const int v = (t < nb) ? parts[t] : 0;
  sm[t] = v;
  __syncthreads();
  for (int off = 1; off < 512; off <<= 1) {
    const int x = (t >= off) ? sm[t - off] : 0;
    __syncthreads();
    sm[t] += x;
    __syncthreads();
  }
  if (t < nb) parts[t] = sm[t] - v;
}

__global__ __launch_bounds__(256) void scan3_2(int* __restrict__ rs_sp,
                                               int* __restrict__ rs_gs,
                                               const int* __restrict__ parts2,
                                               int N, int E) {
  int* rs = blockIdx.y ? rs_gs : rs_sp;
  const int* parts = parts2 + blockIdx.y * 512;
  const int i = blockIdx.x * 256 + threadIdx.x;
  if (i < N) rs[i] += parts[blockIdx.x];
  if (i == 0) rs[N] = E;
}

__global__ __launch_bounds__(256) void scatter2(const int* __restrict__ ei_sp,
                                                const int* __restrict__ ei_gs,
                                                const int* __restrict__ rs_sp,
                                                const int* __restrict__ rs_gs,
                                                int* __restrict__ cur_sp,
                                                int* __restrict__ cur_gs,
                                                int* __restrict__ csr_sp,
                                                int* __restrict__ csr_gs, int E) {
  const int m = blockIdx.x * 256 + threadIdx.x;
  if (m >= E) return;
  {
    const int s = ei_sp[m], d = ei_sp[E + m];
    csr_sp[rs_sp[d] + atomicAdd(&cur_sp[d], 1)] = s;
  }
  {
    const int s = ei_gs[m], d = ei_gs[E + m];
    csr_gs[rs_gs[d] + atomicAdd(&cur_gs[d], 1)] = s;
  }
}

// ---------------- fused layer-1: h_sp, h_gs = bf16(x @ {W_sp, W_gs}) ----------------
// 64-row blocks, 512 threads (8 waves). Per k-step: x fp32 -> bf16 reg-staged to
// LDS (read ONCE); both weight tiles via global_load_lds. Waves 0-3 compute the
// 64x256 h_sp tile, waves 4-7 the h_gs tile.
__global__ __launch_bounds__(512) void gemm2_fused(const float* __restrict__ x,
                                                   const unsigned short* __restrict__ wsp,
                                                   const unsigned short* __restrict__ wgs,
                                                   unsigned short* __restrict__ hb_sp,
                                                   unsigned short* __restrict__ hb_gs,
                                                   int M) {
  constexpr int BK = 32;
  constexpr int SAP = 40;  // padded A stride (bf16 elems): breaks 8-way bank conflict
  __shared__ unsigned short sA[64 * SAP];
  __shared__ unsigned short sW[2][256 * BK];
  const int tid = threadIdx.x;
  const int w = tid >> 6, l = tid & 63;
  const int bm = blockIdx.x * 64;
  const int arow = tid >> 3;        // 0..63
  const int acol = (tid & 7) * 4;   // 0,4,..,28
  int axr = bm + arow;
  axr = axr < M ? axr : M - 1;      // clamp (rows discarded on store)
  const float* __restrict__ xrow = x + (size_t)axr * 512;

  f32x4 acc[4][4] = {};
  for (int k0 = 0; k0 < 512; k0 += BK) {
    __syncthreads();
    // A: fp32 -> bf16 into padded LDS
    {
      const float4 v = *(const float4*)(xrow + k0 + acol);
      ushort4 o;
      o.x = f2bf(v.x); o.y = f2bf(v.y); o.z = f2bf(v.z); o.w = f2bf(v.w);
      *(ushort4*)&sA[arow * SAP + acol] = o;
    }
    // W: both weights, 2 x 16B chunks per thread each
#pragma unroll
    for (int c = 0; c < 2; ++c) {
      const int ch = c * 512 + tid;          // 0..1023
      const int row = ch >> 2, kp = (ch & 3) * 8;
      const size_t gb = (size_t)row * 1024 + (size_t)(k0 + kp) * 2;
      const size_t lb = (size_t)(c * 512 + (w << 6)) * 16;  // wave-uniform base
      GLOAD16(((const char*)wsp) + gb, ((char*)sW[0]) + lb);
      GLOAD16(((const char*)wgs) + gb, ((char*)sW[1]) + lb);
    }
    __syncthreads();
    bf16x8 af[4], bf[4];
    const unsigned short* __restrict__ sWw = sW[w >> 2];
    const int wc = (w & 3) * 64;
#pragma unroll
    for (int m = 0; m < 4; ++m)
      af[m] = *(const bf16x8*)&sA[(m * 16 + (l & 15)) * SAP + (l >> 4) * 8];
#pragma unroll
    for (int n = 0; n < 4; ++n)
      bf[n] = *(const bf16x8*)&sWw[(wc + n * 16 + (l & 15)) * BK + (l >> 4) * 8];
#pragma unroll
    for (int m = 0; m < 4; ++m)
#pragma unroll
      for (int n = 0; n < 4; ++n)
        acc[m][n] = __builtin_amdgcn_mfma_f32_16x16x32_bf16(af[m], bf[n], acc[m][n], 0, 0, 0);
  }
  unsigned short* __restrict__ outp = (w >> 2) ? hb_gs : hb_sp;
  const int wc = (w & 3) * 64;
#pragma unroll
  for (int m = 0; m < 4; ++m) {
#pragma unroll
    for (int r = 0; r < 4; ++r) {
      const int row = bm + m * 16 + (l >> 4) * 4 + r;
      if (row < M) {
#pragma unroll
        for (int n = 0; n < 4; ++n)
          outp[(size_t)row * 256 + wc + n * 16 + (l & 15)] = f2bf(acc[m][n][r]);
      }
    }
  }
}

// ---------------- bf16 MFMA GEMM (NT) for fusion layer (256->64) ----------------
template <int BN>
__global__ __launch_bounds__(256) void gemm_bf16_nt(const unsigned short* __restrict__ A,
                                                    const unsigned short* __restrict__ Bt,
                                                    unsigned short* __restrict__ C,
                                                    int M, int Nc, int K) {
  constexpr int BM = 128, BK = 64;
  constexpr int NW = BN / 64;
  constexpr int MW = 4 / NW;
  constexpr int MF = (BM / MW) / 16;
  constexpr int NF = 4;
  constexpr int ACW = (BM * BK * 2 / 1024) / 4;
  constexpr int BCW = (BN * BK * 2 / 1024) / 4;
  __shared__ unsigned short sA[BM * BK];
  __shared__ unsigned short sB[BN * BK];
  const int tid = threadIdx.x;
  const int w = tid >> 6, l = tid & 63;
  const int wr = w / NW, wc = w % NW;
  const int bm = blockIdx.x * BM;
  const int bn = blockIdx.y * BN;
  const int crow = l >> 3;
  const int cbyte = (l & 7) * 16;

  f32x4 acc[MF][NF] = {};
  for (int k0 = 0; k0 < K; k0 += BK) {
    __syncthreads();
#pragma unroll
    for (int c = 0; c < ACW; ++c) {
      const int ch = w * ACW + c;
      int row = bm + ch * 8 + crow;
      row = row < M ? row : M - 1;
      const char* g = (const char*)A + (size_t)row * K * 2 + (size_t)k0 * 2 + cbyte;
      GLOAD16(g, ((char*)sA) + ch * 1024);
    }
#pragma unroll
    for (int c = 0; c < BCW; ++c) {
      const int ch = w * BCW + c;
      const int row = bn + ch * 8 + crow;
      const char* g = (const char*)Bt + (size_t)row * K * 2 + (size_t)k0 * 2 + cbyte;
      GLOAD16(g, ((char*)sB) + ch * 1024);
    }
    __syncthreads();
#pragma unroll
    for (int ks = 0; ks < 2; ++ks) {
      bf16x8 af[MF], bfr[NF];
#pragma unroll
      for (int m = 0; m < MF; ++m) {
        const int r = wr * (BM / MW) + m * 16 + (l & 15);
        af[m] = *(const bf16x8*)&sA[r * BK + ks * 32 + (l >> 4) * 8];
      }
#pragma unroll
      for (int n = 0; n < NF; ++n) {
        const int r = wc * 64 + n * 16 + (l & 15);
        bfr[n] = *(const bf16x8*)&sB[r * BK + ks * 32 + (l >> 4) * 8];
      }
#pragma unroll
      for (int m = 0; m < MF; ++m)
#pragma unroll
        for (int n = 0; n < NF; ++n)
          acc[m][n] = __builtin_amdgcn_mfma_f32_16x16x32_bf16(af[m], bfr[n], acc[m][n], 0, 0, 0);
    }
  }
#pragma unroll
  for (int m = 0; m < MF; ++m) {
#pragma unroll
    for (int r = 0; r < 4; ++r) {
      const int row = bm + wr * (BM / MW) + m * 16 + (l >> 4) * 4 + r;
      if (row < M) {
#pragma unroll
        for (int n = 0; n < NF; ++n)
          C[(size_t)row * Nc + bn + wc * 64 + n * 16 + (l & 15)] = f2bf(acc[m][n][r]);
      }
    }
  }
}

// ---------------- dual alpha dots (both layer-1 graphs in one pass) ----------------
__global__ __launch_bounds__(256) void alpha2_256(const ushort4* __restrict__ hsp,
                                                  const ushort4* __restrict__ hgs,
                                                  const float* __restrict__ av_sp_s,
                                                  const float* __restrict__ av_sp_d,
                                                  const float* __restrict__ av_gs_s,
                                                  const float* __restrict__ av_gs_d,
                                                  float* __restrict__ asrc_sp,
                                                  float* __restrict__ adst_sp,
                                                  float* __restrict__ asrc_gs,
                                                  float* __restrict__ adst_gs, int N) {
  const int wave = (int)((blockIdx.x * (size_t)blockDim.x + threadIdx.x) >> 6);
  const int lane = threadIdx.x & 63;
  if (wave >= N) return;
  const ushort4 h1 = hsp[(size_t)wave * 64 + lane];
  const ushort4 h2 = hgs[(size_t)wave * 64 + lane];
  const float4 s1 = ((const float4*)av_sp_s)[lane];
  const float4 d1 = ((const float4*)av_sp_d)[lane];
  const float4 s2 = ((const float4*)av_gs_s)[lane];
  const float4 d2 = ((const float4*)av_gs_d)[lane];
  const float a0 = bf2f(h1.x), a1 = bf2f(h1.y), a2 = bf2f(h1.z), a3 = bf2f(h1.w);
  const float b0 = bf2f(h2.x), b1 = bf2f(h2.y), b2 = bf2f(h2.z), b3 = bf2f(h2.w);
  float p0 = a0 * s1.x + a1 * s1.y + a2 * s1.z + a3 * s1.w;
  float p1 = a0 * d1.x + a1 * d1.y + a2 * d1.z + a3 * d1.w;
  float p2 = b0 * s2.x + b1 * s2.y + b2 * s2.z + b3 * s2.w;
  float p3 = b0 * d2.x + b1 * d2.y + b2 * d2.z + b3 * d2.w;
#pragma unroll
  for (int off = 32; off; off >>= 1) {
    p0 += __shfl_down(p0, off);
    p1 += __shfl_down(p1, off);
    p2 += __shfl_down(p2, off);
    p3 += __shfl_down(p3, off);
  }
  if (lane == 0) {
    asrc_sp[wave] = p0; adst_sp[wave] = p1;
    asrc_gs[wave] = p2; adst_gs[wave] = p3;
  }
}

__global__ __launch_bounds__(256) void alpha64(const unsigned short* __restrict__ h,
                                               const float* __restrict__ a_src,
                                               const float* __restrict__ a_dst,
                                               float* __restrict__ asrc,
                                               float* __restrict__ adst, int N) {
  const int wave = (int)((blockIdx.x * (size_t)blockDim.x + threadIdx.x) >> 6);
  const int lane = threadIdx.x & 63;
  if (wave >= N) return;
  const float hv = bf2f(h[(size_t)wave * 64 + lane]);
  float ps = hv * a_src[lane];
  float pd = hv * a_dst[lane];
#pragma unroll
  for (int off = 32; off; off >>= 1) {
    ps += __shfl_down(ps, off);
    pd += __shfl_down(pd, off);
  }
  if (lane == 0) { asrc[wave] = ps; adst[wave] = pd; }
}

// ---------------- fused CSR aggregation, H=256, bf16 h ----------------
template <int EPI>
__global__ __launch_bounds__(256) void agg_csr256(const int* __restrict__ rs,
                                                  const int* __restrict__ csr,
                                                  const float* __restrict__ asrc,
                                                  const float* __restrict__ adst,
                                                  const ushort4* __restrict__ h4,
                                                  const float* __restrict__ bias,
                                                  const ushort4* __restrict__ other16,
                                                  ushort4* __restrict__ out16, int N) {
  const int d = (int)((blockIdx.x * (size_t)blockDim.x + threadIdx.x) >> 6);
  const int lane = threadIdx.x & 63;
  if (d >= N) return;
  const float ad = adst[d];

  float e = asrc[d] + ad;
  e = e > 0.f ? e : NEG_SLOPE * e;
  const float wself = expf(e);
  float denl = (lane == 0) ? wself : 0.f;
  const ushort4 hv = h4[(size_t)d * 64 + lane];
  float ax = wself * bf2f(hv.x), ay = wself * bf2f(hv.y),
        az = wself * bf2f(hv.z), aw = wself * bf2f(hv.w);

  const int base = rs[d], mend = rs[d + 1];
  for (int c = base; c < mend; c += 64) {
    const int m = c + lane;
    int s = 0;
    float w = 0.f;
    if (m < mend) {
      s = csr[m];
      float e2 = asrc[s] + ad;
      e2 = e2 > 0.f ? e2 : NEG_SLOPE * e2;
      w = expf(e2);
    }
    denl += w;
    const int cnt = min(64, mend - c);
    int j = 0;
    for (; j + 3 < cnt; j += 4) {
      const int s0 = rl_i(s, j), s1 = rl_i(s, j + 1), s2 = rl_i(s, j + 2), s3 = rl_i(s, j + 3);
      const float w0 = rl_f(w, j), w1 = rl_f(w, j + 1), w2 = rl_f(w, j + 2), w3 = rl_f(w, j + 3);
      const ushort4 a0 = h4[(size_t)s0 * 64 + lane];
      const ushort4 a1 = h4[(size_t)s1 * 64 + lane];
      const ushort4 a2 = h4[(size_t)s2 * 64 + lane];
      const ushort4 a3 = h4[(size_t)s3 * 64 + lane];
      ax += w0 * bf2f(a0.x) + w1 * bf2f(a1.x) + w2 * bf2f(a2.x) + w3 * bf2f(a3.x);
      ay += w0 * bf2f(a0.y) + w1 * bf2f(a1.y) + w2 * bf2f(a2.y) + w3 * bf2f(a3.y);
      az += w0 * bf2f(a0.z) + w1 * bf2f(a1.z) + w2 * bf2f(a2.z) + w3 * bf2f(a3.z);
      aw += w0 * bf2f(a0.w) + w1 * bf2f(a1.w) + w2 * bf2f(a2.w) + w3 * bf2f(a3.w);
    }
    for (; j < cnt; ++j) {
      const int sj = rl_i(s, j);
      const float wj = rl_f(w, j);
      const ushort4 aj = h4[(size_t)sj * 64 + lane];
      ax += wj * bf2f(aj.x);
      ay += wj * bf2f(aj.y);
      az += wj * bf2f(aj.z);
      aw += wj * bf2f(aj.w);
    }
  }
#pragma unroll
  for (int off = 32; off; off >>= 1) denl += __shfl_xor(denl, off);
  const float inv = 1.f / denl;

  const float4 b4 = ((const float4*)bias)[lane];
  float v[4] = {ax * inv + b4.x, ay * inv + b4.y, az * inv + b4.z, aw * inv + b4.w};
#pragma unroll
  for (int j = 0; j < 4; ++j) v[j] = v[j] > 0.f ? v[j] : (expf(v[j]) - 1.f);
  ushort4 pk;
  if (EPI == 2) {
    const ushort4 ov = other16[(size_t)d * 64 + lane];
    pk.x = f2bf(0.5f * v[0] + 0.5f * bf2f(ov.x));
    pk.y = f2bf(0.5f * v[1] + 0.5f * bf2f(ov.y));
    pk.z = f2bf(0.5f * v[2] + 0.5f * bf2f(ov.z));
    pk.w = f2bf(0.5f * v[3] + 0.5f * bf2f(ov.w));
  } else {
    pk.x = f2bf(v[0]); pk.y = f2bf(v[1]); pk.z = f2bf(v[2]); pk.w = f2bf(v[3]);
  }
  out16[(size_t)d * 64 + lane] = pk;
}

// ---------------- fused CSR aggregation, H=64, bf16 h -> fp32 d_out ----------------
__global__ __launch_bounds__(256) void agg_csr64(const int* __restrict__ rs,
                                                 const int* __restrict__ csr,
                                                 const float* __restrict__ asrc,
                                                 const float* __restrict__ adst,
                                                 const unsigned short* __restrict__ h,
                                                 const float* __restrict__ bias,
                                                 float* __restrict__ outb, int N) {
  const int d = (int)((blockIdx.x * (size_t)blockDim.x + threadIdx.x) >> 6);
  const int lane = threadIdx.x & 63;
  if (d >= N) return;
  const float ad = adst[d];

  float e = asrc[d] + ad;
  e = e > 0.f ? e : NEG_SLOPE * e;
  const float wself = expf(e);
  float denl = (lane == 0) ? wself : 0.f;
  float acc = wself * bf2f(h[(size_t)d * 64 + lane]);

  const int base = rs[d], mend = rs[d + 1];
  for (int c = base; c < mend; c += 64) {
    const int m = c + lane;
    int s = 0;
    float w = 0.f;
    if (m < mend) {
      s = csr[m];
      float e2 = asrc[s] + ad;
      e2 = e2 > 0.f ? e2 : NEG_SLOPE * e2;
      w = expf(e2);
    }
    denl += w;
    const int cnt = min(64, mend - c);
    int j = 0;
    for (; j + 3 < cnt; j += 4) {
      const int s0 = rl_i(s, j), s1 = rl_i(s, j + 1), s2 = rl_i(s, j + 2), s3 = rl_i(s, j + 3);
      const float w0 = rl_f(w, j), w1 = rl_f(w, j + 1), w2 = rl_f(w, j + 2), w3 = rl_f(w, j + 3);
      const float a0 = bf2f(h[(size_t)s0 * 64 + lane]);
      const float a1 = bf2f(h[(size_t)s1 * 64 + lane]);
      const float a2 = bf2f(h[(size_t)s2 * 64 + lane]);
      const float a3 = bf2f(h[(size_t)s3 * 64 + lane]);
      acc += w0 * a0 + w1 * a1 + w2 * a2 + w3 * a3;
    }
    for (; j < cnt; ++j) {
      const int sj = rl_i(s, j);
      const float wj = rl_f(w, j);
      acc += wj * bf2f(h[(size_t)sj * 64 + lane]);
    }
  }
#pragma unroll
  for (int off = 32; off; off >>= 1) denl += __shfl_xor(denl, off);
  outb[(size_t)d * 64 + lane] = acc / denl + bias[lane];
}

extern "C" void kernel_launch(void* const* d_in, const int* in_sizes, int n_in,
                              void* d_out, int out_size, void* d_ws, size_t ws_size,
                              hipStream_t stream) {
  const float* x        = (const float*)d_in[0];
  const int*   ei_sp    = (const int*)d_in[1];
  const int*   ei_gs    = (const int*)d_in[2];
  const float* W_sp     = (const float*)d_in[3];
  const float* a_src_sp = (const float*)d_in[4];
  const float* a_dst_sp = (const float*)d_in[5];
  const float* b_sp     = (const float*)d_in[6];
  const float* W_gs     = (const float*)d_in[7];
  const float* a_src_gs = (const float*)d_in[8];
  const float* a_dst_gs = (const float*)d_in[9];
  const float* b_gs     = (const float*)d_in[10];
  const float* W_fu     = (const float*)d_in[11];
  const float* a_src_fu = (const float*)d_in[12];
  const float* a_dst_fu = (const float*)d_in[13];
  const float* b_fu     = (const float*)d_in[14];
  float* out = (float*)d_out;

  const int N = in_sizes[0] / 512;
  const int E = in_sizes[1] / 2;
  const int nb = (N + 255) / 256;

  // ---- workspace layout ----
  unsigned short* wt_sp = (unsigned short*)d_ws;       // 256*512
  unsigned short* wt_gs = wt_sp + 256 * 512;           // 256*512
  unsigned short* wt_fu = wt_gs + 256 * 512;           // 64*256
  unsigned short* hb_sp = wt_fu + 64 * 256;            // N*256 bf16
  unsigned short* hb_gs = hb_sp + (size_t)N * 256;     // N*256 bf16
  unsigned short* B3    = hb_gs + (size_t)N * 256;     // N*256 bf16 (later hfu N*64)
  unsigned short* hfb   = B3 + (size_t)N * 256;        // N*256 bf16 h_fused
  float* asrc_sp = (float*)(hfb + (size_t)N * 256);    // N
  float* adst_sp = asrc_sp + N;                        // N
  float* asrc_gs = adst_sp + N;                        // N
  float* adst_gs = asrc_gs + N;                        // N
  int* rs_sp  = (int*)(adst_gs + N);                   // N+1
  int* rs_gs  = rs_sp + (N + 1);                       // N+1
  int* csr_sp = rs_gs + (N + 1);                       // E
  int* csr_gs = csr_sp + E;                            // E
  int* deg_sp = csr_gs + E;                            // N
  int* deg_gs = deg_sp + N;                            // N
  int* parts2 = deg_gs + N;                            // 2*512

  unsigned short* hfu = B3;                            // [N][64] bf16 (B3 dead)

  const int BLK = 256;
  const int eGrid = (E + BLK - 1) / BLK;
  const int nodeWaveGrid = (N + 3) / 4;
  const dim3 gFu((N + 127) / 128, 1);

  // ---- CSR builds (both graphs) ----
  hipMemsetAsync(deg_sp, 0, (size_t)2 * N * 4, stream);
  hist2<<<eGrid, BLK, 0, stream>>>(ei_sp + E, ei_gs + E, deg_sp, deg_gs, E);
  scan1_2<<<dim3(nb, 2), BLK, 0, stream>>>(deg_sp, deg_gs, rs_sp, rs_gs, parts2, N);
  scan2_2<<<2, 512, 0, stream>>>(parts2, nb);
  scan3_2<<<dim3(nb, 2), BLK, 0, stream>>>(rs_sp, rs_gs, parts2, N, E);
  hipMemsetAsync(deg_sp, 0, (size_t)2 * N * 4, stream);
  scatter2<<<eGrid, BLK, 0, stream>>>(ei_sp, ei_gs, rs_sp, rs_gs, deg_sp, deg_gs,
                                      csr_sp, csr_gs, E);

  // ---- weight conversions (one launch) ----
  wt_bf16_all<<<(278528 + 255) / 256, BLK, 0, stream>>>(W_sp, W_gs, W_fu,
                                                        wt_sp, wt_gs, wt_fu);

  // ---- fused layer-1 GEMMs: x read once ----
  gemm2_fused<<<(N + 63) / 64, 512, 0, stream>>>(x, wt_sp, wt_gs, hb_sp, hb_gs, N);

  // ---- dual alpha ----
  alpha2_256<<<nodeWaveGrid, BLK, 0, stream>>>((const ushort4*)hb_sp,
                                               (const ushort4*)hb_gs,
                                               a_src_sp, a_dst_sp, a_src_gs, a_dst_gs,
                                               asrc_sp, adst_sp, asrc_gs, adst_gs, N);

  // ---- spatial conv -> B3 = bf16(elu(agg+b_sp)) ----
  agg_csr256<1><<<nodeWaveGrid, BLK, 0, stream>>>(rs_sp, csr_sp, asrc_sp, adst_sp,
                                                  (const ushort4*)hb_sp, b_sp,
                                                  nullptr, (ushort4*)B3, N);

  // ---- gene conv + blend -> h_fused bf16 ----
  agg_csr256<2><<<nodeWaveGrid, BLK, 0, stream>>>(rs_gs, csr_gs, asrc_gs, adst_gs,
                                                  (const ushort4*)hb_gs, b_gs,
                                                  (const ushort4*)B3, (ushort4*)hfb, N);

  // ---- fusion conv (256->64, spatial graph) ----
  gemm_bf16_nt<64><<<gFu, BLK, 0, stream>>>(hfb, wt_fu, hfu, N, 64, 256);
  alpha64<<<nodeWaveGrid, BLK, 0, stream>>>(hfu, a_src_fu, a_dst_fu,
                                            asrc_sp, adst_sp, N);
  agg_csr64<<<nodeWaveGrid, BLK, 0, stream>>>(rs_sp, csr_sp, asrc_sp, adst_sp,
                                              hfu, b_fu, out, N);
}

// Round 7
// 527.329 us; speedup vs baseline: 14.8360x; 1.0681x over previous
//
#include <hip/hip_runtime.h>
#include <math.h>

// Round 7: gemm2_fused rebuilt — BK=64 (8 k-steps, half the barriers), dual-output
// (waves 0-3: h_sp, 4-7: h_gs, each wave one 64-col quarter of a 64-row tile),
// XOR-swizzled LDS (linear dest for global_load_lds + pre-swizzled global source
// + swizzled ds_read; reg-staged A swizzled on ds_write). 72KB LDS, 2 blocks/CU.
// Everything else unchanged from round 6.

#define NEG_SLOPE 0.2f

typedef __attribute__((ext_vector_type(8))) short bf16x8;
typedef __attribute__((ext_vector_type(4))) float f32x4;

__device__ __forceinline__ unsigned short f2bf(float f) {
  unsigned int u = __float_as_uint(f);
  u = (u + 0x7FFFu + ((u >> 16) & 1u)) >> 16;  // RNE
  return (unsigned short)u;
}
__device__ __forceinline__ float bf2f(unsigned short u) {
  return __uint_as_float((unsigned int)u << 16);
}
__device__ __forceinline__ int rl_i(int v, int l) {
  return __builtin_amdgcn_readlane(v, l);
}
__device__ __forceinline__ float rl_f(float v, int l) {
  return __uint_as_float(__builtin_amdgcn_readlane(__float_as_uint(v), l));
}

#define GLOAD16(g, l)                                                   \
  __builtin_amdgcn_global_load_lds(                                     \
      (const __attribute__((address_space(1))) void*)(g),               \
      (__attribute__((address_space(3))) void*)(l), 16, 0, 0)

// ---------------- weight conversions (all three in one launch) ----------------
__global__ __launch_bounds__(256) void wt_bf16_all(const float* __restrict__ W_sp,
                                                   const float* __restrict__ W_gs,
                                                   const float* __restrict__ W_fu,
                                                   unsigned short* __restrict__ wt_sp,
                                                   unsigned short* __restrict__ wt_gs,
                                                   unsigned short* __restrict__ wt_fu) {
  const int i = blockIdx.x * 256 + threadIdx.x;
  if (i < 131072) {                       // 512x256 spatial
    const int k = i >> 8, n = i & 255;
    wt_sp[n * 512 + k] = f2bf(W_sp[i]);
  } else if (i < 262144) {                // 512x256 gene
    const int j = i - 131072;
    const int k = j >> 8, n = j & 255;
    wt_gs[n * 512 + k] = f2bf(W_gs[j]);
  } else if (i < 278528) {                // 256x64 fusion
    const int j = i - 262144;
    const int k = j >> 6, n = j & 63;
    wt_fu[n * 256 + k] = f2bf(W_fu[j]);
  }
}

// ---------------- CSR build (both graphs per launch) ----------------
__global__ __launch_bounds__(256) void hist2(const int* __restrict__ dst_sp,
                                             const int* __restrict__ dst_gs,
                                             int* __restrict__ deg_sp,
                                             int* __restrict__ deg_gs, int E) {
  const int m = blockIdx.x * 256 + threadIdx.x;
  if (m < E) {
    atomicAdd(&deg_sp[dst_sp[m]], 1);
    atomicAdd(&deg_gs[dst_gs[m]], 1);
  }
}

__global__ __launch_bounds__(256) void scan1_2(const int* __restrict__ deg_sp,
                                               const int* __restrict__ deg_gs,
                                               int* __restrict__ rs_sp,
                                               int* __restrict__ rs_gs,
                                               int* __restrict__ parts2, int N) {
  __shared__ int sm[256];
  const int* deg = blockIdx.y ? deg_gs : deg_sp;
  int* rs = blockIdx.y ? rs_gs : rs_sp;
  int* parts = parts2 + blockIdx.y * 512;
  const int i = blockIdx.x * 256 + threadIdx.x;
  const int v = (i < N) ? deg[i] : 0;
  sm[threadIdx.x] = v;
  __syncthreads();
  for (int off = 1; off < 256; off <<= 1) {
    const int x = (threadIdx.x >= off) ? sm[threadIdx.x - off] : 0;
    __syncthreads();
    sm[threadIdx.x] += x;
    __syncthreads();
  }
  if (i < N) rs[i] = sm[threadIdx.x] - v;
  if (threadIdx.x == 255) parts[blockIdx.x] = sm[255];
}

__global__ __launch_bounds__(512) void scan2_2(int* __restrict__ parts2, int nb) {
  __shared__ int sm[512];
  int* parts = parts2 + blockIdx.x * 512;
  const int t = threadIdx.x;
  const int v = (t < nb) ? parts[t] : 0;
  sm[t] = v;
  __syncthreads();
  for (int off = 1; off < 512; off <<= 1) {
    const int x = (t >= off) ? sm[t - off] : 0;
    __syncthreads();
    sm[t] += x;
    __syncthreads();
  }
  if (t < nb) parts[t] = sm[t] - v;
}

__global__ __launch_bounds__(256) void scan3_2(int* __restrict__ rs_sp,
                                               int* __restrict__ rs_gs,
                                               const int* __restrict__ parts2,
                                               int N, int E) {
  int* rs = blockIdx.y ? rs_gs : rs_sp;
  const int* parts = parts2 + blockIdx.y * 512;
  const int i = blockIdx.x * 256 + threadIdx.x;
  if (i < N) rs[i] += parts[blockIdx.x];
  if (i == 0) rs[N] = E;
}

__global__ __launch_bounds__(256) void scatter2(const int* __restrict__ ei_sp,
                                                const int* __restrict__ ei_gs,
                                                const int* __restrict__ rs_sp,
                                                const int* __restrict__ rs_gs,
                                                int* __restrict__ cur_sp,
                                                int* __restrict__ cur_gs,
                                                int* __restrict__ csr_sp,
                                                int* __restrict__ csr_gs, int E) {
  const int m = blockIdx.x * 256 + threadIdx.x;
  if (m >= E) return;
  {
    const int s = ei_sp[m], d = ei_sp[E + m];
    csr_sp[rs_sp[d] + atomicAdd(&cur_sp[d], 1)] = s;
  }
  {
    const int s = ei_gs[m], d = ei_gs[E + m];
    csr_gs[rs_gs[d] + atomicAdd(&cur_gs[d], 1)] = s;
  }
}

// ---------------- fused layer-1: h_sp, h_gs = bf16(x @ {W_sp, W_gs}) ----------------
// 64-row blocks, 512 threads (8 waves), BK=64 (8 k-steps). Waves 0-3 compute the
// 64x256 h_sp tile (one 64-col quarter each), waves 4-7 h_gs. x fp32 read once,
// converted to bf16 into swizzled LDS by reg-staging; weights via global_load_lds
// with pre-swizzled global source byte (linear LDS dest), swizzled ds_read.
__global__ __launch_bounds__(512) void gemm2_fused(const float* __restrict__ x,
                                                   const unsigned short* __restrict__ wsp,
                                                   const unsigned short* __restrict__ wgs,
                                                   unsigned short* __restrict__ hb_sp,
                                                   unsigned short* __restrict__ hb_gs,
                                                   int M) {
  __shared__ unsigned short sA[64 * 64];       // 8 KB, row stride 128B, XOR-swizzled
  __shared__ unsigned short sW[2][256 * 64];   // 2 x 32 KB, same swizzle
  const int tid = threadIdx.x;
  const int w = tid >> 6, l = tid & 63;
  const int whalf = w >> 2;        // 0 = spatial, 1 = gene
  const int wq = w & 3;            // 64-col quarter of the 256-col output
  const int bm = blockIdx.x * 64;

  // A-load mapping: 2 rounds x 512 threads = 1024 float4 = 64 rows x 16 float4
  const int arow0 = tid >> 4;            // 0..31 (round r adds 32)
  const int acol4 = (tid & 15) * 4;      // fp32 col 0,4,..,60
  // W-staging mapping (per wave: 8 chunks of 1KB of its half's 32KB tile)
  const unsigned short* __restrict__ wtp = whalf ? wgs : wsp;
  const int wrow_in_ch = l >> 3;         // 0..7
  const int wbyte = ((l & 7) * 16) ^ ((wrow_in_ch & 7) << 4);  // pre-swizzled source

  f32x4 acc[4][4] = {};
  for (int k0 = 0; k0 < 512; k0 += 64) {
    __syncthreads();
    // ---- A: fp32 -> bf16 into swizzled LDS ----
#pragma unroll
    for (int r = 0; r < 2; ++r) {
      const int row = arow0 + r * 32;
      int grow = bm + row;
      grow = grow < M ? grow : M - 1;  // clamp; rows discarded on store
      const float4 v = *(const float4*)(x + (size_t)grow * 512 + k0 + acol4);
      ushort4 o;
      o.x = f2bf(v.x); o.y = f2bf(v.y); o.z = f2bf(v.z); o.w = f2bf(v.w);
      const int byte = (row * 128 + acol4 * 2) ^ ((row & 7) << 4);
      *(ushort4*)(((char*)sA) + byte) = o;
    }
    // ---- W: each half stages its own 32KB tile, pre-swizzled source ----
#pragma unroll
    for (int c = 0; c < 8; ++c) {
      const int ch = c * 4 + wq;                       // 0..31
      const int grow = ch * 8 + wrow_in_ch;            // Wt row 0..255
      const char* g = (const char*)wtp + (size_t)grow * 1024 + (size_t)k0 * 2 + wbyte;
      GLOAD16(g, ((char*)sW[whalf]) + ch * 1024);
    }
    __syncthreads();
    // ---- MFMA ----
#pragma unroll
    for (int ks = 0; ks < 2; ++ks) {
      const int cb = ks * 64 + (l >> 4) * 16;  // unswizzled byte-in-row of fragment
      bf16x8 af[4], bf[4];
#pragma unroll
      for (int m = 0; m < 4; ++m) {
        const int r = m * 16 + (l & 15);
        af[m] = *(const bf16x8*)(((const char*)sA) + r * 128 + (cb ^ ((r & 7) << 4)));
      }
#pragma unroll
      for (int n = 0; n < 4; ++n) {
        const int r = wq * 64 + n * 16 + (l & 15);
        bf[n] = *(const bf16x8*)(((const char*)sW[whalf]) + r * 128 + (cb ^ ((r & 7) << 4)));
      }
#pragma unroll
      for (int m = 0; m < 4; ++m)
#pragma unroll
        for (int n = 0; n < 4; ++n)
          acc[m][n] = __builtin_amdgcn_mfma_f32_16x16x32_bf16(af[m], bf[n], acc[m][n], 0, 0, 0);
    }
  }
  unsigned short* __restrict__ outp = whalf ? hb_gs : hb_sp;
#pragma unroll
  for (int m = 0; m < 4; ++m) {
#pragma unroll
    for (int r = 0; r < 4; ++r) {
      const int row = bm + m * 16 + (l >> 4) * 4 + r;
      if (row < M) {
#pragma unroll
        for (int n = 0; n < 4; ++n)
          outp[(size_t)row * 256 + wq * 64 + n * 16 + (l & 15)] = f2bf(acc[m][n][r]);
      }
    }
  }
}

// ---------------- bf16 MFMA GEMM (NT) for fusion layer (256->64) ----------------
template <int BN>
__global__ __launch_bounds__(256) void gemm_bf16_nt(const unsigned short* __restrict__ A,
                                                    const unsigned short* __restrict__ Bt,
                                                    unsigned short* __restrict__ C,
                                                    int M, int Nc, int K) {
  constexpr int BM = 128, BK = 64;
  constexpr int NW = BN / 64;
  constexpr int MW = 4 / NW;
  constexpr int MF = (BM / MW) / 16;
  constexpr int NF = 4;
  constexpr int ACW = (BM * BK * 2 / 1024) / 4;
  constexpr int BCW = (BN * BK * 2 / 1024) / 4;
  __shared__ unsigned short sA[BM * BK];
  __shared__ unsigned short sB[BN * BK];
  const int tid = threadIdx.x;
  const int w = tid >> 6, l = tid & 63;
  const int wr = w / NW, wc = w % NW;
  const int bm = blockIdx.x * BM;
  const int bn = blockIdx.y * BN;
  const int crow = l >> 3;
  const int cbyte = (l & 7) * 16;

  f32x4 acc[MF][NF] = {};
  for (int k0 = 0; k0 < K; k0 += BK) {
    __syncthreads();
#pragma unroll
    for (int c = 0; c < ACW; ++c) {
      const int ch = w * ACW + c;
      int row = bm + ch * 8 + crow;
      row = row < M ? row : M - 1;
      const char* g = (const char*)A + (size_t)row * K * 2 + (size_t)k0 * 2 + cbyte;
      GLOAD16(g, ((char*)sA) + ch * 1024);
    }
#pragma unroll
    for (int c = 0; c < BCW; ++c) {
      const int ch = w * BCW + c;
      const int row = bn + ch * 8 + crow;
      const char* g = (const char*)Bt + (size_t)row * K * 2 + (size_t)k0 * 2 + cbyte;
      GLOAD16(g, ((char*)sB) + ch * 1024);
    }
    __syncthreads();
#pragma unroll
    for (int ks = 0; ks < 2; ++ks) {
      bf16x8 af[MF], bfr[NF];
#pragma unroll
      for (int m = 0; m < MF; ++m) {
        const int r = wr * (BM / MW) + m * 16 + (l & 15);
        af[m] = *(const bf16x8*)&sA[r * BK + ks * 32 + (l >> 4) * 8];
      }
#pragma unroll
      for (int n = 0; n < NF; ++n) {
        const int r = wc * 64 + n * 16 + (l & 15);
        bfr[n] = *(const bf16x8*)&sB[r * BK + ks * 32 + (l >> 4) * 8];
      }
#pragma unroll
      for (int m = 0; m < MF; ++m)
#pragma unroll
        for (int n = 0; n < NF; ++n)
          acc[m][n] = __builtin_amdgcn_mfma_f32_16x16x32_bf16(af[m], bfr[n], acc[m][n], 0, 0, 0);
    }
  }
#pragma unroll
  for (int m = 0; m < MF; ++m) {
#pragma unroll
    for (int r = 0; r < 4; ++r) {
      const int row = bm + wr * (BM / MW) + m * 16 + (l >> 4) * 4 + r;
      if (row < M) {
#pragma unroll
        for (int n = 0; n < NF; ++n)
          C[(size_t)row * Nc + bn + wc * 64 + n * 16 + (l & 15)] = f2bf(acc[m][n][r]);
      }
    }
  }
}

// ---------------- dual alpha dots ----------------
__global__ __launch_bounds__(256) void alpha2_256(const ushort4* __restrict__ hsp,
                                                  const ushort4* __restrict__ hgs,
                                                  const float* __restrict__ av_sp_s,
                                                  const float* __restrict__ av_sp_d,
                                                  const float* __restrict__ av_gs_s,
                                                  const float* __restrict__ av_gs_d,
                                                  float* __restrict__ asrc_sp,
                                                  float* __restrict__ adst_sp,
                                                  float* __restrict__ asrc_gs,
                                                  float* __restrict__ adst_gs, int N) {
  const int wave = (int)((blockIdx.x * (size_t)blockDim.x + threadIdx.x) >> 6);
  const int lane = threadIdx.x & 63;
  if (wave >= N) return;
  const ushort4 h1 = hsp[(size_t)wave * 64 + lane];
  const ushort4 h2 = hgs[(size_t)wave * 64 + lane];
  const float4 s1 = ((const float4*)av_sp_s)[lane];
  const float4 d1 = ((const float4*)av_sp_d)[lane];
  const float4 s2 = ((const float4*)av_gs_s)[lane];
  const float4 d2 = ((const float4*)av_gs_d)[lane];
  const float a0 = bf2f(h1.x), a1 = bf2f(h1.y), a2 = bf2f(h1.z), a3 = bf2f(h1.w);
  const float b0 = bf2f(h2.x), b1 = bf2f(h2.y), b2 = bf2f(h2.z), b3 = bf2f(h2.w);
  float p0 = a0 * s1.x + a1 * s1.y + a2 * s1.z + a3 * s1.w;
  float p1 = a0 * d1.x + a1 * d1.y + a2 * d1.z + a3 * d1.w;
  float p2 = b0 * s2.x + b1 * s2.y + b2 * s2.z + b3 * s2.w;
  float p3 = b0 * d2.x + b1 * d2.y + b2 * d2.z + b3 * d2.w;
#pragma unroll
  for (int off = 32; off; off >>= 1) {
    p0 += __shfl_down(p0, off);
    p1 += __shfl_down(p1, off);
    p2 += __shfl_down(p2, off);
    p3 += __shfl_down(p3, off);
  }
  if (lane == 0) {
    asrc_sp[wave] = p0; adst_sp[wave] = p1;
    asrc_gs[wave] = p2; adst_gs[wave] = p3;
  }
}

__global__ __launch_bounds__(256) void alpha64(const unsigned short* __restrict__ h,
                                               const float* __restrict__ a_src,
                                               const float* __restrict__ a_dst,
                                               float* __restrict__ asrc,
                                               float* __restrict__ adst, int N) {
  const int wave = (int)((blockIdx.x * (size_t)blockDim.x + threadIdx.x) >> 6);
  const int lane = threadIdx.x & 63;
  if (wave >= N) return;
  const float hv = bf2f(h[(size_t)wave * 64 + lane]);
  float ps = hv * a_src[lane];
  float pd = hv * a_dst[lane];
#pragma unroll
  for (int off = 32; off; off >>= 1) {
    ps += __shfl_down(ps, off);
    pd += __shfl_down(pd, off);
  }
  if (lane == 0) { asrc[wave] = ps; adst[wave] = pd; }
}

// ---------------- fused CSR aggregation, H=256, bf16 h ----------------
template <int EPI>
__global__ __launch_bounds__(256) void agg_csr256(const int* __restrict__ rs,
                                                  const int* __restrict__ csr,
                                                  const float* __restrict__ asrc,
                                                  const float* __restrict__ adst,
                                                  const ushort4* __restrict__ h4,
                                                  const float* __restrict__ bias,
                                                  const ushort4* __restrict__ other16,
                                                  ushort4* __restrict__ out16, int N) {
  const int d = (int)((blockIdx.x * (size_t)blockDim.x + threadIdx.x) >> 6);
  const int lane = threadIdx.x & 63;
  if (d >= N) return;
  const float ad = adst[d];

  float e = asrc[d] + ad;
  e = e > 0.f ? e : NEG_SLOPE * e;
  const float wself = expf(e);
  float denl = (lane == 0) ? wself : 0.f;
  const ushort4 hv = h4[(size_t)d * 64 + lane];
  float ax = wself * bf2f(hv.x), ay = wself * bf2f(hv.y),
        az = wself * bf2f(hv.z), aw = wself * bf2f(hv.w);

  const int base = rs[d], mend = rs[d + 1];
  for (int c = base; c < mend; c += 64) {
    const int m = c + lane;
    int s = 0;
    float w = 0.f;
    if (m < mend) {
      s = csr[m];
      float e2 = asrc[s] + ad;
      e2 = e2 > 0.f ? e2 : NEG_SLOPE * e2;
      w = expf(e2);
    }
    denl += w;
    const int cnt = min(64, mend - c);
    int j = 0;
    for (; j + 3 < cnt; j += 4) {
      const int s0 = rl_i(s, j), s1 = rl_i(s, j + 1), s2 = rl_i(s, j + 2), s3 = rl_i(s, j + 3);
      const float w0 = rl_f(w, j), w1 = rl_f(w, j + 1), w2 = rl_f(w, j + 2), w3 = rl_f(w, j + 3);
      const ushort4 a0 = h4[(size_t)s0 * 64 + lane];
      const ushort4 a1 = h4[(size_t)s1 * 64 + lane];
      const ushort4 a2 = h4[(size_t)s2 * 64 + lane];
      const ushort4 a3 = h4[(size_t)s3 * 64 + lane];
      ax += w0 * bf2f(a0.x) + w1 * bf2f(a1.x) + w2 * bf2f(a2.x) + w3 * bf2f(a3.x);
      ay += w0 * bf2f(a0.y) + w1 * bf2f(a1.y) + w2 * bf2f(a2.y) + w3 * bf2f(a3.y);
      az += w0 * bf2f(a0.z) + w1 * bf2f(a1.z) + w2 * bf2f(a2.z) + w3 * bf2f(a3.z);
      aw += w0 * bf2f(a0.w) + w1 * bf2f(a1.w) + w2 * bf2f(a2.w) + w3 * bf2f(a3.w);
    }
    for (; j < cnt; ++j) {
      const int sj = rl_i(s, j);
      const float wj = rl_f(w, j);
      const ushort4 aj = h4[(size_t)sj * 64 + lane];
      ax += wj * bf2f(aj.x);
      ay += wj * bf2f(aj.y);
      az += wj * bf2f(aj.z);
      aw += wj * bf2f(aj.w);
    }
  }
#pragma unroll
  for (int off = 32; off; off >>= 1) denl += __shfl_xor(denl, off);
  const float inv = 1.f / denl;

  const float4 b4 = ((const float4*)bias)[lane];
  float v[4] = {ax * inv + b4.x, ay * inv + b4.y, az * inv + b4.z, aw * inv + b4.w};
#pragma unroll
  for (int j = 0; j < 4; ++j) v[j] = v[j] > 0.f ? v[j] : (expf(v[j]) - 1.f);
  ushort4 pk;
  if (EPI == 2) {
    const ushort4 ov = other16[(size_t)d * 64 + lane];
    pk.x = f2bf(0.5f * v[0] + 0.5f * bf2f(ov.x));
    pk.y = f2bf(0.5f * v[1] + 0.5f * bf2f(ov.y));
    pk.z = f2bf(0.5f * v[2] + 0.5f * bf2f(ov.z));
    pk.w = f2bf(0.5f * v[3] + 0.5f * bf2f(ov.w));
  } else {
    pk.x = f2bf(v[0]); pk.y = f2bf(v[1]); pk.z = f2bf(v[2]); pk.w = f2bf(v[3]);
  }
  out16[(size_t)d * 64 + lane] = pk;
}

// ---------------- fused CSR aggregation, H=64, bf16 h -> fp32 d_out ----------------
__global__ __launch_bounds__(256) void agg_csr64(const int* __restrict__ rs,
                                                 const int* __restrict__ csr,
                                                 const float* __restrict__ asrc,
                                                 const float* __restrict__ adst,
                                                 const unsigned short* __restrict__ h,
                                                 const float* __restrict__ bias,
                                                 float* __restrict__ outb, int N) {
  const int d = (int)((blockIdx.x * (size_t)blockDim.x + threadIdx.x) >> 6);
  const int lane = threadIdx.x & 63;
  if (d >= N) return;
  const float ad = adst[d];

  float e = asrc[d] + ad;
  e = e > 0.f ? e : NEG_SLOPE * e;
  const float wself = expf(e);
  float denl = (lane == 0) ? wself : 0.f;
  float acc = wself * bf2f(h[(size_t)d * 64 + lane]);

  const int base = rs[d], mend = rs[d + 1];
  for (int c = base; c < mend; c += 64) {
    const int m = c + lane;
    int s = 0;
    float w = 0.f;
    if (m < mend) {
      s = csr[m];
      float e2 = asrc[s] + ad;
      e2 = e2 > 0.f ? e2 : NEG_SLOPE * e2;
      w = expf(e2);
    }
    denl += w;
    const int cnt = min(64, mend - c);
    int j = 0;
    for (; j + 3 < cnt; j += 4) {
      const int s0 = rl_i(s, j), s1 = rl_i(s, j + 1), s2 = rl_i(s, j + 2), s3 = rl_i(s, j + 3);
      const float w0 = rl_f(w, j), w1 = rl_f(w, j + 1), w2 = rl_f(w, j + 2), w3 = rl_f(w, j + 3);
      const float a0 = bf2f(h[(size_t)s0 * 64 + lane]);
      const float a1 = bf2f(h[(size_t)s1 * 64 + lane]);
      const float a2 = bf2f(h[(size_t)s2 * 64 + lane]);
      const float a3 = bf2f(h[(size_t)s3 * 64 + lane]);
      acc += w0 * a0 + w1 * a1 + w2 * a2 + w3 * a3;
    }
    for (; j < cnt; ++j) {
      const int sj = rl_i(s, j);
      const float wj = rl_f(w, j);
      acc += wj * bf2f(h[(size_t)sj * 64 + lane]);
    }
  }
#pragma unroll
  for (int off = 32; off; off >>= 1) denl += __shfl_xor(denl, off);
  outb[(size_t)d * 64 + lane] = acc / denl + bias[lane];
}

extern "C" void kernel_launch(void* const* d_in, const int* in_sizes, int n_in,
                              void* d_out, int out_size, void* d_ws, size_t ws_size,
                              hipStream_t stream) {
  const float* x        = (const float*)d_in[0];
  const int*   ei_sp    = (const int*)d_in[1];
  const int*   ei_gs    = (const int*)d_in[2];
  const float* W_sp     = (const float*)d_in[3];
  const float* a_src_sp = (const float*)d_in[4];
  const float* a_dst_sp = (const float*)d_in[5];
  const float* b_sp     = (const float*)d_in[6];
  const float* W_gs     = (const float*)d_in[7];
  const float* a_src_gs = (const float*)d_in[8];
  const float* a_dst_gs = (const float*)d_in[9];
  const float* b_gs     = (const float*)d_in[10];
  const float* W_fu     = (const float*)d_in[11];
  const float* a_src_fu = (const float*)d_in[12];
  const float* a_dst_fu = (const float*)d_in[13];
  const float* b_fu     = (const float*)d_in[14];
  float* out = (float*)d_out;

  const int N = in_sizes[0] / 512;
  const int E = in_sizes[1] / 2;
  const int nb = (N + 255) / 256;

  // ---- workspace layout ----
  unsigned short* wt_sp = (unsigned short*)d_ws;       // 256*512
  unsigned short* wt_gs = wt_sp + 256 * 512;           // 256*512
  unsigned short* wt_fu = wt_gs + 256 * 512;           // 64*256
  unsigned short* hb_sp = wt_fu + 64 * 256;            // N*256 bf16
  unsigned short* hb_gs = hb_sp + (size_t)N * 256;     // N*256 bf16
  unsigned short* B3    = hb_gs + (size_t)N * 256;     // N*256 bf16 (later hfu N*64)
  unsigned short* hfb   = B3 + (size_t)N * 256;        // N*256 bf16 h_fused
  float* asrc_sp = (float*)(hfb + (size_t)N * 256);    // N
  float* adst_sp = asrc_sp + N;                        // N
  float* asrc_gs = adst_sp + N;                        // N
  float* adst_gs = asrc_gs + N;                        // N
  int* rs_sp  = (int*)(adst_gs + N);                   // N+1
  int* rs_gs  = rs_sp + (N + 1);                       // N+1
  int* csr_sp = rs_gs + (N + 1);                       // E
  int* csr_gs = csr_sp + E;                            // E
  int* deg_sp = csr_gs + E;                            // N
  int* deg_gs = deg_sp + N;                            // N
  int* parts2 = deg_gs + N;                            // 2*512

  unsigned short* hfu = B3;                            // [N][64] bf16 (B3 dead)

  const int BLK = 256;
  const int eGrid = (E + BLK - 1) / BLK;
  const int nodeWaveGrid = (N + 3) / 4;
  const dim3 gFu((N + 127) / 128, 1);

  // ---- CSR builds (both graphs) ----
  hipMemsetAsync(deg_sp, 0, (size_t)2 * N * 4, stream);
  hist2<<<eGrid, BLK, 0, stream>>>(ei_sp + E, ei_gs + E, deg_sp, deg_gs, E);
  scan1_2<<<dim3(nb, 2), BLK, 0, stream>>>(deg_sp, deg_gs, rs_sp, rs_gs, parts2, N);
  scan2_2<<<2, 512, 0, stream>>>(parts2, nb);
  scan3_2<<<dim3(nb, 2), BLK, 0, stream>>>(rs_sp, rs_gs, parts2, N, E);
  hipMemsetAsync(deg_sp, 0, (size_t)2 * N * 4, stream);
  scatter2<<<eGrid, BLK, 0, stream>>>(ei_sp, ei_gs, rs_sp, rs_gs, deg_sp, deg_gs,
                                      csr_sp, csr_gs, E);

  // ---- weight conversions (one launch) ----
  wt_bf16_all<<<(278528 + 255) / 256, BLK, 0, stream>>>(W_sp, W_gs, W_fu,
                                                        wt_sp, wt_gs, wt_fu);

  // ---- fused layer-1 GEMMs: x read once ----
  gemm2_fused<<<(N + 63) / 64, 512, 0, stream>>>(x, wt_sp, wt_gs, hb_sp, hb_gs, N);

  // ---- dual alpha ----
  alpha2_256<<<nodeWaveGrid, BLK, 0, stream>>>((const ushort4*)hb_sp,
                                               (const ushort4*)hb_gs,
                                               a_src_sp, a_dst_sp, a_src_gs, a_dst_gs,
                                               asrc_sp, adst_sp, asrc_gs, adst_gs, N);

  // ---- spatial conv -> B3 = bf16(elu(agg+b_sp)) ----
  agg_csr256<1><<<nodeWaveGrid, BLK, 0, stream>>>(rs_sp, csr_sp, asrc_sp, adst_sp,
                                                  (const ushort4*)hb_sp, b_sp,
                                                  nullptr, (ushort4*)B3, N);

  // ---- gene conv + blend -> h_fused bf16 ----
  agg_csr256<2><<<nodeWaveGrid, BLK, 0, stream>>>(rs_gs, csr_gs, asrc_gs, adst_gs,
                                                  (const ushort4*)hb_gs, b_gs,
                                                  (const ushort4*)B3, (ushort4*)hfb, N);

  // ---- fusion conv (256->64, spatial graph) ----
  gemm_bf16_nt<64><<<gFu, BLK, 0, stream>>>(hfb, wt_fu, hfu, N, 64, 256);
  alpha64<<<nodeWaveGrid, BLK, 0, stream>>>(hfu, a_src_fu, a_dst_fu,
                                            asrc_sp, adst_sp, N);
  agg_csr64<<<nodeWaveGrid, BLK, 0, stream>>>(rs_sp, csr_sp, asrc_sp, adst_sp,
                                              hfu, b_fu, out, N);
}

// Round 8
// 507.534 us; speedup vs baseline: 15.4146x; 1.0390x over previous
//
#include <hip/hip_runtime.h>
#include <math.h>

// Round 8: (1) CSR scatter de-atomized — hist2 stores the atomicAdd-returned
// ordinal per edge; scatter2 computes slot = rs[d] + ord[m] with no atomics and
// no cursor memset. (2) gemm2_fused software-pipelines the x row loads: regs
// prefetched one k-step ahead, issued after the draining barrier so the HBM
// latency hides under MFMA; raw s_barrier (no drain) guards the LDS overwrite.

#define NEG_SLOPE 0.2f

typedef __attribute__((ext_vector_type(8))) short bf16x8;
typedef __attribute__((ext_vector_type(4))) float f32x4;

__device__ __forceinline__ unsigned short f2bf(float f) {
  unsigned int u = __float_as_uint(f);
  u = (u + 0x7FFFu + ((u >> 16) & 1u)) >> 16;  // RNE
  return (unsigned short)u;
}
__device__ __forceinline__ float bf2f(unsigned short u) {
  return __uint_as_float((unsigned int)u << 16);
}
__device__ __forceinline__ int rl_i(int v, int l) {
  return __builtin_amdgcn_readlane(v, l);
}
__device__ __forceinline__ float rl_f(float v, int l) {
  return __uint_as_float(__builtin_amdgcn_readlane(__float_as_uint(v), l));
}

#define GLOAD16(g, l)                                                   \
  __builtin_amdgcn_global_load_lds(                                     \
      (const __attribute__((address_space(1))) void*)(g),               \
      (__attribute__((address_space(3))) void*)(l), 16, 0, 0)

// ---------------- weight conversions (all three in one launch) ----------------
__global__ __launch_bounds__(256) void wt_bf16_all(const float* __restrict__ W_sp,
                                                   const float* __restrict__ W_gs,
                                                   const float* __restrict__ W_fu,
                                                   unsigned short* __restrict__ wt_sp,
                                                   unsigned short* __restrict__ wt_gs,
                                                   unsigned short* __restrict__ wt_fu) {
  const int i = blockIdx.x * 256 + threadIdx.x;
  if (i < 131072) {                       // 512x256 spatial
    const int k = i >> 8, n = i & 255;
    wt_sp[n * 512 + k] = f2bf(W_sp[i]);
  } else if (i < 262144) {                // 512x256 gene
    const int j = i - 131072;
    const int k = j >> 8, n = j & 255;
    wt_gs[n * 512 + k] = f2bf(W_gs[j]);
  } else if (i < 278528) {                // 256x64 fusion
    const int j = i - 262144;
    const int k = j >> 6, n = j & 63;
    wt_fu[n * 256 + k] = f2bf(W_fu[j]);
  }
}

// ---------------- CSR build ----------------
// hist2 also records each edge's within-dst ordinal (the atomicAdd return).
__global__ __launch_bounds__(256) void hist2(const int* __restrict__ dst_sp,
                                             const int* __restrict__ dst_gs,
                                             int* __restrict__ deg_sp,
                                             int* __restrict__ deg_gs,
                                             int* __restrict__ ord_sp,
                                             int* __restrict__ ord_gs, int E) {
  const int m = blockIdx.x * 256 + threadIdx.x;
  if (m < E) {
    ord_sp[m] = atomicAdd(&deg_sp[dst_sp[m]], 1);
    ord_gs[m] = atomicAdd(&deg_gs[dst_gs[m]], 1);
  }
}

__global__ __launch_bounds__(256) void scan1_2(const int* __restrict__ deg_sp,
                                               const int* __restrict__ deg_gs,
                                               int* __restrict__ rs_sp,
                                               int* __restrict__ rs_gs,
                                               int* __restrict__ parts2, int N) {
  __shared__ int sm[256];
  const int* deg = blockIdx.y ? deg_gs : deg_sp;
  int* rs = blockIdx.y ? rs_gs : rs_sp;
  int* parts = parts2 + blockIdx.y * 512;
  const int i = blockIdx.x * 256 + threadIdx.x;
  const int v = (i < N) ? deg[i] : 0;
  sm[threadIdx.x] = v;
  __syncthreads();
  for (int off = 1; off < 256; off <<= 1) {
    const int x = (threadIdx.x >= off) ? sm[threadIdx.x - off] : 0;
    __syncthreads();
    sm[threadIdx.x] += x;
    __syncthreads();
  }
  if (i < N) rs[i] = sm[threadIdx.x] - v;
  if (threadIdx.x == 255) parts[blockIdx.x] = sm[255];
}

__global__ __launch_bounds__(512) void scan2_2(int* __restrict__ parts2, int nb) {
  __shared__ int sm[512];
  int* parts = parts2 + blockIdx.x * 512;
  const int t = threadIdx.x;
  const int v = (t < nb) ? parts[t] : 0;
  sm[t] = v;
  __syncthreads();
  for (int off = 1; off < 512; off <<= 1) {
    const int x = (t >= off) ? sm[t - off] : 0;
    __syncthreads();
    sm[t] += x;
    __syncthreads();
  }
  if (t < nb) parts[t] = sm[t] - v;
}

__global__ __launch_bounds__(256) void scan3_2(int* __restrict__ rs_sp,
                                               int* __restrict__ rs_gs,
                                               const int* __restrict__ parts2,
                                               int N, int E) {
  int* rs = blockIdx.y ? rs_gs : rs_sp;
  const int* parts = parts2 + blockIdx.y * 512;
  const int i = blockIdx.x * 256 + threadIdx.x;
  if (i < N) rs[i] += parts[blockIdx.x];
  if (i == 0) rs[N] = E;
}

// atomic-free scatter: slot = rs[dst] + ord
__global__ __launch_bounds__(256) void scatter2(const int* __restrict__ ei_sp,
                                                const int* __restrict__ ei_gs,
                                                const int* __restrict__ rs_sp,
                                                const int* __restrict__ rs_gs,
                                                const int* __restrict__ ord_sp,
                                                const int* __restrict__ ord_gs,
                                                int* __restrict__ csr_sp,
                                                int* __restrict__ csr_gs, int E) {
  const int m = blockIdx.x * 256 + threadIdx.x;
  if (m >= E) return;
  csr_sp[rs_sp[ei_sp[E + m]] + ord_sp[m]] = ei_sp[m];
  csr_gs[rs_gs[ei_gs[E + m]] + ord_gs[m]] = ei_gs[m];
}

// ---------------- fused layer-1: h_sp, h_gs = bf16(x @ {W_sp, W_gs}) ----------------
// 64-row blocks, 512 threads (8 waves), BK=64. Waves 0-3: h_sp (one 64-col quarter
// each), waves 4-7: h_gs. x read once; reg-prefetched one k-step ahead (issued
// after the draining barrier so HBM latency hides under MFMA). XOR-swizzled LDS.
__global__ __launch_bounds__(512) void gemm2_fused(const float* __restrict__ x,
                                                   const unsigned short* __restrict__ wsp,
                                                   const unsigned short* __restrict__ wgs,
                                                   unsigned short* __restrict__ hb_sp,
                                                   unsigned short* __restrict__ hb_gs,
                                                   int M) {
  __shared__ unsigned short sA[64 * 64];       // 8 KB, swizzled
  __shared__ unsigned short sW[2][256 * 64];   // 2 x 32 KB, swizzled
  const int tid = threadIdx.x;
  const int w = tid >> 6, l = tid & 63;
  const int whalf = w >> 2;
  const int wq = w & 3;
  const int bm = blockIdx.x * 64;

  // A-load mapping: 2 rows per thread (arow0, arow0+32), one float4 each
  const int arow0 = tid >> 4;
  const int acol4 = (tid & 15) * 4;
  int g0 = bm + arow0;      g0 = g0 < M ? g0 : M - 1;
  int g1 = bm + arow0 + 32; g1 = g1 < M ? g1 : M - 1;
  const float* __restrict__ ap0 = x + (size_t)g0 * 512 + acol4;
  const float* __restrict__ ap1 = x + (size_t)g1 * 512 + acol4;
  const int abyte0 = (arow0 * 128 + acol4 * 2) ^ ((arow0 & 7) << 4);
  const int abyte1 = ((arow0 + 32) * 128 + acol4 * 2) ^ (((arow0 + 32) & 7) << 4);

  const unsigned short* __restrict__ wtp = whalf ? wgs : wsp;
  const int wrow_in_ch = l >> 3;
  const int wbyte = ((l & 7) * 16) ^ ((wrow_in_ch & 7) << 4);

  f32x4 acc[4][4] = {};
  float4 xr0 = *(const float4*)ap0;   // prologue prefetch for k0=0
  float4 xr1 = *(const float4*)ap1;
  for (int k0 = 0; k0 < 512; k0 += 64) {
    __builtin_amdgcn_s_barrier();  // raw (no drain): prev MFMA done with LDS;
                                   // in-flight x prefetch regs survive this
    // ---- A: cvt + swizzled ds_write (auto-waits the prefetched regs) ----
    {
      ushort4 o0, o1;
      o0.x = f2bf(xr0.x); o0.y = f2bf(xr0.y); o0.z = f2bf(xr0.z); o0.w = f2bf(xr0.w);
      o1.x = f2bf(xr1.x); o1.y = f2bf(xr1.y); o1.z = f2bf(xr1.z); o1.w = f2bf(xr1.w);
      *(ushort4*)(((char*)sA) + abyte0) = o0;
      *(ushort4*)(((char*)sA) + abyte1) = o1;
    }
    // ---- W: each half stages its own 32KB tile, pre-swizzled source ----
#pragma unroll
    for (int c = 0; c < 8; ++c) {
      const int ch = c * 4 + wq;
      const int grow = ch * 8 + wrow_in_ch;
      const char* g = (const char*)wtp + (size_t)grow * 1024 + (size_t)k0 * 2 + wbyte;
      GLOAD16(g, ((char*)sW[whalf]) + ch * 1024);
    }
    __syncthreads();  // full drain: W + sA visible to all
    // ---- prefetch next x (latency hides under MFMA below) ----
    if (k0 < 448) {
      xr0 = *(const float4*)(ap0 + k0 + 64);
      xr1 = *(const float4*)(ap1 + k0 + 64);
    }
    asm volatile("" ::: "memory");  // pin prefetch issue before the MFMA cluster
    // ---- MFMA ----
#pragma unroll
    for (int ks = 0; ks < 2; ++ks) {
      const int cb = ks * 64 + (l >> 4) * 16;
      bf16x8 af[4], bf[4];
#pragma unroll
      for (int m = 0; m < 4; ++m) {
        const int r = m * 16 + (l & 15);
        af[m] = *(const bf16x8*)(((const char*)sA) + r * 128 + (cb ^ ((r & 7) << 4)));
      }
#pragma unroll
      for (int n = 0; n < 4; ++n) {
        const int r = wq * 64 + n * 16 + (l & 15);
        bf[n] = *(const bf16x8*)(((const char*)sW[whalf]) + r * 128 + (cb ^ ((r & 7) << 4)));
      }
#pragma unroll
      for (int m = 0; m < 4; ++m)
#pragma unroll
        for (int n = 0; n < 4; ++n)
          acc[m][n] = __builtin_amdgcn_mfma_f32_16x16x32_bf16(af[m], bf[n], acc[m][n], 0, 0, 0);
    }
  }
  unsigned short* __restrict__ outp = whalf ? hb_gs : hb_sp;
#pragma unroll
  for (int m = 0; m < 4; ++m) {
#pragma unroll
    for (int r = 0; r < 4; ++r) {
      const int row = bm + m * 16 + (l >> 4) * 4 + r;
      if (row < M) {
#pragma unroll
        for (int n = 0; n < 4; ++n)
          outp[(size_t)row * 256 + wq * 64 + n * 16 + (l & 15)] = f2bf(acc[m][n][r]);
      }
    }
  }
}

// ---------------- bf16 MFMA GEMM (NT) for fusion layer (256->64) ----------------
template <int BN>
__global__ __launch_bounds__(256) void gemm_bf16_nt(const unsigned short* __restrict__ A,
                                                    const unsigned short* __restrict__ Bt,
                                                    unsigned short* __restrict__ C,
                                                    int M, int Nc, int K) {
  constexpr int BM = 128, BK = 64;
  constexpr int NW = BN / 64;
  constexpr int MW = 4 / NW;
  constexpr int MF = (BM / MW) / 16;
  constexpr int NF = 4;
  constexpr int ACW = (BM * BK * 2 / 1024) / 4;
  constexpr int BCW = (BN * BK * 2 / 1024) / 4;
  __shared__ unsigned short sA[BM * BK];
  __shared__ unsigned short sB[BN * BK];
  const int tid = threadIdx.x;
  const int w = tid >> 6, l = tid & 63;
  const int wr = w / NW, wc = w % NW;
  const int bm = blockIdx.x * BM;
  const int bn = blockIdx.y * BN;
  const int crow = l >> 3;
  const int cbyte = (l & 7) * 16;

  f32x4 acc[MF][NF] = {};
  for (int k0 = 0; k0 < K; k0 += BK) {
    __syncthreads();
#pragma unroll
    for (int c = 0; c < ACW; ++c) {
      const int ch = w * ACW + c;
      int row = bm + ch * 8 + crow;
      row = row < M ? row : M - 1;
      const char* g = (const char*)A + (size_t)row * K * 2 + (size_t)k0 * 2 + cbyte;
      GLOAD16(g, ((char*)sA) + ch * 1024);
    }
#pragma unroll
    for (int c = 0; c < BCW; ++c) {
      const int ch = w * BCW + c;
      const int row = bn + ch * 8 + crow;
      const char* g = (const char*)Bt + (size_t)row * K * 2 + (size_t)k0 * 2 + cbyte;
      GLOAD16(g, ((char*)sB) + ch * 1024);
    }
    __syncthreads();
#pragma unroll
    for (int ks = 0; ks < 2; ++ks) {
      bf16x8 af[MF], bfr[NF];
#pragma unroll
      for (int m = 0; m < MF; ++m) {
        const int r = wr * (BM / MW) + m * 16 + (l & 15);
        af[m] = *(const bf16x8*)&sA[r * BK + ks * 32 + (l >> 4) * 8];
      }
#pragma unroll
      for (int n = 0; n < NF; ++n) {
        const int r = wc * 64 + n * 16 + (l & 15);
        bfr[n] = *(const bf16x8*)&sB[r * BK + ks * 32 + (l >> 4) * 8];
      }
#pragma unroll
      for (int m = 0; m < MF; ++m)
#pragma unroll
        for (int n = 0; n < NF; ++n)
          acc[m][n] = __builtin_amdgcn_mfma_f32_16x16x32_bf16(af[m], bfr[n], acc[m][n], 0, 0, 0);
    }
  }
#pragma unroll
  for (int m = 0; m < MF; ++m) {
#pragma unroll
    for (int r = 0; r < 4; ++r) {
      const int row = bm + wr * (BM / MW) + m * 16 + (l >> 4) * 4 + r;
      if (row < M) {
#pragma unroll
        for (int n = 0; n < NF; ++n)
          C[(size_t)row * Nc + bn + wc * 64 + n * 16 + (l & 15)] = f2bf(acc[m][n][r]);
      }
    }
  }
}

// ---------------- dual alpha dots ----------------
__global__ __launch_bounds__(256) void alpha2_256(const ushort4* __restrict__ hsp,
                                                  const ushort4* __restrict__ hgs,
                                                  const float* __restrict__ av_sp_s,
                                                  const float* __restrict__ av_sp_d,
                                                  const float* __restrict__ av_gs_s,
                                                  const float* __restrict__ av_gs_d,
                                                  float* __restrict__ asrc_sp,
                                                  float* __restrict__ adst_sp,
                                                  float* __restrict__ asrc_gs,
                                                  float* __restrict__ adst_gs, int N) {
  const int wave = (int)((blockIdx.x * (size_t)blockDim.x + threadIdx.x) >> 6);
  const int lane = threadIdx.x & 63;
  if (wave >= N) return;
  const ushort4 h1 = hsp[(size_t)wave * 64 + lane];
  const ushort4 h2 = hgs[(size_t)wave * 64 + lane];
  const float4 s1 = ((const float4*)av_sp_s)[lane];
  const float4 d1 = ((const float4*)av_sp_d)[lane];
  const float4 s2 = ((const float4*)av_gs_s)[lane];
  const float4 d2 = ((const float4*)av_gs_d)[lane];
  const float a0 = bf2f(h1.x), a1 = bf2f(h1.y), a2 = bf2f(h1.z), a3 = bf2f(h1.w);
  const float b0 = bf2f(h2.x), b1 = bf2f(h2.y), b2 = bf2f(h2.z), b3 = bf2f(h2.w);
  float p0 = a0 * s1.x + a1 * s1.y + a2 * s1.z + a3 * s1.w;
  float p1 = a0 * d1.x + a1 * d1.y + a2 * d1.z + a3 * d1.w;
  float p2 = b0 * s2.x + b1 * s2.y + b2 * s2.z + b3 * s2.w;
  float p3 = b0 * d2.x + b1 * d2.y + b2 * d2.z + b3 * d2.w;
#pragma unroll
  for (int off = 32; off; off >>= 1) {
    p0 += __shfl_down(p0, off);
    p1 += __shfl_down(p1, off);
    p2 += __shfl_down(p2, off);
    p3 += __shfl_down(p3, off);
  }
  if (lane == 0) {
    asrc_sp[wave] = p0; adst_sp[wave] = p1;
    asrc_gs[wave] = p2; adst_gs[wave] = p3;
  }
}

__global__ __launch_bounds__(256) void alpha64(const unsigned short* __restrict__ h,
                                               const float* __restrict__ a_src,
                                               const float* __restrict__ a_dst,
                                               float* __restrict__ asrc,
                                               float* __restrict__ adst, int N) {
  const int wave = (int)((blockIdx.x * (size_t)blockDim.x + threadIdx.x) >> 6);
  const int lane = threadIdx.x & 63;
  if (wave >= N) return;
  const float hv = bf2f(h[(size_t)wave * 64 + lane]);
  float ps = hv * a_src[lane];
  float pd = hv * a_dst[lane];
#pragma unroll
  for (int off = 32; off; off >>= 1) {
    ps += __shfl_down(ps, off);
    pd += __shfl_down(pd, off);
  }
  if (lane == 0) { asrc[wave] = ps; adst[wave] = pd; }
}

// ---------------- fused CSR aggregation, H=256, bf16 h ----------------
template <int EPI>
__global__ __launch_bounds__(256) void agg_csr256(const int* __restrict__ rs,
                                                  const int* __restrict__ csr,
                                                  const float* __restrict__ asrc,
                                                  const float* __restrict__ adst,
                                                  const ushort4* __restrict__ h4,
                                                  const float* __restrict__ bias,
                                                  const ushort4* __restrict__ other16,
                                                  ushort4* __restrict__ out16, int N) {
  const int d = (int)((blockIdx.x * (size_t)blockDim.x + threadIdx.x) >> 6);
  const int lane = threadIdx.x & 63;
  if (d >= N) return;
  const float ad = adst[d];

  float e = asrc[d] + ad;
  e = e > 0.f ? e : NEG_SLOPE * e;
  const float wself = expf(e);
  float denl = (lane == 0) ? wself : 0.f;
  const ushort4 hv = h4[(size_t)d * 64 + lane];
  float ax = wself * bf2f(hv.x), ay = wself * bf2f(hv.y),
        az = wself * bf2f(hv.z), aw = wself * bf2f(hv.w);

  const int base = rs[d], mend = rs[d + 1];
  for (int c = base; c < mend; c += 64) {
    const int m = c + lane;
    int s = 0;
    float w = 0.f;
    if (m < mend) {
      s = csr[m];
      float e2 = asrc[s] + ad;
      e2 = e2 > 0.f ? e2 : NEG_SLOPE * e2;
      w = expf(e2);
    }
    denl += w;
    const int cnt = min(64, mend - c);
    int j = 0;
    for (; j + 3 < cnt; j += 4) {
      const int s0 = rl_i(s, j), s1 = rl_i(s, j + 1), s2 = rl_i(s, j + 2), s3 = rl_i(s, j + 3);
      const float w0 = rl_f(w, j), w1 = rl_f(w, j + 1), w2 = rl_f(w, j + 2), w3 = rl_f(w, j + 3);
      const ushort4 a0 = h4[(size_t)s0 * 64 + lane];
      const ushort4 a1 = h4[(size_t)s1 * 64 + lane];
      const ushort4 a2 = h4[(size_t)s2 * 64 + lane];
      const ushort4 a3 = h4[(size_t)s3 * 64 + lane];
      ax += w0 * bf2f(a0.x) + w1 * bf2f(a1.x) + w2 * bf2f(a2.x) + w3 * bf2f(a3.x);
      ay += w0 * bf2f(a0.y) + w1 * bf2f(a1.y) + w2 * bf2f(a2.y) + w3 * bf2f(a3.y);
      az += w0 * bf2f(a0.z) + w1 * bf2f(a1.z) + w2 * bf2f(a2.z) + w3 * bf2f(a3.z);
      aw += w0 * bf2f(a0.w) + w1 * bf2f(a1.w) + w2 * bf2f(a2.w) + w3 * bf2f(a3.w);
    }
    for (; j < cnt; ++j) {
      const int sj = rl_i(s, j);
      const float wj = rl_f(w, j);
      const ushort4 aj = h4[(size_t)sj * 64 + lane];
      ax += wj * bf2f(aj.x);
      ay += wj * bf2f(aj.y);
      az += wj * bf2f(aj.z);
      aw += wj * bf2f(aj.w);
    }
  }
#pragma unroll
  for (int off = 32; off; off >>= 1) denl += __shfl_xor(denl, off);
  const float inv = 1.f / denl;

  const float4 b4 = ((const float4*)bias)[lane];
  float v[4] = {ax * inv + b4.x, ay * inv + b4.y, az * inv + b4.z, aw * inv + b4.w};
#pragma unroll
  for (int j = 0; j < 4; ++j) v[j] = v[j] > 0.f ? v[j] : (expf(v[j]) - 1.f);
  ushort4 pk;
  if (EPI == 2) {
    const ushort4 ov = other16[(size_t)d * 64 + lane];
    pk.x = f2bf(0.5f * v[0] + 0.5f * bf2f(ov.x));
    pk.y = f2bf(0.5f * v[1] + 0.5f * bf2f(ov.y));
    pk.z = f2bf(0.5f * v[2] + 0.5f * bf2f(ov.z));
    pk.w = f2bf(0.5f * v[3] + 0.5f * bf2f(ov.w));
  } else {
    pk.x = f2bf(v[0]); pk.y = f2bf(v[1]); pk.z = f2bf(v[2]); pk.w = f2bf(v[3]);
  }
  out16[(size_t)d * 64 + lane] = pk;
}

// ---------------- fused CSR aggregation, H=64, bf16 h -> fp32 d_out ----------------
__global__ __launch_bounds__(256) void agg_csr64(const int* __restrict__ rs,
                                                 const int* __restrict__ csr,
                                                 const float* __restrict__ asrc,
                                                 const float* __restrict__ adst,
                                                 const unsigned short* __restrict__ h,
                                                 const float* __restrict__ bias,
                                                 float* __restrict__ outb, int N) {
  const int d = (int)((blockIdx.x * (size_t)blockDim.x + threadIdx.x) >> 6);
  const int lane = threadIdx.x & 63;
  if (d >= N) return;
  const float ad = adst[d];

  float e = asrc[d] + ad;
  e = e > 0.f ? e : NEG_SLOPE * e;
  const float wself = expf(e);
  float denl = (lane == 0) ? wself : 0.f;
  float acc = wself * bf2f(h[(size_t)d * 64 + lane]);

  const int base = rs[d], mend = rs[d + 1];
  for (int c = base; c < mend; c += 64) {
    const int m = c + lane;
    int s = 0;
    float w = 0.f;
    if (m < mend) {
      s = csr[m];
      float e2 = asrc[s] + ad;
      e2 = e2 > 0.f ? e2 : NEG_SLOPE * e2;
      w = expf(e2);
    }
    denl += w;
    const int cnt = min(64, mend - c);
    int j = 0;
    for (; j + 3 < cnt; j += 4) {
      const int s0 = rl_i(s, j), s1 = rl_i(s, j + 1), s2 = rl_i(s, j + 2), s3 = rl_i(s, j + 3);
      const float w0 = rl_f(w, j), w1 = rl_f(w, j + 1), w2 = rl_f(w, j + 2), w3 = rl_f(w, j + 3);
      const float a0 = bf2f(h[(size_t)s0 * 64 + lane]);
      const float a1 = bf2f(h[(size_t)s1 * 64 + lane]);
      const float a2 = bf2f(h[(size_t)s2 * 64 + lane]);
      const float a3 = bf2f(h[(size_t)s3 * 64 + lane]);
      acc += w0 * a0 + w1 * a1 + w2 * a2 + w3 * a3;
    }
    for (; j < cnt; ++j) {
      const int sj = rl_i(s, j);
      const float wj = rl_f(w, j);
      acc += wj * bf2f(h[(size_t)sj * 64 + lane]);
    }
  }
#pragma unroll
  for (int off = 32; off; off >>= 1) denl += __shfl_xor(denl, off);
  outb[(size_t)d * 64 + lane] = acc / denl + bias[lane];
}

extern "C" void kernel_launch(void* const* d_in, const int* in_sizes, int n_in,
                              void* d_out, int out_size, void* d_ws, size_t ws_size,
                              hipStream_t stream) {
  const float* x        = (const float*)d_in[0];
  const int*   ei_sp    = (const int*)d_in[1];
  const int*   ei_gs    = (const int*)d_in[2];
  const float* W_sp     = (const float*)d_in[3];
  const float* a_src_sp = (const float*)d_in[4];
  const float* a_dst_sp = (const float*)d_in[5];
  const float* b_sp     = (const float*)d_in[6];
  const float* W_gs     = (const float*)d_in[7];
  const float* a_src_gs = (const float*)d_in[8];
  const float* a_dst_gs = (const float*)d_in[9];
  const float* b_gs     = (const float*)d_in[10];
  const float* W_fu     = (const float*)d_in[11];
  const float* a_src_fu = (const float*)d_in[12];
  const float* a_dst_fu = (const float*)d_in[13];
  const float* b_fu     = (const float*)d_in[14];
  float* out = (float*)d_out;

  const int N = in_sizes[0] / 512;
  const int E = in_sizes[1] / 2;
  const int nb = (N + 255) / 256;

  // ---- workspace layout ----
  unsigned short* wt_sp = (unsigned short*)d_ws;       // 256*512
  unsigned short* wt_gs = wt_sp + 256 * 512;           // 256*512
  unsigned short* wt_fu = wt_gs + 256 * 512;           // 64*256
  unsigned short* hb_sp = wt_fu + 64 * 256;            // N*256 bf16
  unsigned short* hb_gs = hb_sp + (size_t)N * 256;     // N*256 bf16
  unsigned short* B3    = hb_gs + (size_t)N * 256;     // N*256 bf16 (later hfu N*64)
  unsigned short* hfb   = B3 + (size_t)N * 256;        // N*256 bf16 h_fused
  float* asrc_sp = (float*)(hfb + (size_t)N * 256);    // N
  float* adst_sp = asrc_sp + N;                        // N
  float* asrc_gs = adst_sp + N;                        // N
  float* adst_gs = asrc_gs + N;                        // N
  int* rs_sp  = (int*)(adst_gs + N);                   // N+1
  int* rs_gs  = rs_sp + (N + 1);                       // N+1
  int* csr_sp = rs_gs + (N + 1);                       // E
  int* csr_gs = csr_sp + E;                            // E
  int* deg_sp = csr_gs + E;                            // N
  int* deg_gs = deg_sp + N;                            // N
  int* parts2 = deg_gs + N;                            // 2*512
  int* ord_sp = parts2 + 1024;                         // E
  int* ord_gs = ord_sp + E;                            // E

  unsigned short* hfu = B3;                            // [N][64] bf16 (B3 dead)

  const int BLK = 256;
  const int eGrid = (E + BLK - 1) / BLK;
  const int nodeWaveGrid = (N + 3) / 4;
  const dim3 gFu((N + 127) / 128, 1);

  // ---- CSR builds (both graphs, atomic-free scatter) ----
  hipMemsetAsync(deg_sp, 0, (size_t)2 * N * 4, stream);
  hist2<<<eGrid, BLK, 0, stream>>>(ei_sp + E, ei_gs + E, deg_sp, deg_gs,
                                   ord_sp, ord_gs, E);
  scan1_2<<<dim3(nb, 2), BLK, 0, stream>>>(deg_sp, deg_gs, rs_sp, rs_gs, parts2, N);
  scan2_2<<<2, 512, 0, stream>>>(parts2, nb);
  scan3_2<<<dim3(nb, 2), BLK, 0, stream>>>(rs_sp, rs_gs, parts2, N, E);
  scatter2<<<eGrid, BLK, 0, stream>>>(ei_sp, ei_gs, rs_sp, rs_gs, ord_sp, ord_gs,
                                      csr_sp, csr_gs, E);

  // ---- weight conversions (one launch) ----
  wt_bf16_all<<<(278528 + 255) / 256, BLK, 0, stream>>>(W_sp, W_gs, W_fu,
                                                        wt_sp, wt_gs, wt_fu);

  // ---- fused layer-1 GEMMs: x read once ----
  gemm2_fused<<<(N + 63) / 64, 512, 0, stream>>>(x, wt_sp, wt_gs, hb_sp, hb_gs, N);

  // ---- dual alpha ----
  alpha2_256<<<nodeWaveGrid, BLK, 0, stream>>>((const ushort4*)hb_sp,
                                               (const ushort4*)hb_gs,
                                               a_src_sp, a_dst_sp, a_src_gs, a_dst_gs,
                                               asrc_sp, adst_sp, asrc_gs, adst_gs, N);

  // ---- spatial conv -> B3 = bf16(elu(agg+b_sp)) ----
  agg_csr256<1><<<nodeWaveGrid, BLK, 0, stream>>>(rs_sp, csr_sp, asrc_sp, adst_sp,
                                                  (const ushort4*)hb_sp, b_sp,
                                                  nullptr, (ushort4*)B3, N);

  // ---- gene conv + blend -> h_fused bf16 ----
  agg_csr256<2><<<nodeWaveGrid, BLK, 0, stream>>>(rs_gs, csr_gs, asrc_gs, adst_gs,
                                                  (const ushort4*)hb_gs, b_gs,
                                                  (const ushort4*)B3, (ushort4*)hfb, N);

  // ---- fusion conv (256->64, spatial graph) ----
  gemm_bf16_nt<64><<<gFu, BLK, 0, stream>>>(hfb, wt_fu, hfu, N, 64, 256);
  alpha64<<<nodeWaveGrid, BLK, 0, stream>>>(hfu, a_src_fu, a_dst_fu,
                                            asrc_sp, adst_sp, N);
  agg_csr64<<<nodeWaveGrid, BLK, 0, stream>>>(rs_sp, csr_sp, asrc_sp, adst_sp,
                                              hfu, b_fu, out, N);
}

// Round 9
// 491.657 us; speedup vs baseline: 15.9124x; 1.0323x over previous
//
#include <hip/hip_runtime.h>
#include <math.h>

// Round 9: gemm2_fused at BM=128 / 1024 threads (16 waves) — halves the per-block
// weight re-staging traffic (800 -> 400 MB L2->LDS), reverts round-8's prefetch
// (it cost occupancy). Round-7 2-barrier loop body, XOR-swizzled LDS (verified
// conflict-free). CSR build with atomic-free scatter kept from round 8.

#define NEG_SLOPE 0.2f

typedef __attribute__((ext_vector_type(8))) short bf16x8;
typedef __attribute__((ext_vector_type(4))) float f32x4;

__device__ __forceinline__ unsigned short f2bf(float f) {
  unsigned int u = __float_as_uint(f);
  u = (u + 0x7FFFu + ((u >> 16) & 1u)) >> 16;  // RNE
  return (unsigned short)u;
}
__device__ __forceinline__ float bf2f(unsigned short u) {
  return __uint_as_float((unsigned int)u << 16);
}
__device__ __forceinline__ int rl_i(int v, int l) {
  return __builtin_amdgcn_readlane(v, l);
}
__device__ __forceinline__ float rl_f(float v, int l) {
  return __uint_as_float(__builtin_amdgcn_readlane(__float_as_uint(v), l));
}

#define GLOAD16(g, l)                                                   \
  __builtin_amdgcn_global_load_lds(                                     \
      (const __attribute__((address_space(1))) void*)(g),               \
      (__attribute__((address_space(3))) void*)(l), 16, 0, 0)

// ---------------- weight conversions (all three in one launch) ----------------
__global__ __launch_bounds__(256) void wt_bf16_all(const float* __restrict__ W_sp,
                                                   const float* __restrict__ W_gs,
                                                   const float* __restrict__ W_fu,
                                                   unsigned short* __restrict__ wt_sp,
                                                   unsigned short* __restrict__ wt_gs,
                                                   unsigned short* __restrict__ wt_fu) {
  const int i = blockIdx.x * 256 + threadIdx.x;
  if (i < 131072) {                       // 512x256 spatial
    const int k = i >> 8, n = i & 255;
    wt_sp[n * 512 + k] = f2bf(W_sp[i]);
  } else if (i < 262144) {                // 512x256 gene
    const int j = i - 131072;
    const int k = j >> 8, n = j & 255;
    wt_gs[n * 512 + k] = f2bf(W_gs[j]);
  } else if (i < 278528) {                // 256x64 fusion
    const int j = i - 262144;
    const int k = j >> 6, n = j & 63;
    wt_fu[n * 256 + k] = f2bf(W_fu[j]);
  }
}

// ---------------- CSR build ----------------
__global__ __launch_bounds__(256) void hist2(const int* __restrict__ dst_sp,
                                             const int* __restrict__ dst_gs,
                                             int* __restrict__ deg_sp,
                                             int* __restrict__ deg_gs,
                                             int* __restrict__ ord_sp,
                                             int* __restrict__ ord_gs, int E) {
  const int m = blockIdx.x * 256 + threadIdx.x;
  if (m < E) {
    ord_sp[m] = atomicAdd(&deg_sp[dst_sp[m]], 1);
    ord_gs[m] = atomicAdd(&deg_gs[dst_gs[m]], 1);
  }
}

__global__ __launch_bounds__(256) void scan1_2(const int* __restrict__ deg_sp,
                                               const int* __restrict__ deg_gs,
                                               int* __restrict__ rs_sp,
                                               int* __restrict__ rs_gs,
                                               int* __restrict__ parts2, int N) {
  __shared__ int sm[256];
  const int* deg = blockIdx.y ? deg_gs : deg_sp;
  int* rs = blockIdx.y ? rs_gs : rs_sp;
  int* parts = parts2 + blockIdx.y * 512;
  const int i = blockIdx.x * 256 + threadIdx.x;
  const int v = (i < N) ? deg[i] : 0;
  sm[threadIdx.x] = v;
  __syncthreads();
  for (int off = 1; off < 256; off <<= 1) {
    const int x = (threadIdx.x >= off) ? sm[threadIdx.x - off] : 0;
    __syncthreads();
    sm[threadIdx.x] += x;
    __syncthreads();
  }
  if (i < N) rs[i] = sm[threadIdx.x] - v;
  if (threadIdx.x == 255) parts[blockIdx.x] = sm[255];
}

__global__ __launch_bounds__(512) void scan2_2(int* __restrict__ parts2, int nb) {
  __shared__ int sm[512];
  int* parts = parts2 + blockIdx.x * 512;
  const int t = threadIdx.x;
  const int v = (t < nb) ? parts[t] : 0;
  sm[t] = v;
  __syncthreads();
  for (int off = 1; off < 512; off <<= 1) {
    const int x = (t >= off) ? sm[t - off] : 0;
    __syncthreads();
    sm[t] += x;
    __syncthreads();
  }
  if (t < nb) parts[t] = sm[t] - v;
}

__global__ __launch_bounds__(256) void scan3_2(int* __restrict__ rs_sp,
                                               int* __restrict__ rs_gs,
                                               const int* __restrict__ parts2,
                                               int N, int E) {
  int* rs = blockIdx.y ? rs_gs : rs_sp;
  const int* parts = parts2 + blockIdx.y * 512;
  const int i = blockIdx.x * 256 + threadIdx.x;
  if (i < N) rs[i] += parts[blockIdx.x];
  if (i == 0) rs[N] = E;
}

__global__ __launch_bounds__(256) void scatter2(const int* __restrict__ ei_sp,
                                                const int* __restrict__ ei_gs,
                                                const int* __restrict__ rs_sp,
                                                const int* __restrict__ rs_gs,
                                                const int* __restrict__ ord_sp,
                                                const int* __restrict__ ord_gs,
                                                int* __restrict__ csr_sp,
                                                int* __restrict__ csr_gs, int E) {
  const int m = blockIdx.x * 256 + threadIdx.x;
  if (m >= E) return;
  csr_sp[rs_sp[ei_sp[E + m]] + ord_sp[m]] = ei_sp[m];
  csr_gs[rs_gs[ei_gs[E + m]] + ord_gs[m]] = ei_gs[m];
}

// ---------------- fused layer-1: h_sp, h_gs = bf16(x @ {W_sp, W_gs}) ----------------
// BM=128, 1024 threads (16 waves), BK=64. Halves: waves 0-7 -> h_sp, 8-15 -> h_gs.
// Within a half: wr = row-group (2 x 64 rows), wq = col-quarter (4 x 64 cols).
// x fp32 read once -> bf16 swizzled LDS; W via global_load_lds (pre-swizzled src).
__global__ __launch_bounds__(1024) void gemm2_fused(const float* __restrict__ x,
                                                    const unsigned short* __restrict__ wsp,
                                                    const unsigned short* __restrict__ wgs,
                                                    unsigned short* __restrict__ hb_sp,
                                                    unsigned short* __restrict__ hb_gs,
                                                    int M) {
  __shared__ unsigned short sA[128 * 64];      // 16 KB, swizzled
  __shared__ unsigned short sW[2][256 * 64];   // 2 x 32 KB, swizzled
  const int tid = threadIdx.x;
  const int w = tid >> 6, l = tid & 63;
  const int whalf = w >> 3;        // 0 = spatial, 1 = gene
  const int wsub = w & 7;
  const int wr = wsub >> 2;        // row-group 0..1
  const int wq = wsub & 3;         // col-quarter 0..3
  const int bm = blockIdx.x * 128;

  // A-load mapping: 2 rows per thread (arow0, arow0+64), one float4 each
  const int arow0 = tid >> 4;            // 0..63
  const int acol4 = (tid & 15) * 4;      // fp32 col 0,4,..,60
  int g0 = bm + arow0;       g0 = g0 < M ? g0 : M - 1;
  int g1 = bm + arow0 + 64;  g1 = g1 < M ? g1 : M - 1;
  const float* __restrict__ ap0 = x + (size_t)g0 * 512 + acol4;
  const float* __restrict__ ap1 = x + (size_t)g1 * 512 + acol4;
  const int abyte0 = (arow0 * 128 + acol4 * 2) ^ ((arow0 & 7) << 4);
  const int abyte1 = ((arow0 + 64) * 128 + acol4 * 2) ^ (((arow0 + 64) & 7) << 4);

  const unsigned short* __restrict__ wtp = whalf ? wgs : wsp;
  const int wrow_in_ch = l >> 3;
  const int wbyte = ((l & 7) * 16) ^ ((wrow_in_ch & 7) << 4);

  f32x4 acc[4][4] = {};
  for (int k0 = 0; k0 < 512; k0 += 64) {
    __syncthreads();
    // ---- A: fp32 -> bf16 into swizzled LDS ----
    {
      const float4 v0 = *(const float4*)(ap0 + k0);
      const float4 v1 = *(const float4*)(ap1 + k0);
      ushort4 o0, o1;
      o0.x = f2bf(v0.x); o0.y = f2bf(v0.y); o0.z = f2bf(v0.z); o0.w = f2bf(v0.w);
      o1.x = f2bf(v1.x); o1.y = f2bf(v1.y); o1.z = f2bf(v1.z); o1.w = f2bf(v1.w);
      *(ushort4*)(((char*)sA) + abyte0) = o0;
      *(ushort4*)(((char*)sA) + abyte1) = o1;
    }
    // ---- W: each half (8 waves) stages its 32KB tile: 4 chunks/wave ----
#pragma unroll
    for (int c = 0; c < 4; ++c) {
      const int ch = c * 8 + wsub;                     // 0..31
      const int grow = ch * 8 + wrow_in_ch;            // Wt row 0..255
      const char* g = (const char*)wtp + (size_t)grow * 1024 + (size_t)k0 * 2 + wbyte;
      GLOAD16(g, ((char*)sW[whalf]) + ch * 1024);
    }
    __syncthreads();
    // ---- MFMA ----
#pragma unroll
    for (int ks = 0; ks < 2; ++ks) {
      const int cb = ks * 64 + (l >> 4) * 16;
      bf16x8 af[4], bf[4];
#pragma unroll
      for (int m = 0; m < 4; ++m) {
        const int r = wr * 64 + m * 16 + (l & 15);
        af[m] = *(const bf16x8*)(((const char*)sA) + r * 128 + (cb ^ ((r & 7) << 4)));
      }
#pragma unroll
      for (int n = 0; n < 4; ++n) {
        const int r = wq * 64 + n * 16 + (l & 15);
        bf[n] = *(const bf16x8*)(((const char*)sW[whalf]) + r * 128 + (cb ^ ((r & 7) << 4)));
      }
#pragma unroll
      for (int m = 0; m < 4; ++m)
#pragma unroll
        for (int n = 0; n < 4; ++n)
          acc[m][n] = __builtin_amdgcn_mfma_f32_16x16x32_bf16(af[m], bf[n], acc[m][n], 0, 0, 0);
    }
  }
  unsigned short* __restrict__ outp = whalf ? hb_gs : hb_sp;
#pragma unroll
  for (int m = 0; m < 4; ++m) {
#pragma unroll
    for (int r = 0; r < 4; ++r) {
      const int row = bm + wr * 64 + m * 16 + (l >> 4) * 4 + r;
      if (row < M) {
#pragma unroll
        for (int n = 0; n < 4; ++n)
          outp[(size_t)row * 256 + wq * 64 + n * 16 + (l & 15)] = f2bf(acc[m][n][r]);
      }
    }
  }
}

// ---------------- bf16 MFMA GEMM (NT) for fusion layer (256->64) ----------------
template <int BN>
__global__ __launch_bounds__(256) void gemm_bf16_nt(const unsigned short* __restrict__ A,
                                                    const unsigned short* __restrict__ Bt,
                                                    unsigned short* __restrict__ C,
                                                    int M, int Nc, int K) {
  constexpr int BM = 128, BK = 64;
  constexpr int NW = BN / 64;
  constexpr int MW = 4 / NW;
  constexpr int MF = (BM / MW) / 16;
  constexpr int NF = 4;
  constexpr int ACW = (BM * BK * 2 / 1024) / 4;
  constexpr int BCW = (BN * BK * 2 / 1024) / 4;
  __shared__ unsigned short sA[BM * BK];
  __shared__ unsigned short sB[BN * BK];
  const int tid = threadIdx.x;
  const int w = tid >> 6, l = tid & 63;
  const int wr = w / NW, wc = w % NW;
  const int bm = blockIdx.x * BM;
  const int bn = blockIdx.y * BN;
  const int crow = l >> 3;
  const int cbyte = (l & 7) * 16;

  f32x4 acc[MF][NF] = {};
  for (int k0 = 0; k0 < K; k0 += BK) {
    __syncthreads();
#pragma unroll
    for (int c = 0; c < ACW; ++c) {
      const int ch = w * ACW + c;
      int row = bm + ch * 8 + crow;
      row = row < M ? row : M - 1;
      const char* g = (const char*)A + (size_t)row * K * 2 + (size_t)k0 * 2 + cbyte;
      GLOAD16(g, ((char*)sA) + ch * 1024);
    }
#pragma unroll
    for (int c = 0; c < BCW; ++c) {
      const int ch = w * BCW + c;
      const int row = bn + ch * 8 + crow;
      const char* g = (const char*)Bt + (size_t)row * K * 2 + (size_t)k0 * 2 + cbyte;
      GLOAD16(g, ((char*)sB) + ch * 1024);
    }
    __syncthreads();
#pragma unroll
    for (int ks = 0; ks < 2; ++ks) {
      bf16x8 af[MF], bfr[NF];
#pragma unroll
      for (int m = 0; m < MF; ++m) {
        const int r = wr * (BM / MW) + m * 16 + (l & 15);
        af[m] = *(const bf16x8*)&sA[r * BK + ks * 32 + (l >> 4) * 8];
      }
#pragma unroll
      for (int n = 0; n < NF; ++n) {
        const int r = wc * 64 + n * 16 + (l & 15);
        bfr[n] = *(const bf16x8*)&sB[r * BK + ks * 32 + (l >> 4) * 8];
      }
#pragma unroll
      for (int m = 0; m < MF; ++m)
#pragma unroll
        for (int n = 0; n < NF; ++n)
          acc[m][n] = __builtin_amdgcn_mfma_f32_16x16x32_bf16(af[m], bfr[n], acc[m][n], 0, 0, 0);
    }
  }
#pragma unroll
  for (int m = 0; m < MF; ++m) {
#pragma unroll
    for (int r = 0; r < 4; ++r) {
      const int row = bm + wr * (BM / MW) + m * 16 + (l >> 4) * 4 + r;
      if (row < M) {
#pragma unroll
        for (int n = 0; n < NF; ++n)
          C[(size_t)row * Nc + bn + wc * 64 + n * 16 + (l & 15)] = f2bf(acc[m][n][r]);
      }
    }
  }
}

// ---------------- dual alpha dots ----------------
__global__ __launch_bounds__(256) void alpha2_256(const ushort4* __restrict__ hsp,
                                                  const ushort4* __restrict__ hgs,
                                                  const float* __restrict__ av_sp_s,
                                                  const float* __restrict__ av_sp_d,
                                                  const float* __restrict__ av_gs_s,
                                                  const float* __restrict__ av_gs_d,
                                                  float* __restrict__ asrc_sp,
                                                  float* __restrict__ adst_sp,
                                                  float* __restrict__ asrc_gs,
                                                  float* __restrict__ adst_gs, int N) {
  const int wave = (int)((blockIdx.x * (size_t)blockDim.x + threadIdx.x) >> 6);
  const int lane = threadIdx.x & 63;
  if (wave >= N) return;
  const ushort4 h1 = hsp[(size_t)wave * 64 + lane];
  const ushort4 h2 = hgs[(size_t)wave * 64 + lane];
  const float4 s1 = ((const float4*)av_sp_s)[lane];
  const float4 d1 = ((const float4*)av_sp_d)[lane];
  const float4 s2 = ((const float4*)av_gs_s)[lane];
  const float4 d2 = ((const float4*)av_gs_d)[lane];
  const float a0 = bf2f(h1.x), a1 = bf2f(h1.y), a2 = bf2f(h1.z), a3 = bf2f(h1.w);
  const float b0 = bf2f(h2.x), b1 = bf2f(h2.y), b2 = bf2f(h2.z), b3 = bf2f(h2.w);
  float p0 = a0 * s1.x + a1 * s1.y + a2 * s1.z + a3 * s1.w;
  float p1 = a0 * d1.x + a1 * d1.y + a2 * d1.z + a3 * d1.w;
  float p2 = b0 * s2.x + b1 * s2.y + b2 * s2.z + b3 * s2.w;
  float p3 = b0 * d2.x + b1 * d2.y + b2 * d2.z + b3 * d2.w;
#pragma unroll
  for (int off = 32; off; off >>= 1) {
    p0 += __shfl_down(p0, off);
    p1 += __shfl_down(p1, off);
    p2 += __shfl_down(p2, off);
    p3 += __shfl_down(p3, off);
  }
  if (lane == 0) {
    asrc_sp[wave] = p0; adst_sp[wave] = p1;
    asrc_gs[wave] = p2; adst_gs[wave] = p3;
  }
}

__global__ __launch_bounds__(256) void alpha64(const unsigned short* __restrict__ h,
                                               const float* __restrict__ a_src,
                                               const float* __restrict__ a_dst,
                                               float* __restrict__ asrc,
                                               float* __restrict__ adst, int N) {
  const int wave = (int)((blockIdx.x * (size_t)blockDim.x + threadIdx.x) >> 6);
  const int lane = threadIdx.x & 63;
  if (wave >= N) return;
  const float hv = bf2f(h[(size_t)wave * 64 + lane]);
  float ps = hv * a_src[lane];
  float pd = hv * a_dst[lane];
#pragma unroll
  for (int off = 32; off; off >>= 1) {
    ps += __shfl_down(ps, off);
    pd += __shfl_down(pd, off);
  }
  if (lane == 0) { asrc[wave] = ps; adst[wave] = pd; }
}

// ---------------- fused CSR aggregation, H=256, bf16 h ----------------
template <int EPI>
__global__ __launch_bounds__(256) void agg_csr256(const int* __restrict__ rs,
                                                  const int* __restrict__ csr,
                                                  const float* __restrict__ asrc,
                                                  const float* __restrict__ adst,
                                                  const ushort4* __restrict__ h4,
                                                  const float* __restrict__ bias,
                                                  const ushort4* __restrict__ other16,
                                                  ushort4* __restrict__ out16, int N) {
  const int d = (int)((blockIdx.x * (size_t)blockDim.x + threadIdx.x) >> 6);
  const int lane = threadIdx.x & 63;
  if (d >= N) return;
  const float ad = adst[d];

  float e = asrc[d] + ad;
  e = e > 0.f ? e : NEG_SLOPE * e;
  const float wself = expf(e);
  float denl = (lane == 0) ? wself : 0.f;
  const ushort4 hv = h4[(size_t)d * 64 + lane];
  float ax = wself * bf2f(hv.x), ay = wself * bf2f(hv.y),
        az = wself * bf2f(hv.z), aw = wself * bf2f(hv.w);

  const int base = rs[d], mend = rs[d + 1];
  for (int c = base; c < mend; c += 64) {
    const int m = c + lane;
    int s = 0;
    float w = 0.f;
    if (m < mend) {
      s = csr[m];
      float e2 = asrc[s] + ad;
      e2 = e2 > 0.f ? e2 : NEG_SLOPE * e2;
      w = expf(e2);
    }
    denl += w;
    const int cnt = min(64, mend - c);
    int j = 0;
    for (; j + 3 < cnt; j += 4) {
      const int s0 = rl_i(s, j), s1 = rl_i(s, j + 1), s2 = rl_i(s, j + 2), s3 = rl_i(s, j + 3);
      const float w0 = rl_f(w, j), w1 = rl_f(w, j + 1), w2 = rl_f(w, j + 2), w3 = rl_f(w, j + 3);
      const ushort4 a0 = h4[(size_t)s0 * 64 + lane];
      const ushort4 a1 = h4[(size_t)s1 * 64 + lane];
      const ushort4 a2 = h4[(size_t)s2 * 64 + lane];
      const ushort4 a3 = h4[(size_t)s3 * 64 + lane];
      ax += w0 * bf2f(a0.x) + w1 * bf2f(a1.x) + w2 * bf2f(a2.x) + w3 * bf2f(a3.x);
      ay += w0 * bf2f(a0.y) + w1 * bf2f(a1.y) + w2 * bf2f(a2.y) + w3 * bf2f(a3.y);
      az += w0 * bf2f(a0.z) + w1 * bf2f(a1.z) + w2 * bf2f(a2.z) + w3 * bf2f(a3.z);
      aw += w0 * bf2f(a0.w) + w1 * bf2f(a1.w) + w2 * bf2f(a2.w) + w3 * bf2f(a3.w);
    }
    for (; j < cnt; ++j) {
      const int sj = rl_i(s, j);
      const float wj = rl_f(w, j);
      const ushort4 aj = h4[(size_t)sj * 64 + lane];
      ax += wj * bf2f(aj.x);
      ay += wj * bf2f(aj.y);
      az += wj * bf2f(aj.z);
      aw += wj * bf2f(aj.w);
    }
  }
#pragma unroll
  for (int off = 32; off; off >>= 1) denl += __shfl_xor(denl, off);
  const float inv = 1.f / denl;

  const float4 b4 = ((const float4*)bias)[lane];
  float v[4] = {ax * inv + b4.x, ay * inv + b4.y, az * inv + b4.z, aw * inv + b4.w};
#pragma unroll
  for (int j = 0; j < 4; ++j) v[j] = v[j] > 0.f ? v[j] : (expf(v[j]) - 1.f);
  ushort4 pk;
  if (EPI == 2) {
    const ushort4 ov = other16[(size_t)d * 64 + lane];
    pk.x = f2bf(0.5f * v[0] + 0.5f * bf2f(ov.x));
    pk.y = f2bf(0.5f * v[1] + 0.5f * bf2f(ov.y));
    pk.z = f2bf(0.5f * v[2] + 0.5f * bf2f(ov.z));
    pk.w = f2bf(0.5f * v[3] + 0.5f * bf2f(ov.w));
  } else {
    pk.x = f2bf(v[0]); pk.y = f2bf(v[1]); pk.z = f2bf(v[2]); pk.w = f2bf(v[3]);
  }
  out16[(size_t)d * 64 + lane] = pk;
}

// ---------------- fused CSR aggregation, H=64, bf16 h -> fp32 d_out ----------------
__global__ __launch_bounds__(256) void agg_csr64(const int* __restrict__ rs,
                                                 const int* __restrict__ csr,
                                                 const float* __restrict__ asrc,
                                                 const float* __restrict__ adst,
                                                 const unsigned short* __restrict__ h,
                                                 const float* __restrict__ bias,
                                                 float* __restrict__ outb, int N) {
  const int d = (int)((blockIdx.x * (size_t)blockDim.x + threadIdx.x) >> 6);
  const int lane = threadIdx.x & 63;
  if (d >= N) return;
  const float ad = adst[d];

  float e = asrc[d] + ad;
  e = e > 0.f ? e : NEG_SLOPE * e;
  const float wself = expf(e);
  float denl = (lane == 0) ? wself : 0.f;
  float acc = wself * bf2f(h[(size_t)d * 64 + lane]);

  const int base = rs[d], mend = rs[d + 1];
  for (int c = base; c < mend; c += 64) {
    const int m = c + lane;
    int s = 0;
    float w = 0.f;
    if (m < mend) {
      s = csr[m];
      float e2 = asrc[s] + ad;
      e2 = e2 > 0.f ? e2 : NEG_SLOPE * e2;
      w = expf(e2);
    }
    denl += w;
    const int cnt = min(64, mend - c);
    int j = 0;
    for (; j + 3 < cnt; j += 4) {
      const int s0 = rl_i(s, j), s1 = rl_i(s, j + 1), s2 = rl_i(s, j + 2), s3 = rl_i(s, j + 3);
      const float w0 = rl_f(w, j), w1 = rl_f(w, j + 1), w2 = rl_f(w, j + 2), w3 = rl_f(w, j + 3);
      const float a0 = bf2f(h[(size_t)s0 * 64 + lane]);
      const float a1 = bf2f(h[(size_t)s1 * 64 + lane]);
      const float a2 = bf2f(h[(size_t)s2 * 64 + lane]);
      const float a3 = bf2f(h[(size_t)s3 * 64 + lane]);
      acc += w0 * a0 + w1 * a1 + w2 * a2 + w3 * a3;
    }
    for (; j < cnt; ++j) {
      const int sj = rl_i(s, j);
      const float wj = rl_f(w, j);
      acc += wj * bf2f(h[(size_t)sj * 64 + lane]);
    }
  }
#pragma unroll
  for (int off = 32; off; off >>= 1) denl += __shfl_xor(denl, off);
  outb[(size_t)d * 64 + lane] = acc / denl + bias[lane];
}

extern "C" void kernel_launch(void* const* d_in, const int* in_sizes, int n_in,
                              void* d_out, int out_size, void* d_ws, size_t ws_size,
                              hipStream_t stream) {
  const float* x        = (const float*)d_in[0];
  const int*   ei_sp    = (const int*)d_in[1];
  const int*   ei_gs    = (const int*)d_in[2];
  const float* W_sp     = (const float*)d_in[3];
  const float* a_src_sp = (const float*)d_in[4];
  const float* a_dst_sp = (const float*)d_in[5];
  const float* b_sp     = (const float*)d_in[6];
  const float* W_gs     = (const float*)d_in[7];
  const float* a_src_gs = (const float*)d_in[8];
  const float* a_dst_gs = (const float*)d_in[9];
  const float* b_gs     = (const float*)d_in[10];
  const float* W_fu     = (const float*)d_in[11];
  const float* a_src_fu = (const float*)d_in[12];
  const float* a_dst_fu = (const float*)d_in[13];
  const float* b_fu     = (const float*)d_in[14];
  float* out = (float*)d_out;

  const int N = in_sizes[0] / 512;
  const int E = in_sizes[1] / 2;
  const int nb = (N + 255) / 256;

  // ---- workspace layout ----
  unsigned short* wt_sp = (unsigned short*)d_ws;       // 256*512
  unsigned short* wt_gs = wt_sp + 256 * 512;           // 256*512
  unsigned short* wt_fu = wt_gs + 256 * 512;           // 64*256
  unsigned short* hb_sp = wt_fu + 64 * 256;            // N*256 bf16
  unsigned short* hb_gs = hb_sp + (size_t)N * 256;     // N*256 bf16
  unsigned short* B3    = hb_gs + (size_t)N * 256;     // N*256 bf16 (later hfu N*64)
  unsigned short* hfb   = B3 + (size_t)N * 256;        // N*256 bf16 h_fused
  float* asrc_sp = (float*)(hfb + (size_t)N * 256);    // N
  float* adst_sp = asrc_sp + N;                        // N
  float* asrc_gs = adst_sp + N;                        // N
  float* adst_gs = asrc_gs + N;                        // N
  int* rs_sp  = (int*)(adst_gs + N);                   // N+1
  int* rs_gs  = rs_sp + (N + 1);                       // N+1
  int* csr_sp = rs_gs + (N + 1);                       // E
  int* csr_gs = csr_sp + E;                            // E
  int* deg_sp = csr_gs + E;                            // N
  int* deg_gs = deg_sp + N;                            // N
  int* parts2 = deg_gs + N;                            // 2*512
  int* ord_sp = parts2 + 1024;                         // E
  int* ord_gs = ord_sp + E;                            // E

  unsigned short* hfu = B3;                            // [N][64] bf16 (B3 dead)

  const int BLK = 256;
  const int eGrid = (E + BLK - 1) / BLK;
  const int nodeWaveGrid = (N + 3) / 4;
  const dim3 gFu((N + 127) / 128, 1);

  // ---- CSR builds (both graphs, atomic-free scatter) ----
  hipMemsetAsync(deg_sp, 0, (size_t)2 * N * 4, stream);
  hist2<<<eGrid, BLK, 0, stream>>>(ei_sp + E, ei_gs + E, deg_sp, deg_gs,
                                   ord_sp, ord_gs, E);
  scan1_2<<<dim3(nb, 2), BLK, 0, stream>>>(deg_sp, deg_gs, rs_sp, rs_gs, parts2, N);
  scan2_2<<<2, 512, 0, stream>>>(parts2, nb);
  scan3_2<<<dim3(nb, 2), BLK, 0, stream>>>(rs_sp, rs_gs, parts2, N, E);
  scatter2<<<eGrid, BLK, 0, stream>>>(ei_sp, ei_gs, rs_sp, rs_gs, ord_sp, ord_gs,
                                      csr_sp, csr_gs, E);

  // ---- weight conversions (one launch) ----
  wt_bf16_all<<<(278528 + 255) / 256, BLK, 0, stream>>>(W_sp, W_gs, W_fu,
                                                        wt_sp, wt_gs, wt_fu);

  // ---- fused layer-1 GEMMs: x read once, BM=128 ----
  gemm2_fused<<<(N + 127) / 128, 1024, 0, stream>>>(x, wt_sp, wt_gs, hb_sp, hb_gs, N);

  // ---- dual alpha ----
  alpha2_256<<<nodeWaveGrid, BLK, 0, stream>>>((const ushort4*)hb_sp,
                                               (const ushort4*)hb_gs,
                                               a_src_sp, a_dst_sp, a_src_gs, a_dst_gs,
                                               asrc_sp, adst_sp, asrc_gs, adst_gs, N);

  // ---- spatial conv -> B3 = bf16(elu(agg+b_sp)) ----
  agg_csr256<1><<<nodeWaveGrid, BLK, 0, stream>>>(rs_sp, csr_sp, asrc_sp, adst_sp,
                                                  (const ushort4*)hb_sp, b_sp,
                                                  nullptr, (ushort4*)B3, N);

  // ---- gene conv + blend -> h_fused bf16 ----
  agg_csr256<2><<<nodeWaveGrid, BLK, 0, stream>>>(rs_gs, csr_gs, asrc_gs, adst_gs,
                                                  (const ushort4*)hb_gs, b_gs,
                                                  (const ushort4*)B3, (ushort4*)hfb, N);

  // ---- fusion conv (256->64, spatial graph) ----
  gemm_bf16_nt<64><<<gFu, BLK, 0, stream>>>(hfb, wt_fu, hfu, N, 64, 256);
  alpha64<<<nodeWaveGrid, BLK, 0, stream>>>(hfu, a_src_fu, a_dst_fu,
                                            asrc_sp, adst_sp, N);
  agg_csr64<<<nodeWaveGrid, BLK, 0, stream>>>(rs_sp, csr_sp, asrc_sp, adst_sp,
                                              hfu, b_fu, out, N);
}